// Round 17
// baseline (413.301 us; speedup 1.0000x reference)
//
#include <hip/hip_runtime.h>
#include <cstdint>
#include <cstddef>

namespace {

constexpr int Bb  = 8;
constexpr int Tt  = 1024;
constexpr int Dd  = 768;
constexpr int Hh  = 12;
constexpr int DFF = 3072;
constexpr int BT  = Bb * Tt;

typedef __attribute__((ext_vector_type(8))) short bf16x8;
typedef __attribute__((ext_vector_type(4))) short bf16x4;
typedef __attribute__((ext_vector_type(4))) float f32x4;

__device__ __forceinline__ short f2bf(float f) {
  union { float f; unsigned u; } v; v.f = f;
  unsigned r = v.u + 0x7fffu + ((v.u >> 16) & 1u);   // RNE
  return (short)(r >> 16);
}
__device__ __forceinline__ float bf2f(short s) {
  union { unsigned u; float f; } v;
  v.u = ((unsigned)(unsigned short)s) << 16;
  return v.f;
}
__device__ __forceinline__ float gelu_exact(float v) {
  return 0.5f * v * (1.0f + erff(v * 0.70710678118654752f));
}

#define MFMA16(a, b, c) __builtin_amdgcn_mfma_f32_16x16x32_bf16(a, b, c, 0, 0, 0)

__device__ __forceinline__ void gl_lds16(const short* g, short* l) {
  __builtin_amdgcn_global_load_lds(
      (const __attribute__((address_space(1))) unsigned int*)(g),
      (__attribute__((address_space(3))) unsigned int*)(l), 16, 0, 0);
}

// ---------- weight convert+transpose body ----------
__device__ __forceinline__ void cvt_body(float (*tile)[33],
                                         const float* __restrict__ in,
                                         short* __restrict__ out,
                                         int K, int N, int bx, int by) {
  int k0 = bx * 32, n0 = by * 32;
  int tx = threadIdx.x & 31, ty = threadIdx.x >> 5;
  #pragma unroll
  for (int r = ty; r < 32; r += 8)
    tile[r][tx] = in[(size_t)(k0 + r) * N + n0 + tx];
  __syncthreads();
  #pragma unroll
  for (int r = ty; r < 32; r += 8)
    out[(size_t)(n0 + r) * K + k0 + tx] = f2bf(tile[tx][r]);
}

// ---------- LayerNorm body ----------
__device__ __forceinline__ void ln_body(const float* __restrict__ x,
                                        const float* __restrict__ g,
                                        const float* __restrict__ b,
                                        short* __restrict__ out, int blkrow) {
  int lane = threadIdx.x & 63, wid = threadIdx.x >> 6;
  int row = blkrow * 4 + wid;
  const float* xr = x + (size_t)row * Dd;
  float v[12];
  float s = 0.f, ss = 0.f;
  #pragma unroll
  for (int c = 0; c < 3; c++) {
    float4 t = *(const float4*)&xr[c * 256 + lane * 4];
    v[c * 4 + 0] = t.x; v[c * 4 + 1] = t.y; v[c * 4 + 2] = t.z; v[c * 4 + 3] = t.w;
    s  += t.x + t.y + t.z + t.w;
    ss += t.x * t.x + t.y * t.y + t.z * t.z + t.w * t.w;
  }
  #pragma unroll
  for (int off = 1; off < 64; off <<= 1) {
    s += __shfl_xor(s, off); ss += __shfl_xor(ss, off);
  }
  float mu   = s * (1.f / Dd);
  float var  = ss * (1.f / Dd) - mu * mu;
  float rstd = rsqrtf(var + 1e-5f);
  #pragma unroll
  for (int c = 0; c < 3; c++) {
    bf16x4 o;
    #pragma unroll
    for (int j = 0; j < 4; j++) {
      int d = c * 256 + lane * 4 + j;
      o[j] = f2bf((v[c * 4 + j] - mu) * rstd * g[d] + b[d]);
    }
    *(bf16x4*)&out[(size_t)row * Dd + c * 256 + lane * 4] = o;
  }
}

// ---------- prep: 4 weight-converts + LN1 ----------
__global__ __launch_bounds__(256) void prep(const float* __restrict__ w_qkv, short* wqkvT,
                                            const float* __restrict__ w_out, short* woutT,
                                            const float* __restrict__ w_fc1, short* wfc1T,
                                            const float* __restrict__ w_fc2, short* wfc2T,
                                            const float* __restrict__ x,
                                            const float* __restrict__ g,
                                            const float* __restrict__ b,
                                            short* __restrict__ h) {
  __shared__ float tile[32][33];
  int j = blockIdx.x;
  if (j < 1728)      cvt_body(tile, w_qkv, wqkvT, 768, 2304, j % 24, j / 24);
  else if (j < 2304) { int t = j - 1728; cvt_body(tile, w_out, woutT, 768, 768, t % 24, t / 24); }
  else if (j < 4608) { int t = j - 2304; cvt_body(tile, w_fc1, wfc1T, 768, 3072, t % 24, t / 24); }
  else if (j < 6912) { int t = j - 4608; cvt_body(tile, w_fc2, wfc2T, 3072, 768, t % 96, t / 96); }
  else               ln_body(x, g, b, h, j - 6912);
}

// ---------- standalone LayerNorm (LN2) ----------
__global__ __launch_bounds__(256) void ln_rows(const float* __restrict__ x,
                                               const float* __restrict__ g,
                                               const float* __restrict__ b,
                                               short* __restrict__ out) {
  ln_body(x, g, b, out, blockIdx.x);
}

// ---------- 128x128 GEMM (QKV w/ VTR) ----------
template <int EPI, int N, bool VTR>
__global__ __launch_bounds__(256) void gemm_bt(const short* __restrict__ A,
                                               const short* __restrict__ Bt,
                                               const float* __restrict__ bias,
                                               const float* __restrict__ add,
                                               void* __restrict__ outp,
                                               int K,
                                               short* __restrict__ vt) {
  __shared__ short S[17408];
  short* As0 = S;
  short* As1 = S + 4096;
  short* Bs0 = S + 8192;
  short* Bs1 = S + 12288;

  int nbx = gridDim.x;
  int flat = blockIdx.y * nbx + blockIdx.x;
  int cpx = (nbx * gridDim.y) >> 3;
  int swz = (flat & 7) * cpx + (flat >> 3);
  int m0 = (swz % nbx) * 128, n0 = (swz / nbx) * 128;

  int tid = threadIdx.x;
  int lane = tid & 63, wid = tid >> 6;
  int wm = wid >> 1, wn = wid & 1;
  int l15 = lane & 15, lg = lane >> 4;

  int jr = tid >> 2, jc = (tid & 3) << 3;
  int ldsb = wid << 9;

  auto stage = [&](short* Ad, short* Bd, int k0) {
    gl_lds16(&A[(size_t)(m0 + jr) * K + k0 + jc],       Ad + ldsb);
    gl_lds16(&A[(size_t)(m0 + 64 + jr) * K + k0 + jc],  Ad + 2048 + ldsb);
    gl_lds16(&Bt[(size_t)(n0 + jr) * K + k0 + jc],      Bd + ldsb);
    gl_lds16(&Bt[(size_t)(n0 + 64 + jr) * K + k0 + jc], Bd + 2048 + ldsb);
  };

  f32x4 acc[4][4] = {};
  stage(As0, Bs0, 0);
  int nk = K >> 5;
  for (int t = 0; t < nk; ++t) {
    short* Ab = (t & 1) ? As1 : As0;
    short* Bb = (t & 1) ? Bs1 : Bs0;
    if (t + 1 < nk) {
      stage((t & 1) ? As0 : As1, (t & 1) ? Bs0 : Bs1, (t + 1) << 5);
      asm volatile("s_waitcnt vmcnt(4)" ::: "memory");
    } else {
      asm volatile("s_waitcnt vmcnt(0)" ::: "memory");
    }
    __syncthreads();
    bf16x8 af[4], bfr[4];
    #pragma unroll
    for (int i = 0; i < 4; i++) af[i]  = *(bf16x8*)&Ab[(wm * 64 + i * 16 + l15) * 32 + lg * 8];
    #pragma unroll
    for (int j = 0; j < 4; j++) bfr[j] = *(bf16x8*)&Bb[(wn * 64 + j * 16 + l15) * 32 + lg * 8];
    #pragma unroll
    for (int i = 0; i < 4; i++)
      #pragma unroll
      for (int j = 0; j < 4; j++)
        acc[i][j] = MFMA16(af[i], bfr[j], acc[i][j]);
    __syncthreads();
  }

  if (EPI == 0 || EPI == 2) {
    short (*Cl)[136] = (short (*)[136])S;
    #pragma unroll
    for (int i = 0; i < 4; i++)
      #pragma unroll
      for (int j = 0; j < 4; j++)
        #pragma unroll
        for (int r = 0; r < 4; r++) {
          int row = wm * 64 + i * 16 + lg * 4 + r;
          int col = wn * 64 + j * 16 + l15;
          float vv = acc[i][j][r] + bias[n0 + col];
          if (EPI == 2) vv = gelu_exact(vv);
          int ch = col >> 3, co = col & 7;
          Cl[row][((ch ^ (row & 7)) << 3) | co] = f2bf(vv);
        }
    __syncthreads();
    if (VTR && n0 >= 1536) {
      int b = m0 >> 10, tbase = m0 & 1023;
      int h0 = (n0 - 1536) >> 6;
      #pragma unroll
      for (int half = 0; half < 2; ++half) {
        int c = (tid >> 2) + half * 64;
        int hh = c >> 6, d = c & 63;
        short* dst = vt + ((size_t)((b * Hh + h0 + hh) * 64 + d)) * Tt
                        + tbase + (tid & 3) * 32;
        #pragma unroll
        for (int j = 0; j < 4; ++j) {
          bf16x8 v8;
          #pragma unroll
          for (int k = 0; k < 8; ++k) {
            int t = (tid & 3) * 32 + j * 8 + k;
            v8[k] = Cl[t][(((c >> 3) ^ (t & 7)) << 3) | (c & 7)];
          }
          *(bf16x8*)(dst + j * 8) = v8;
        }
      }
    } else {
      int row = tid >> 1;
      int cb = (tid & 1) * 8;
      #pragma unroll
      for (int c = 0; c < 8; c++) {
        int ch = cb + c;
        bf16x8 v8 = *(bf16x8*)&Cl[row][(ch ^ (row & 7)) << 3];
        *(bf16x8*)&((short*)outp)[(size_t)(m0 + row) * N + n0 + (ch << 3)] = v8;
      }
    }
  } else {
    #pragma unroll
    for (int i = 0; i < 4; i++)
      #pragma unroll
      for (int j = 0; j < 4; j++)
        #pragma unroll
        for (int r = 0; r < 4; r++) {
          int m = m0 + wm * 64 + i * 16 + lg * 4 + r;
          int n = n0 + wn * 64 + j * 16 + l15;
          float vv = acc[i][j][r] + bias[n];
          size_t idx = (size_t)m * N + n;
          float ov = vv + add[idx];
          if (EPI == 3) __builtin_nontemporal_store(ov, &((float*)outp)[idx]);
          else          ((float*)outp)[idx] = ov;
        }
  }
}

// ---------- 64x128 GEMM, BK=32 (out-proj) ----------
template <int EPI>
__global__ __launch_bounds__(256) void gemm_n64(const short* __restrict__ A,
                                                const short* __restrict__ Bt,
                                                const float* __restrict__ bias,
                                                const float* __restrict__ add,
                                                float* __restrict__ outp,
                                                int K) {
  constexpr int N = 768;
  __shared__ short S[12288];
  short* As0 = S;
  short* As1 = S + 2048;
  short* Bs0 = S + 4096;
  short* Bs1 = S + 8192;

  int nbx = gridDim.x;
  int flat = blockIdx.y * nbx + blockIdx.x;
  int cpx = (nbx * gridDim.y) >> 3;
  int swz = (flat & 7) * cpx + (flat >> 3);
  int m0 = (swz % nbx) * 64, n0 = (swz / nbx) * 128;

  int tid = threadIdx.x;
  int lane = tid & 63, wid = tid >> 6;
  int wm = wid & 1, wn = wid >> 1;
  int l15 = lane & 15, lg = lane >> 4;

  int jr = tid >> 2, jc = (tid & 3) << 3;
  int ldsb = wid << 9;

  auto stage = [&](short* Ad, short* Bd, int k0) {
    gl_lds16(&A[(size_t)(m0 + jr) * K + k0 + jc],       Ad + ldsb);
    gl_lds16(&Bt[(size_t)(n0 + jr) * K + k0 + jc],      Bd + ldsb);
    gl_lds16(&Bt[(size_t)(n0 + 64 + jr) * K + k0 + jc], Bd + 2048 + ldsb);
  };

  f32x4 acc[2][4] = {};
  stage(As0, Bs0, 0);
  int nk = K >> 5;
  for (int t = 0; t < nk; ++t) {
    short* Ab = (t & 1) ? As1 : As0;
    short* Bb = (t & 1) ? Bs1 : Bs0;
    if (t + 1 < nk) {
      stage((t & 1) ? As0 : As1, (t & 1) ? Bs0 : Bs1, (t + 1) << 5);
      asm volatile("s_waitcnt vmcnt(3)" ::: "memory");
    } else {
      asm volatile("s_waitcnt vmcnt(0)" ::: "memory");
    }
    __syncthreads();
    bf16x8 af[2], bfr[4];
    #pragma unroll
    for (int i = 0; i < 2; i++) af[i]  = *(bf16x8*)&Ab[(wm * 32 + i * 16 + l15) * 32 + lg * 8];
    #pragma unroll
    for (int j = 0; j < 4; j++) bfr[j] = *(bf16x8*)&Bb[(wn * 64 + j * 16 + l15) * 32 + lg * 8];
    #pragma unroll
    for (int i = 0; i < 2; i++)
      #pragma unroll
      for (int j = 0; j < 4; j++)
        acc[i][j] = MFMA16(af[i], bfr[j], acc[i][j]);
    __syncthreads();
  }

  #pragma unroll
  for (int i = 0; i < 2; i++)
    #pragma unroll
    for (int j = 0; j < 4; j++)
      #pragma unroll
      for (int r = 0; r < 4; r++) {
        int m = m0 + wm * 32 + i * 16 + lg * 4 + r;
        int n = n0 + wn * 64 + j * 16 + l15;
        float vv = acc[i][j][r] + bias[n];
        size_t idx = (size_t)m * N + n;
        float ov = vv + add[idx];
        if (EPI == 3) __builtin_nontemporal_store(ov, &outp[idx]);
        else          outp[idx] = ov;
      }
}

// ---------- 64x128 GEMM, BK=64 + XOR-swizzled LDS (fc1: EPI2 bf16-gelu; fc2: EPI3 f32+add) ----------
template <int EPI, int N>
__global__ __launch_bounds__(256) void gemm_n64k64(const short* __restrict__ A,
                                                   const short* __restrict__ Bt,
                                                   const float* __restrict__ bias,
                                                   const float* __restrict__ add,
                                                   void* __restrict__ outp,
                                                   int K) {
  __shared__ short S[24576];          // 49.2 KB
  short* As0 = S;                     // 64x64
  short* As1 = S + 4096;
  short* Bs0 = S + 8192;              // 128x64
  short* Bs1 = S + 16384;

  int nbx = gridDim.x;
  int flat = blockIdx.y * nbx + blockIdx.x;
  int cpx = (nbx * gridDim.y) >> 3;
  int swz = (flat & 7) * cpx + (flat >> 3);
  int m0 = (swz % nbx) * 64, n0 = (swz / nbx) * 128;

  int tid = threadIdx.x;
  int lane = tid & 63, wid = tid >> 6;
  int wm = wid & 1, wn = wid >> 1;
  int l15 = lane & 15, lg = lane >> 4;

  int r8 = tid >> 3;
  int gsl = (tid & 7) ^ (r8 & 7);
  int wb = wid << 9;

  auto stage = [&](short* Ad, short* Bd, int k0) {
    #pragma unroll
    for (int c = 0; c < 2; ++c)
      gl_lds16(&A[(size_t)(m0 + c * 32 + r8) * K + k0 + gsl * 8], Ad + c * 2048 + wb);
    #pragma unroll
    for (int c = 0; c < 4; ++c)
      gl_lds16(&Bt[(size_t)(n0 + c * 32 + r8) * K + k0 + gsl * 8], Bd + c * 2048 + wb);
  };

  f32x4 acc[2][4] = {};
  stage(As0, Bs0, 0);
  int nk = K >> 6;
  for (int t = 0; t < nk; ++t) {
    short* Ab = (t & 1) ? As1 : As0;
    short* Bb = (t & 1) ? Bs1 : Bs0;
    if (t + 1 < nk) {
      stage((t & 1) ? As0 : As1, (t & 1) ? Bs0 : Bs1, (t + 1) << 6);
      asm volatile("s_waitcnt vmcnt(6)" ::: "memory");
    } else {
      asm volatile("s_waitcnt vmcnt(0)" ::: "memory");
    }
    __syncthreads();
    bf16x8 af[2][2], bfr[4][2];
    #pragma unroll
    for (int i = 0; i < 2; i++) {
      int r = wm * 32 + i * 16 + l15;
      #pragma unroll
      for (int kk = 0; kk < 2; kk++)
        af[i][kk] = *(bf16x8*)&Ab[r * 64 + (((kk * 4 + lg) ^ (r & 7)) << 3)];
    }
    #pragma unroll
    for (int j = 0; j < 4; j++) {
      int r = wn * 64 + j * 16 + l15;
      #pragma unroll
      for (int kk = 0; kk < 2; kk++)
        bfr[j][kk] = *(bf16x8*)&Bb[r * 64 + (((kk * 4 + lg) ^ (r & 7)) << 3)];
    }
    #pragma unroll
    for (int kk = 0; kk < 2; kk++)
      #pragma unroll
      for (int i = 0; i < 2; i++)
        #pragma unroll
        for (int j = 0; j < 4; j++)
          acc[i][j] = MFMA16(af[i][kk], bfr[j][kk], acc[i][j]);
    __syncthreads();
  }

  if (EPI == 2) {
    // gelu -> bf16, LDS-staged coalesced stores (Cl[64][136], chunk-XOR)
    short (*Cl)[136] = (short (*)[136])S;
    #pragma unroll
    for (int i = 0; i < 2; i++)
      #pragma unroll
      for (int j = 0; j < 4; j++)
        #pragma unroll
        for (int r = 0; r < 4; r++) {
          int row = wm * 32 + i * 16 + lg * 4 + r;
          int col = wn * 64 + j * 16 + l15;
          float vv = gelu_exact(acc[i][j][r] + bias[n0 + col]);
          int ch = col >> 3, co = col & 7;
          Cl[row][((ch ^ (row & 7)) << 3) | co] = f2bf(vv);
        }
    __syncthreads();
    int row = tid >> 2;
    #pragma unroll
    for (int c = 0; c < 4; c++) {
      int ch = (tid & 3) + c * 4;
      bf16x8 v8 = *(bf16x8*)&Cl[row][(ch ^ (row & 7)) << 3];
      *(bf16x8*)&((short*)outp)[(size_t)(m0 + row) * N + n0 + (ch << 3)] = v8;
    }
  } else {
    #pragma unroll
    for (int i = 0; i < 2; i++)
      #pragma unroll
      for (int j = 0; j < 4; j++)
        #pragma unroll
        for (int r = 0; r < 4; r++) {
          int m = m0 + wm * 32 + i * 16 + lg * 4 + r;
          int n = n0 + wn * 64 + j * 16 + l15;
          float vv = acc[i][j][r] + bias[n];
          size_t idx = (size_t)m * N + n;
          float ov = vv + add[idx];
          __builtin_nontemporal_store(ov, &((float*)outp)[idx]);
        }
  }
}

// ---------- fused causal attention (bf16 P staging: 25.6 KB LDS -> 6 blocks/CU) ----------
__global__ __launch_bounds__(256) void attn_fused(const short* __restrict__ qkv,
                                                  const short* __restrict__ vt,
                                                  float* __restrict__ attw,
                                                  short* __restrict__ ctx) {
  __shared__ short VtL[2][4096];
  __shared__ short Pb[4][16][72];    // per-wave P (bf16), 9.2 KB
  int flat = blockIdx.y * 16 + blockIdx.x;
  int xcd = flat & 7, rr0 = flat >> 3;
  int bh   = xcd * 12 + (rr0 >> 4);
  int tile = 15 - (rr0 & 15);
  int q0 = tile * 64;
  int b = bh / Hh, h = bh % Hh;
  int tid = threadIdx.x, lane = tid & 63, wid = tid >> 6;
  int l15 = lane & 15, lg = lane >> 4;
  const short* base = qkv + (size_t)b * Tt * 2304;

  bf16x8 qa[2];
  {
    const short* qp = base + (size_t)(q0 + wid * 16 + l15) * 2304 + h * 64 + lg * 8;
    qa[0] = *(const bf16x8*)qp;
    qa[1] = *(const bf16x8*)(qp + 32);
  }

  // ---- pass 1: per-lane sumexp ----
  float l[4] = {0.f, 0.f, 0.f, 0.f};
  for (int kt = 0; kt <= tile; ++kt) {
    f32x4 acc[4] = {};
    #pragma unroll
    for (int nf = 0; nf < 4; ++nf) {
      const short* kp = base + (size_t)(kt * 64 + nf * 16 + l15) * 2304 + 768 + h * 64 + lg * 8;
      bf16x8 k0 = *(const bf16x8*)kp;
      bf16x8 k1 = *(const bf16x8*)(kp + 32);
      acc[nf] = MFMA16(qa[0], k0, acc[nf]);
      acc[nf] = MFMA16(qa[1], k1, acc[nf]);
    }
    #pragma unroll
    for (int r = 0; r < 4; r++) {
      int qg = q0 + wid * 16 + lg * 4 + r;
      #pragma unroll
      for (int nf = 0; nf < 4; nf++) {
        int kg = kt * 64 + nf * 16 + l15;
        l[r] += (kg <= qg) ? __expf(acc[nf][r] * 0.125f) : 0.f;
      }
    }
  }
  float rl[4];
  #pragma unroll
  for (int r = 0; r < 4; r++) {
    float s = l[r];
    #pragma unroll
    for (int off = 1; off < 16; off <<= 1) s += __shfl_xor(s, off);
    rl[r] = 1.f / s;
  }

  // ---- pass 2 ----
  const short* vtb = vt + (size_t)bh * 64 * Tt;
  int dS = wid * 16 + (lane >> 3);
  int cS = (lane & 7) ^ (lane >> 3);
  auto stageV = [&](int bi, int kt) {
    gl_lds16(&vtb[(size_t)dS * Tt + kt * 64 + cS * 8],       &VtL[bi][wid * 1024]);
    gl_lds16(&vtb[(size_t)(dS + 8) * Tt + kt * 64 + cS * 8], &VtL[bi][wid * 1024 + 512]);
  };

  f32x4 oacc[4] = {};
  stageV(0, 0);
  for (int kt = 0; kt <= tile; ++kt) {
    int cur = kt & 1;
    f32x4 acc[4] = {};
    #pragma unroll
    for (int nf = 0; nf < 4; nf++) {
      const short* kp = base + (size_t)(kt * 64 + nf * 16 + l15) * 2304 + 768 + h * 64 + lg * 8;
      bf16x8 k0 = *(const bf16x8*)kp;
      bf16x8 k1 = *(const bf16x8*)(kp + 32);
      acc[nf] = MFMA16(qa[0], k0, acc[nf]);
      acc[nf] = MFMA16(qa[1], k1, acc[nf]);
    }
    #pragma unroll
    for (int nf = 0; nf < 4; nf++) {
      #pragma unroll
      for (int r = 0; r < 4; r++) {
        int qg = q0 + wid * 16 + lg * 4 + r;
        int kg = kt * 64 + nf * 16 + l15;
        float p = (kg <= qg) ? __expf(acc[nf][r] * 0.125f) * rl[r] : 0.f;
        Pb[wid][lg * 4 + r][nf * 16 + l15] = f2bf(p);
      }
    }
    asm volatile("s_waitcnt lgkmcnt(0)" ::: "memory");
    __builtin_amdgcn_sched_barrier(0);
    // coalesced nt attw stores: 2 passes x (8 rows x 8 lanes x 32B)
    #pragma unroll
    for (int it = 0; it < 2; ++it) {
      int pr = it * 8 + (lane >> 3);
      int cb = (lane & 7) * 8;
      bf16x8 pv = *(bf16x8*)&Pb[wid][pr][cb];
      f32x4 lo, hi;
      #pragma unroll
      for (int j = 0; j < 4; j++) { lo[j] = bf2f(pv[j]); hi[j] = bf2f(pv[4 + j]); }
      float* dst = &attw[((size_t)bh * Tt + q0 + wid * 16 + pr) * Tt + kt * 64 + cb];
      __builtin_nontemporal_store(lo, (f32x4*)dst);
      __builtin_nontemporal_store(hi, (f32x4*)(dst + 4));
    }
    // P fragments direct from bf16 LDS
    bf16x8 pa0 = *(bf16x8*)&Pb[wid][l15][lg * 8];
    bf16x8 pa1 = *(bf16x8*)&Pb[wid][l15][lg * 8 + 32];
    asm volatile("s_waitcnt vmcnt(4)" ::: "memory");
    __builtin_amdgcn_s_barrier();
    __builtin_amdgcn_sched_barrier(0);
    if (kt < tile) stageV(cur ^ 1, kt + 1);
    #pragma unroll
    for (int nf = 0; nf < 4; nf++) {
      int dA = nf * 16 + l15;
      int sw = dA & 7;
      bf16x8 vb0 = *(bf16x8*)&VtL[cur][dA * 64 + ((lg ^ sw) << 3)];
      bf16x8 vb1 = *(bf16x8*)&VtL[cur][dA * 64 + (((4 + lg) ^ sw) << 3)];
      oacc[nf] = MFMA16(pa0, vb0, oacc[nf]);
      oacc[nf] = MFMA16(pa1, vb1, oacc[nf]);
    }
  }
  f32x4 z = {0.f, 0.f, 0.f, 0.f};
  for (int kt = tile + 1; kt < 16; ++kt) {
    #pragma unroll
    for (int it = 0; it < 4; ++it) {
      int pr = it * 4 + lg;
      __builtin_nontemporal_store(
          z, (f32x4*)&attw[((size_t)bh * Tt + q0 + wid * 16 + pr) * Tt + kt * 64 + l15 * 4]);
    }
  }
  #pragma unroll
  for (int nf = 0; nf < 4; nf++) {
    #pragma unroll
    for (int r = 0; r < 4; r++) {
      int t = q0 + wid * 16 + lg * 4 + r;
      ctx[((size_t)b * Tt + t) * Dd + h * 64 + nf * 16 + l15] = f2bf(oacc[nf][r]);
    }
  }
}

}  // namespace

extern "C" void kernel_launch(void* const* d_in, const int* in_sizes, int n_in,
                              void* d_out, int out_size, void* d_ws, size_t ws_size,
                              hipStream_t stream) {
  const float* x     = (const float*)d_in[0];
  const float* ln1g  = (const float*)d_in[1];
  const float* ln1b  = (const float*)d_in[2];
  const float* w_qkv = (const float*)d_in[3];
  const float* b_qkv = (const float*)d_in[4];
  const float* w_out = (const float*)d_in[5];
  const float* b_out = (const float*)d_in[6];
  const float* ln2g  = (const float*)d_in[7];
  const float* ln2b  = (const float*)d_in[8];
  const float* w_fc1 = (const float*)d_in[9];
  const float* b_fc1 = (const float*)d_in[10];
  const float* w_fc2 = (const float*)d_in[11];
  const float* b_fc2 = (const float*)d_in[12];

  char* ws = (char*)d_ws;
  size_t o = 0;
  short* wqkvT = (short*)(ws + o); o += (size_t)2304 * 768 * 2;
  short* woutT = (short*)(ws + o); o += (size_t)768 * 768 * 2;
  short* wfc1T = (short*)(ws + o); o += (size_t)3072 * 768 * 2;
  short* wfc2T = (short*)(ws + o); o += (size_t)768 * 3072 * 2;
  short* h     = (short*)(ws + o); o += (size_t)BT * Dd * 2;
  short* qkv   = (short*)(ws + o); o += (size_t)BT * 2304 * 2;
  float* y1    = (float*)(ws + o); o += (size_t)BT * Dd * 4;
  short* h2    = (short*)(ws + o); o += (size_t)BT * Dd * 2;
  short* vt    = (short*)(ws + o); o += (size_t)96 * 64 * Tt * 2;
  short* ctx  = h;     // reuse: h dead after QKV GEMM
  short* gbuf = h;     // reuse: h+qkv for GELU output (attw fully written before fc1)

  float* out_x = (float*)d_out;
  float* attw  = out_x + (size_t)BT * Dd;

  prep<<<8960, 256, 0, stream>>>(w_qkv, wqkvT, w_out, woutT, w_fc1, wfc1T,
                                 w_fc2, wfc2T, x, ln1g, ln1b, h);
  gemm_bt<0, 2304, true><<<dim3(BT / 128, 2304 / 128), 256, 0, stream>>>(
      h, wqkvT, b_qkv, nullptr, qkv, 768, vt);
  attn_fused<<<dim3(16, 96), 256, 0, stream>>>(qkv, vt, attw, ctx);
  gemm_n64<1><<<dim3(BT / 64, 768 / 128), 256, 0, stream>>>(ctx, woutT, b_out, x, y1, 768);
  ln_rows<<<BT / 4, 256, 0, stream>>>(y1, ln2g, ln2b, h2);
  gemm_n64k64<2, DFF><<<dim3(BT / 64, DFF / 128), 256, 0, stream>>>(
      h2, wfc1T, b_fc1, nullptr, gbuf, 768);
  gemm_n64k64<3, 768><<<dim3(BT / 64, 768 / 128), 256, 0, stream>>>(
      gbuf, wfc2T, b_fc2, y1, out_x, 3072);
}

// Round 18
// 412.934 us; speedup vs baseline: 1.0009x; 1.0009x over previous
//
#include <hip/hip_runtime.h>
#include <cstdint>
#include <cstddef>

namespace {

constexpr int Bb  = 8;
constexpr int Tt  = 1024;
constexpr int Dd  = 768;
constexpr int Hh  = 12;
constexpr int DFF = 3072;
constexpr int BT  = Bb * Tt;

typedef __attribute__((ext_vector_type(8))) short bf16x8;
typedef __attribute__((ext_vector_type(4))) short bf16x4;
typedef __attribute__((ext_vector_type(4))) float f32x4;

__device__ __forceinline__ short f2bf(float f) {
  union { float f; unsigned u; } v; v.f = f;
  unsigned r = v.u + 0x7fffu + ((v.u >> 16) & 1u);   // RNE
  return (short)(r >> 16);
}
__device__ __forceinline__ float bf2f(short s) {
  union { unsigned u; float f; } v;
  v.u = ((unsigned)(unsigned short)s) << 16;
  return v.f;
}
__device__ __forceinline__ float gelu_exact(float v) {
  return 0.5f * v * (1.0f + erff(v * 0.70710678118654752f));
}

#define MFMA16(a, b, c) __builtin_amdgcn_mfma_f32_16x16x32_bf16(a, b, c, 0, 0, 0)

__device__ __forceinline__ void gl_lds16(const short* g, short* l) {
  __builtin_amdgcn_global_load_lds(
      (const __attribute__((address_space(1))) unsigned int*)(g),
      (__attribute__((address_space(3))) unsigned int*)(l), 16, 0, 0);
}

// ---------- weight convert+transpose body ----------
__device__ __forceinline__ void cvt_body(float (*tile)[33],
                                         const float* __restrict__ in,
                                         short* __restrict__ out,
                                         int K, int N, int bx, int by) {
  int k0 = bx * 32, n0 = by * 32;
  int tx = threadIdx.x & 31, ty = threadIdx.x >> 5;
  #pragma unroll
  for (int r = ty; r < 32; r += 8)
    tile[r][tx] = in[(size_t)(k0 + r) * N + n0 + tx];
  __syncthreads();
  #pragma unroll
  for (int r = ty; r < 32; r += 8)
    out[(size_t)(n0 + r) * K + k0 + tx] = f2bf(tile[tx][r]);
}

// ---------- LayerNorm body ----------
__device__ __forceinline__ void ln_body(const float* __restrict__ x,
                                        const float* __restrict__ g,
                                        const float* __restrict__ b,
                                        short* __restrict__ out, int blkrow) {
  int lane = threadIdx.x & 63, wid = threadIdx.x >> 6;
  int row = blkrow * 4 + wid;
  const float* xr = x + (size_t)row * Dd;
  float v[12];
  float s = 0.f, ss = 0.f;
  #pragma unroll
  for (int c = 0; c < 3; c++) {
    float4 t = *(const float4*)&xr[c * 256 + lane * 4];
    v[c * 4 + 0] = t.x; v[c * 4 + 1] = t.y; v[c * 4 + 2] = t.z; v[c * 4 + 3] = t.w;
    s  += t.x + t.y + t.z + t.w;
    ss += t.x * t.x + t.y * t.y + t.z * t.z + t.w * t.w;
  }
  #pragma unroll
  for (int off = 1; off < 64; off <<= 1) {
    s += __shfl_xor(s, off); ss += __shfl_xor(ss, off);
  }
  float mu   = s * (1.f / Dd);
  float var  = ss * (1.f / Dd) - mu * mu;
  float rstd = rsqrtf(var + 1e-5f);
  #pragma unroll
  for (int c = 0; c < 3; c++) {
    bf16x4 o;
    #pragma unroll
    for (int j = 0; j < 4; j++) {
      int d = c * 256 + lane * 4 + j;
      o[j] = f2bf((v[c * 4 + j] - mu) * rstd * g[d] + b[d]);
    }
    *(bf16x4*)&out[(size_t)row * Dd + c * 256 + lane * 4] = o;
  }
}

// ---------- prep: 4 weight-converts + LN1 ----------
__global__ __launch_bounds__(256) void prep(const float* __restrict__ w_qkv, short* wqkvT,
                                            const float* __restrict__ w_out, short* woutT,
                                            const float* __restrict__ w_fc1, short* wfc1T,
                                            const float* __restrict__ w_fc2, short* wfc2T,
                                            const float* __restrict__ x,
                                            const float* __restrict__ g,
                                            const float* __restrict__ b,
                                            short* __restrict__ h) {
  __shared__ float tile[32][33];
  int j = blockIdx.x;
  if (j < 1728)      cvt_body(tile, w_qkv, wqkvT, 768, 2304, j % 24, j / 24);
  else if (j < 2304) { int t = j - 1728; cvt_body(tile, w_out, woutT, 768, 768, t % 24, t / 24); }
  else if (j < 4608) { int t = j - 2304; cvt_body(tile, w_fc1, wfc1T, 768, 3072, t % 24, t / 24); }
  else if (j < 6912) { int t = j - 4608; cvt_body(tile, w_fc2, wfc2T, 3072, 768, t % 96, t / 96); }
  else               ln_body(x, g, b, h, j - 6912);
}

// ---------- standalone LayerNorm (LN2) ----------
__global__ __launch_bounds__(256) void ln_rows(const float* __restrict__ x,
                                               const float* __restrict__ g,
                                               const float* __restrict__ b,
                                               short* __restrict__ out) {
  ln_body(x, g, b, out, blockIdx.x);
}

// ---------- 128x128 GEMM (QKV w/ VTR; fc1 EPI2) ----------
template <int EPI, int N, bool VTR>
__global__ __launch_bounds__(256) void gemm_bt(const short* __restrict__ A,
                                               const short* __restrict__ Bt,
                                               const float* __restrict__ bias,
                                               const float* __restrict__ add,
                                               void* __restrict__ outp,
                                               int K,
                                               short* __restrict__ vt) {
  __shared__ short S[17408];
  short* As0 = S;
  short* As1 = S + 4096;
  short* Bs0 = S + 8192;
  short* Bs1 = S + 12288;

  int nbx = gridDim.x;
  int flat = blockIdx.y * nbx + blockIdx.x;
  int cpx = (nbx * gridDim.y) >> 3;
  int swz = (flat & 7) * cpx + (flat >> 3);
  int m0 = (swz % nbx) * 128, n0 = (swz / nbx) * 128;

  int tid = threadIdx.x;
  int lane = tid & 63, wid = tid >> 6;
  int wm = wid >> 1, wn = wid & 1;
  int l15 = lane & 15, lg = lane >> 4;

  int jr = tid >> 2, jc = (tid & 3) << 3;
  int ldsb = wid << 9;

  auto stage = [&](short* Ad, short* Bd, int k0) {
    gl_lds16(&A[(size_t)(m0 + jr) * K + k0 + jc],       Ad + ldsb);
    gl_lds16(&A[(size_t)(m0 + 64 + jr) * K + k0 + jc],  Ad + 2048 + ldsb);
    gl_lds16(&Bt[(size_t)(n0 + jr) * K + k0 + jc],      Bd + ldsb);
    gl_lds16(&Bt[(size_t)(n0 + 64 + jr) * K + k0 + jc], Bd + 2048 + ldsb);
  };

  f32x4 acc[4][4] = {};
  stage(As0, Bs0, 0);
  int nk = K >> 5;
  for (int t = 0; t < nk; ++t) {
    short* Ab = (t & 1) ? As1 : As0;
    short* Bb = (t & 1) ? Bs1 : Bs0;
    if (t + 1 < nk) {
      stage((t & 1) ? As0 : As1, (t & 1) ? Bs0 : Bs1, (t + 1) << 5);
      asm volatile("s_waitcnt vmcnt(4)" ::: "memory");
    } else {
      asm volatile("s_waitcnt vmcnt(0)" ::: "memory");
    }
    __syncthreads();
    bf16x8 af[4], bfr[4];
    #pragma unroll
    for (int i = 0; i < 4; i++) af[i]  = *(bf16x8*)&Ab[(wm * 64 + i * 16 + l15) * 32 + lg * 8];
    #pragma unroll
    for (int j = 0; j < 4; j++) bfr[j] = *(bf16x8*)&Bb[(wn * 64 + j * 16 + l15) * 32 + lg * 8];
    #pragma unroll
    for (int i = 0; i < 4; i++)
      #pragma unroll
      for (int j = 0; j < 4; j++)
        acc[i][j] = MFMA16(af[i], bfr[j], acc[i][j]);
    __syncthreads();
  }

  if (EPI == 0 || EPI == 2) {
    short (*Cl)[136] = (short (*)[136])S;
    #pragma unroll
    for (int i = 0; i < 4; i++)
      #pragma unroll
      for (int j = 0; j < 4; j++)
        #pragma unroll
        for (int r = 0; r < 4; r++) {
          int row = wm * 64 + i * 16 + lg * 4 + r;
          int col = wn * 64 + j * 16 + l15;
          float vv = acc[i][j][r] + bias[n0 + col];
          if (EPI == 2) vv = gelu_exact(vv);
          int ch = col >> 3, co = col & 7;
          Cl[row][((ch ^ (row & 7)) << 3) | co] = f2bf(vv);
        }
    __syncthreads();
    if (VTR && n0 >= 1536) {
      int b = m0 >> 10, tbase = m0 & 1023;
      int h0 = (n0 - 1536) >> 6;
      #pragma unroll
      for (int half = 0; half < 2; ++half) {
        int c = (tid >> 2) + half * 64;
        int hh = c >> 6, d = c & 63;
        short* dst = vt + ((size_t)((b * Hh + h0 + hh) * 64 + d)) * Tt
                        + tbase + (tid & 3) * 32;
        #pragma unroll
        for (int j = 0; j < 4; ++j) {
          bf16x8 v8;
          #pragma unroll
          for (int k = 0; k < 8; ++k) {
            int t = (tid & 3) * 32 + j * 8 + k;
            v8[k] = Cl[t][(((c >> 3) ^ (t & 7)) << 3) | (c & 7)];
          }
          *(bf16x8*)(dst + j * 8) = v8;
        }
      }
    } else {
      int row = tid >> 1;
      int cb = (tid & 1) * 8;
      #pragma unroll
      for (int c = 0; c < 8; c++) {
        int ch = cb + c;
        bf16x8 v8 = *(bf16x8*)&Cl[row][(ch ^ (row & 7)) << 3];
        *(bf16x8*)&((short*)outp)[(size_t)(m0 + row) * N + n0 + (ch << 3)] = v8;
      }
    }
  } else {
    #pragma unroll
    for (int i = 0; i < 4; i++)
      #pragma unroll
      for (int j = 0; j < 4; j++)
        #pragma unroll
        for (int r = 0; r < 4; r++) {
          int m = m0 + wm * 64 + i * 16 + lg * 4 + r;
          int n = n0 + wn * 64 + j * 16 + l15;
          float vv = acc[i][j][r] + bias[n];
          size_t idx = (size_t)m * N + n;
          float ov = vv + add[idx];
          if (EPI == 3) __builtin_nontemporal_store(ov, &((float*)outp)[idx]);
          else          ((float*)outp)[idx] = ov;
        }
  }
}

// ---------- 64x128 GEMM, BK=32 (out-proj) ----------
template <int EPI>
__global__ __launch_bounds__(256) void gemm_n64(const short* __restrict__ A,
                                                const short* __restrict__ Bt,
                                                const float* __restrict__ bias,
                                                const float* __restrict__ add,
                                                float* __restrict__ outp,
                                                int K) {
  constexpr int N = 768;
  __shared__ short S[12288];
  short* As0 = S;
  short* As1 = S + 2048;
  short* Bs0 = S + 4096;
  short* Bs1 = S + 8192;

  int nbx = gridDim.x;
  int flat = blockIdx.y * nbx + blockIdx.x;
  int cpx = (nbx * gridDim.y) >> 3;
  int swz = (flat & 7) * cpx + (flat >> 3);
  int m0 = (swz % nbx) * 64, n0 = (swz / nbx) * 128;

  int tid = threadIdx.x;
  int lane = tid & 63, wid = tid >> 6;
  int wm = wid & 1, wn = wid >> 1;
  int l15 = lane & 15, lg = lane >> 4;

  int jr = tid >> 2, jc = (tid & 3) << 3;
  int ldsb = wid << 9;

  auto stage = [&](short* Ad, short* Bd, int k0) {
    gl_lds16(&A[(size_t)(m0 + jr) * K + k0 + jc],       Ad + ldsb);
    gl_lds16(&Bt[(size_t)(n0 + jr) * K + k0 + jc],      Bd + ldsb);
    gl_lds16(&Bt[(size_t)(n0 + 64 + jr) * K + k0 + jc], Bd + 2048 + ldsb);
  };

  f32x4 acc[2][4] = {};
  stage(As0, Bs0, 0);
  int nk = K >> 5;
  for (int t = 0; t < nk; ++t) {
    short* Ab = (t & 1) ? As1 : As0;
    short* Bb = (t & 1) ? Bs1 : Bs0;
    if (t + 1 < nk) {
      stage((t & 1) ? As0 : As1, (t & 1) ? Bs0 : Bs1, (t + 1) << 5);
      asm volatile("s_waitcnt vmcnt(3)" ::: "memory");
    } else {
      asm volatile("s_waitcnt vmcnt(0)" ::: "memory");
    }
    __syncthreads();
    bf16x8 af[2], bfr[4];
    #pragma unroll
    for (int i = 0; i < 2; i++) af[i]  = *(bf16x8*)&Ab[(wm * 32 + i * 16 + l15) * 32 + lg * 8];
    #pragma unroll
    for (int j = 0; j < 4; j++) bfr[j] = *(bf16x8*)&Bb[(wn * 64 + j * 16 + l15) * 32 + lg * 8];
    #pragma unroll
    for (int i = 0; i < 2; i++)
      #pragma unroll
      for (int j = 0; j < 4; j++)
        acc[i][j] = MFMA16(af[i], bfr[j], acc[i][j]);
    __syncthreads();
  }

  #pragma unroll
  for (int i = 0; i < 2; i++)
    #pragma unroll
    for (int j = 0; j < 4; j++)
      #pragma unroll
      for (int r = 0; r < 4; r++) {
        int m = m0 + wm * 32 + i * 16 + lg * 4 + r;
        int n = n0 + wn * 64 + j * 16 + l15;
        float vv = acc[i][j][r] + bias[n];
        size_t idx = (size_t)m * N + n;
        float ov = vv + add[idx];
        if (EPI == 3) __builtin_nontemporal_store(ov, &outp[idx]);
        else          outp[idx] = ov;
      }
}

// ---------- 64x128 GEMM, BK=64 + XOR-swizzled LDS (fc2 only: EPI3 f32+add) ----------
template <int EPI, int N>
__global__ __launch_bounds__(256) void gemm_n64k64(const short* __restrict__ A,
                                                   const short* __restrict__ Bt,
                                                   const float* __restrict__ bias,
                                                   const float* __restrict__ add,
                                                   void* __restrict__ outp,
                                                   int K) {
  __shared__ short S[24576];          // 49.2 KB
  short* As0 = S;
  short* As1 = S + 4096;
  short* Bs0 = S + 8192;
  short* Bs1 = S + 16384;

  int nbx = gridDim.x;
  int flat = blockIdx.y * nbx + blockIdx.x;
  int cpx = (nbx * gridDim.y) >> 3;
  int swz = (flat & 7) * cpx + (flat >> 3);
  int m0 = (swz % nbx) * 64, n0 = (swz / nbx) * 128;

  int tid = threadIdx.x;
  int lane = tid & 63, wid = tid >> 6;
  int wm = wid & 1, wn = wid >> 1;
  int l15 = lane & 15, lg = lane >> 4;

  int r8 = tid >> 3;
  int gsl = (tid & 7) ^ (r8 & 7);
  int wb = wid << 9;

  auto stage = [&](short* Ad, short* Bd, int k0) {
    #pragma unroll
    for (int c = 0; c < 2; ++c)
      gl_lds16(&A[(size_t)(m0 + c * 32 + r8) * K + k0 + gsl * 8], Ad + c * 2048 + wb);
    #pragma unroll
    for (int c = 0; c < 4; ++c)
      gl_lds16(&Bt[(size_t)(n0 + c * 32 + r8) * K + k0 + gsl * 8], Bd + c * 2048 + wb);
  };

  f32x4 acc[2][4] = {};
  stage(As0, Bs0, 0);
  int nk = K >> 6;
  for (int t = 0; t < nk; ++t) {
    short* Ab = (t & 1) ? As1 : As0;
    short* Bb = (t & 1) ? Bs1 : Bs0;
    if (t + 1 < nk) {
      stage((t & 1) ? As0 : As1, (t & 1) ? Bs0 : Bs1, (t + 1) << 6);
      asm volatile("s_waitcnt vmcnt(6)" ::: "memory");
    } else {
      asm volatile("s_waitcnt vmcnt(0)" ::: "memory");
    }
    __syncthreads();
    bf16x8 af[2][2], bfr[4][2];
    #pragma unroll
    for (int i = 0; i < 2; i++) {
      int r = wm * 32 + i * 16 + l15;
      #pragma unroll
      for (int kk = 0; kk < 2; kk++)
        af[i][kk] = *(bf16x8*)&Ab[r * 64 + (((kk * 4 + lg) ^ (r & 7)) << 3)];
    }
    #pragma unroll
    for (int j = 0; j < 4; j++) {
      int r = wn * 64 + j * 16 + l15;
      #pragma unroll
      for (int kk = 0; kk < 2; kk++)
        bfr[j][kk] = *(bf16x8*)&Bb[r * 64 + (((kk * 4 + lg) ^ (r & 7)) << 3)];
    }
    #pragma unroll
    for (int kk = 0; kk < 2; kk++)
      #pragma unroll
      for (int i = 0; i < 2; i++)
        #pragma unroll
        for (int j = 0; j < 4; j++)
          acc[i][j] = MFMA16(af[i][kk], bfr[j][kk], acc[i][j]);
    __syncthreads();
  }

  #pragma unroll
  for (int i = 0; i < 2; i++)
    #pragma unroll
    for (int j = 0; j < 4; j++)
      #pragma unroll
      for (int r = 0; r < 4; r++) {
        int m = m0 + wm * 32 + i * 16 + lg * 4 + r;
        int n = n0 + wn * 64 + j * 16 + l15;
        float vv = acc[i][j][r] + bias[n];
        size_t idx = (size_t)m * N + n;
        float ov = vv + add[idx];
        __builtin_nontemporal_store(ov, &((float*)outp)[idx]);
      }
}

// ---------- fused causal attention (bf16 P staging; R16) ----------
__global__ __launch_bounds__(256) void attn_fused(const short* __restrict__ qkv,
                                                  const short* __restrict__ vt,
                                                  float* __restrict__ attw,
                                                  short* __restrict__ ctx) {
  __shared__ short VtL[2][4096];
  __shared__ short Pb[4][16][72];
  int flat = blockIdx.y * 16 + blockIdx.x;
  int xcd = flat & 7, rr0 = flat >> 3;
  int bh   = xcd * 12 + (rr0 >> 4);
  int tile = 15 - (rr0 & 15);
  int q0 = tile * 64;
  int b = bh / Hh, h = bh % Hh;
  int tid = threadIdx.x, lane = tid & 63, wid = tid >> 6;
  int l15 = lane & 15, lg = lane >> 4;
  const short* base = qkv + (size_t)b * Tt * 2304;

  bf16x8 qa[2];
  {
    const short* qp = base + (size_t)(q0 + wid * 16 + l15) * 2304 + h * 64 + lg * 8;
    qa[0] = *(const bf16x8*)qp;
    qa[1] = *(const bf16x8*)(qp + 32);
  }

  float l[4] = {0.f, 0.f, 0.f, 0.f};
  for (int kt = 0; kt <= tile; ++kt) {
    f32x4 acc[4] = {};
    #pragma unroll
    for (int nf = 0; nf < 4; ++nf) {
      const short* kp = base + (size_t)(kt * 64 + nf * 16 + l15) * 2304 + 768 + h * 64 + lg * 8;
      bf16x8 k0 = *(const bf16x8*)kp;
      bf16x8 k1 = *(const bf16x8*)(kp + 32);
      acc[nf] = MFMA16(qa[0], k0, acc[nf]);
      acc[nf] = MFMA16(qa[1], k1, acc[nf]);
    }
    #pragma unroll
    for (int r = 0; r < 4; r++) {
      int qg = q0 + wid * 16 + lg * 4 + r;
      #pragma unroll
      for (int nf = 0; nf < 4; nf++) {
        int kg = kt * 64 + nf * 16 + l15;
        l[r] += (kg <= qg) ? __expf(acc[nf][r] * 0.125f) : 0.f;
      }
    }
  }
  float rl[4];
  #pragma unroll
  for (int r = 0; r < 4; r++) {
    float s = l[r];
    #pragma unroll
    for (int off = 1; off < 16; off <<= 1) s += __shfl_xor(s, off);
    rl[r] = 1.f / s;
  }

  const short* vtb = vt + (size_t)bh * 64 * Tt;
  int dS = wid * 16 + (lane >> 3);
  int cS = (lane & 7) ^ (lane >> 3);
  auto stageV = [&](int bi, int kt) {
    gl_lds16(&vtb[(size_t)dS * Tt + kt * 64 + cS * 8],       &VtL[bi][wid * 1024]);
    gl_lds16(&vtb[(size_t)(dS + 8) * Tt + kt * 64 + cS * 8], &VtL[bi][wid * 1024 + 512]);
  };

  f32x4 oacc[4] = {};
  stageV(0, 0);
  for (int kt = 0; kt <= tile; ++kt) {
    int cur = kt & 1;
    f32x4 acc[4] = {};
    #pragma unroll
    for (int nf = 0; nf < 4; nf++) {
      const short* kp = base + (size_t)(kt * 64 + nf * 16 + l15) * 2304 + 768 + h * 64 + lg * 8;
      bf16x8 k0 = *(const bf16x8*)kp;
      bf16x8 k1 = *(const bf16x8*)(kp + 32);
      acc[nf] = MFMA16(qa[0], k0, acc[nf]);
      acc[nf] = MFMA16(qa[1], k1, acc[nf]);
    }
    #pragma unroll
    for (int nf = 0; nf < 4; nf++) {
      #pragma unroll
      for (int r = 0; r < 4; r++) {
        int qg = q0 + wid * 16 + lg * 4 + r;
        int kg = kt * 64 + nf * 16 + l15;
        float p = (kg <= qg) ? __expf(acc[nf][r] * 0.125f) * rl[r] : 0.f;
        Pb[wid][lg * 4 + r][nf * 16 + l15] = f2bf(p);
      }
    }
    asm volatile("s_waitcnt lgkmcnt(0)" ::: "memory");
    __builtin_amdgcn_sched_barrier(0);
    #pragma unroll
    for (int it = 0; it < 2; ++it) {
      int pr = it * 8 + (lane >> 3);
      int cb = (lane & 7) * 8;
      bf16x8 pv = *(bf16x8*)&Pb[wid][pr][cb];
      f32x4 lo, hi;
      #pragma unroll
      for (int j = 0; j < 4; j++) { lo[j] = bf2f(pv[j]); hi[j] = bf2f(pv[4 + j]); }
      float* dst = &attw[((size_t)bh * Tt + q0 + wid * 16 + pr) * Tt + kt * 64 + cb];
      __builtin_nontemporal_store(lo, (f32x4*)dst);
      __builtin_nontemporal_store(hi, (f32x4*)(dst + 4));
    }
    bf16x8 pa0 = *(bf16x8*)&Pb[wid][l15][lg * 8];
    bf16x8 pa1 = *(bf16x8*)&Pb[wid][l15][lg * 8 + 32];
    asm volatile("s_waitcnt vmcnt(4)" ::: "memory");
    __builtin_amdgcn_s_barrier();
    __builtin_amdgcn_sched_barrier(0);
    if (kt < tile) stageV(cur ^ 1, kt + 1);
    #pragma unroll
    for (int nf = 0; nf < 4; nf++) {
      int dA = nf * 16 + l15;
      int sw = dA & 7;
      bf16x8 vb0 = *(bf16x8*)&VtL[cur][dA * 64 + ((lg ^ sw) << 3)];
      bf16x8 vb1 = *(bf16x8*)&VtL[cur][dA * 64 + (((4 + lg) ^ sw) << 3)];
      oacc[nf] = MFMA16(pa0, vb0, oacc[nf]);
      oacc[nf] = MFMA16(pa1, vb1, oacc[nf]);
    }
  }
  f32x4 z = {0.f, 0.f, 0.f, 0.f};
  for (int kt = tile + 1; kt < 16; ++kt) {
    #pragma unroll
    for (int it = 0; it < 4; ++it) {
      int pr = it * 4 + lg;
      __builtin_nontemporal_store(
          z, (f32x4*)&attw[((size_t)bh * Tt + q0 + wid * 16 + pr) * Tt + kt * 64 + l15 * 4]);
    }
  }
  #pragma unroll
  for (int nf = 0; nf < 4; nf++) {
    #pragma unroll
    for (int r = 0; r < 4; r++) {
      int t = q0 + wid * 16 + lg * 4 + r;
      ctx[((size_t)b * Tt + t) * Dd + h * 64 + nf * 16 + l15] = f2bf(oacc[nf][r]);
    }
  }
}

}  // namespace

extern "C" void kernel_launch(void* const* d_in, const int* in_sizes, int n_in,
                              void* d_out, int out_size, void* d_ws, size_t ws_size,
                              hipStream_t stream) {
  const float* x     = (const float*)d_in[0];
  const float* ln1g  = (const float*)d_in[1];
  const float* ln1b  = (const float*)d_in[2];
  const float* w_qkv = (const float*)d_in[3];
  const float* b_qkv = (const float*)d_in[4];
  const float* w_out = (const float*)d_in[5];
  const float* b_out = (const float*)d_in[6];
  const float* ln2g  = (const float*)d_in[7];
  const float* ln2b  = (const float*)d_in[8];
  const float* w_fc1 = (const float*)d_in[9];
  const float* b_fc1 = (const float*)d_in[10];
  const float* w_fc2 = (const float*)d_in[11];
  const float* b_fc2 = (const float*)d_in[12];

  char* ws = (char*)d_ws;
  size_t o = 0;
  short* wqkvT = (short*)(ws + o); o += (size_t)2304 * 768 * 2;
  short* woutT = (short*)(ws + o); o += (size_t)768 * 768 * 2;
  short* wfc1T = (short*)(ws + o); o += (size_t)3072 * 768 * 2;
  short* wfc2T = (short*)(ws + o); o += (size_t)768 * 3072 * 2;
  short* h     = (short*)(ws + o); o += (size_t)BT * Dd * 2;
  short* qkv   = (short*)(ws + o); o += (size_t)BT * 2304 * 2;
  float* y1    = (float*)(ws + o); o += (size_t)BT * Dd * 4;
  short* h2    = (short*)(ws + o); o += (size_t)BT * Dd * 2;
  short* vt    = (short*)(ws + o); o += (size_t)96 * 64 * Tt * 2;
  short* ctx  = h;     // reuse: h dead after QKV GEMM
  short* gbuf = h;     // reuse: h+qkv for GELU output (attw fully written before fc1)

  float* out_x = (float*)d_out;
  float* attw  = out_x + (size_t)BT * Dd;

  prep<<<8960, 256, 0, stream>>>(w_qkv, wqkvT, w_out, woutT, w_fc1, wfc1T,
                                 w_fc2, wfc2T, x, ln1g, ln1b, h);
  gemm_bt<0, 2304, true><<<dim3(BT / 128, 2304 / 128), 256, 0, stream>>>(
      h, wqkvT, b_qkv, nullptr, qkv, 768, vt);
  attn_fused<<<dim3(16, 96), 256, 0, stream>>>(qkv, vt, attw, ctx);
  gemm_n64<1><<<dim3(BT / 64, 768 / 128), 256, 0, stream>>>(ctx, woutT, b_out, x, y1, 768);
  ln_rows<<<BT / 4, 256, 0, stream>>>(y1, ln2g, ln2b, h2);
  gemm_bt<2, 3072, false><<<dim3(BT / 128, 3072 / 128), 256, 0, stream>>>(
      h2, wfc1T, b_fc1, nullptr, gbuf, 768, nullptr);
  gemm_n64k64<3, 768><<<dim3(BT / 64, 768 / 128), 256, 0, stream>>>(
      gbuf, wfc2T, b_fc2, y1, out_x, 3072);
}

// Round 19
// 404.642 us; speedup vs baseline: 1.0214x; 1.0205x over previous
//
#include <hip/hip_runtime.h>
#include <cstdint>
#include <cstddef>

namespace {

constexpr int Bb  = 8;
constexpr int Tt  = 1024;
constexpr int Dd  = 768;
constexpr int Hh  = 12;
constexpr int DFF = 3072;
constexpr int BT  = Bb * Tt;

typedef __attribute__((ext_vector_type(8))) short bf16x8;
typedef __attribute__((ext_vector_type(4))) short bf16x4;
typedef __attribute__((ext_vector_type(4))) float f32x4;

__device__ __forceinline__ short f2bf(float f) {
  union { float f; unsigned u; } v; v.f = f;
  unsigned r = v.u + 0x7fffu + ((v.u >> 16) & 1u);   // RNE
  return (short)(r >> 16);
}
__device__ __forceinline__ float gelu_exact(float v) {
  return 0.5f * v * (1.0f + erff(v * 0.70710678118654752f));
}

#define MFMA16(a, b, c) __builtin_amdgcn_mfma_f32_16x16x32_bf16(a, b, c, 0, 0, 0)

__device__ __forceinline__ void gl_lds16(const short* g, short* l) {
  __builtin_amdgcn_global_load_lds(
      (const __attribute__((address_space(1))) unsigned int*)(g),
      (__attribute__((address_space(3))) unsigned int*)(l), 16, 0, 0);
}

// ---------- weight convert+transpose body ----------
__device__ __forceinline__ void cvt_body(float (*tile)[33],
                                         const float* __restrict__ in,
                                         short* __restrict__ out,
                                         int K, int N, int bx, int by) {
  int k0 = bx * 32, n0 = by * 32;
  int tx = threadIdx.x & 31, ty = threadIdx.x >> 5;
  #pragma unroll
  for (int r = ty; r < 32; r += 8)
    tile[r][tx] = in[(size_t)(k0 + r) * N + n0 + tx];
  __syncthreads();
  #pragma unroll
  for (int r = ty; r < 32; r += 8)
    out[(size_t)(n0 + r) * K + k0 + tx] = f2bf(tile[tx][r]);
}

// ---------- LayerNorm body ----------
__device__ __forceinline__ void ln_body(const float* __restrict__ x,
                                        const float* __restrict__ g,
                                        const float* __restrict__ b,
                                        short* __restrict__ out, int blkrow) {
  int lane = threadIdx.x & 63, wid = threadIdx.x >> 6;
  int row = blkrow * 4 + wid;
  const float* xr = x + (size_t)row * Dd;
  float v[12];
  float s = 0.f, ss = 0.f;
  #pragma unroll
  for (int c = 0; c < 3; c++) {
    float4 t = *(const float4*)&xr[c * 256 + lane * 4];
    v[c * 4 + 0] = t.x; v[c * 4 + 1] = t.y; v[c * 4 + 2] = t.z; v[c * 4 + 3] = t.w;
    s  += t.x + t.y + t.z + t.w;
    ss += t.x * t.x + t.y * t.y + t.z * t.z + t.w * t.w;
  }
  #pragma unroll
  for (int off = 1; off < 64; off <<= 1) {
    s += __shfl_xor(s, off); ss += __shfl_xor(ss, off);
  }
  float mu   = s * (1.f / Dd);
  float var  = ss * (1.f / Dd) - mu * mu;
  float rstd = rsqrtf(var + 1e-5f);
  #pragma unroll
  for (int c = 0; c < 3; c++) {
    bf16x4 o;
    #pragma unroll
    for (int j = 0; j < 4; j++) {
      int d = c * 256 + lane * 4 + j;
      o[j] = f2bf((v[c * 4 + j] - mu) * rstd * g[d] + b[d]);
    }
    *(bf16x4*)&out[(size_t)row * Dd + c * 256 + lane * 4] = o;
  }
}

// ---------- prep: 4 weight-converts + LN1 ----------
__global__ __launch_bounds__(256) void prep(const float* __restrict__ w_qkv, short* wqkvT,
                                            const float* __restrict__ w_out, short* woutT,
                                            const float* __restrict__ w_fc1, short* wfc1T,
                                            const float* __restrict__ w_fc2, short* wfc2T,
                                            const float* __restrict__ x,
                                            const float* __restrict__ g,
                                            const float* __restrict__ b,
                                            short* __restrict__ h) {
  __shared__ float tile[32][33];
  int j = blockIdx.x;
  if (j < 1728)      cvt_body(tile, w_qkv, wqkvT, 768, 2304, j % 24, j / 24);
  else if (j < 2304) { int t = j - 1728; cvt_body(tile, w_out, woutT, 768, 768, t % 24, t / 24); }
  else if (j < 4608) { int t = j - 2304; cvt_body(tile, w_fc1, wfc1T, 768, 3072, t % 24, t / 24); }
  else if (j < 6912) { int t = j - 4608; cvt_body(tile, w_fc2, wfc2T, 3072, 768, t % 96, t / 96); }
  else               ln_body(x, g, b, h, j - 6912);
}

// ---------- standalone LayerNorm (LN2) ----------
__global__ __launch_bounds__(256) void ln_rows(const float* __restrict__ x,
                                               const float* __restrict__ g,
                                               const float* __restrict__ b,
                                               short* __restrict__ out) {
  ln_body(x, g, b, out, blockIdx.x);
}

// ---------- 128x128 GEMM (QKV w/ VTR; fc1 EPI2) ----------
template <int EPI, int N, bool VTR>
__global__ __launch_bounds__(256) void gemm_bt(const short* __restrict__ A,
                                               const short* __restrict__ Bt,
                                               const float* __restrict__ bias,
                                               const float* __restrict__ add,
                                               void* __restrict__ outp,
                                               int K,
                                               short* __restrict__ vt) {
  __shared__ short S[17408];
  short* As0 = S;
  short* As1 = S + 4096;
  short* Bs0 = S + 8192;
  short* Bs1 = S + 12288;

  int nbx = gridDim.x;
  int flat = blockIdx.y * nbx + blockIdx.x;
  int cpx = (nbx * gridDim.y) >> 3;
  int swz = (flat & 7) * cpx + (flat >> 3);
  int m0 = (swz % nbx) * 128, n0 = (swz / nbx) * 128;

  int tid = threadIdx.x;
  int lane = tid & 63, wid = tid >> 6;
  int wm = wid >> 1, wn = wid & 1;
  int l15 = lane & 15, lg = lane >> 4;

  int jr = tid >> 2, jc = (tid & 3) << 3;
  int ldsb = wid << 9;

  auto stage = [&](short* Ad, short* Bd, int k0) {
    gl_lds16(&A[(size_t)(m0 + jr) * K + k0 + jc],       Ad + ldsb);
    gl_lds16(&A[(size_t)(m0 + 64 + jr) * K + k0 + jc],  Ad + 2048 + ldsb);
    gl_lds16(&Bt[(size_t)(n0 + jr) * K + k0 + jc],      Bd + ldsb);
    gl_lds16(&Bt[(size_t)(n0 + 64 + jr) * K + k0 + jc], Bd + 2048 + ldsb);
  };

  f32x4 acc[4][4] = {};
  stage(As0, Bs0, 0);
  int nk = K >> 5;
  for (int t = 0; t < nk; ++t) {
    short* Ab = (t & 1) ? As1 : As0;
    short* Bb = (t & 1) ? Bs1 : Bs0;
    if (t + 1 < nk) {
      stage((t & 1) ? As0 : As1, (t & 1) ? Bs0 : Bs1, (t + 1) << 5);
      asm volatile("s_waitcnt vmcnt(4)" ::: "memory");
    } else {
      asm volatile("s_waitcnt vmcnt(0)" ::: "memory");
    }
    __syncthreads();
    bf16x8 af[4], bfr[4];
    #pragma unroll
    for (int i = 0; i < 4; i++) af[i]  = *(bf16x8*)&Ab[(wm * 64 + i * 16 + l15) * 32 + lg * 8];
    #pragma unroll
    for (int j = 0; j < 4; j++) bfr[j] = *(bf16x8*)&Bb[(wn * 64 + j * 16 + l15) * 32 + lg * 8];
    #pragma unroll
    for (int i = 0; i < 4; i++)
      #pragma unroll
      for (int j = 0; j < 4; j++)
        acc[i][j] = MFMA16(af[i], bfr[j], acc[i][j]);
    __syncthreads();
  }

  if (EPI == 0 || EPI == 2) {
    short (*Cl)[136] = (short (*)[136])S;
    #pragma unroll
    for (int i = 0; i < 4; i++)
      #pragma unroll
      for (int j = 0; j < 4; j++)
        #pragma unroll
        for (int r = 0; r < 4; r++) {
          int row = wm * 64 + i * 16 + lg * 4 + r;
          int col = wn * 64 + j * 16 + l15;
          float vv = acc[i][j][r] + bias[n0 + col];
          if (EPI == 2) vv = gelu_exact(vv);
          int ch = col >> 3, co = col & 7;
          Cl[row][((ch ^ (row & 7)) << 3) | co] = f2bf(vv);
        }
    __syncthreads();
    if (VTR && n0 >= 1536) {
      int b = m0 >> 10, tbase = m0 & 1023;
      int h0 = (n0 - 1536) >> 6;
      #pragma unroll
      for (int half = 0; half < 2; ++half) {
        int c = (tid >> 2) + half * 64;
        int hh = c >> 6, d = c & 63;
        short* dst = vt + ((size_t)((b * Hh + h0 + hh) * 64 + d)) * Tt
                        + tbase + (tid & 3) * 32;
        #pragma unroll
        for (int j = 0; j < 4; ++j) {
          bf16x8 v8;
          #pragma unroll
          for (int k = 0; k < 8; ++k) {
            int t = (tid & 3) * 32 + j * 8 + k;
            v8[k] = Cl[t][(((c >> 3) ^ (t & 7)) << 3) | (c & 7)];
          }
          *(bf16x8*)(dst + j * 8) = v8;
        }
      }
    } else {
      int row = tid >> 1;
      int cb = (tid & 1) * 8;
      #pragma unroll
      for (int c = 0; c < 8; c++) {
        int ch = cb + c;
        bf16x8 v8 = *(bf16x8*)&Cl[row][(ch ^ (row & 7)) << 3];
        *(bf16x8*)&((short*)outp)[(size_t)(m0 + row) * N + n0 + (ch << 3)] = v8;
      }
    }
  } else {
    #pragma unroll
    for (int i = 0; i < 4; i++)
      #pragma unroll
      for (int j = 0; j < 4; j++)
        #pragma unroll
        for (int r = 0; r < 4; r++) {
          int m = m0 + wm * 64 + i * 16 + lg * 4 + r;
          int n = n0 + wn * 64 + j * 16 + l15;
          float vv = acc[i][j][r] + bias[n];
          size_t idx = (size_t)m * N + n;
          float ov = vv + add[idx];
          if (EPI == 3) __builtin_nontemporal_store(ov, &((float*)outp)[idx]);
          else          ((float*)outp)[idx] = ov;
        }
  }
}

// ---------- 64x128 GEMM, BK=64 + XOR-swizzled LDS (out-proj EPI1, fc2 EPI3) ----------
template <int EPI, int N>
__global__ __launch_bounds__(256) void gemm_n64k64(const short* __restrict__ A,
                                                   const short* __restrict__ Bt,
                                                   const float* __restrict__ bias,
                                                   const float* __restrict__ add,
                                                   void* __restrict__ outp,
                                                   int K) {
  __shared__ short S[24576];          // 49.2 KB
  short* As0 = S;
  short* As1 = S + 4096;
  short* Bs0 = S + 8192;
  short* Bs1 = S + 16384;

  int nbx = gridDim.x;
  int flat = blockIdx.y * nbx + blockIdx.x;
  int cpx = (nbx * gridDim.y) >> 3;
  int swz = (flat & 7) * cpx + (flat >> 3);
  int m0 = (swz % nbx) * 64, n0 = (swz / nbx) * 128;

  int tid = threadIdx.x;
  int lane = tid & 63, wid = tid >> 6;
  int wm = wid & 1, wn = wid >> 1;
  int l15 = lane & 15, lg = lane >> 4;

  int r8 = tid >> 3;
  int gsl = (tid & 7) ^ (r8 & 7);
  int wb = wid << 9;

  auto stage = [&](short* Ad, short* Bd, int k0) {
    #pragma unroll
    for (int c = 0; c < 2; ++c)
      gl_lds16(&A[(size_t)(m0 + c * 32 + r8) * K + k0 + gsl * 8], Ad + c * 2048 + wb);
    #pragma unroll
    for (int c = 0; c < 4; ++c)
      gl_lds16(&Bt[(size_t)(n0 + c * 32 + r8) * K + k0 + gsl * 8], Bd + c * 2048 + wb);
  };

  f32x4 acc[2][4] = {};
  stage(As0, Bs0, 0);
  int nk = K >> 6;
  for (int t = 0; t < nk; ++t) {
    short* Ab = (t & 1) ? As1 : As0;
    short* Bb = (t & 1) ? Bs1 : Bs0;
    if (t + 1 < nk) {
      stage((t & 1) ? As0 : As1, (t & 1) ? Bs0 : Bs1, (t + 1) << 6);
      asm volatile("s_waitcnt vmcnt(6)" ::: "memory");
    } else {
      asm volatile("s_waitcnt vmcnt(0)" ::: "memory");
    }
    __syncthreads();
    bf16x8 af[2][2], bfr[4][2];
    #pragma unroll
    for (int i = 0; i < 2; i++) {
      int r = wm * 32 + i * 16 + l15;
      #pragma unroll
      for (int kk = 0; kk < 2; kk++)
        af[i][kk] = *(bf16x8*)&Ab[r * 64 + (((kk * 4 + lg) ^ (r & 7)) << 3)];
    }
    #pragma unroll
    for (int j = 0; j < 4; j++) {
      int r = wn * 64 + j * 16 + l15;
      #pragma unroll
      for (int kk = 0; kk < 2; kk++)
        bfr[j][kk] = *(bf16x8*)&Bb[r * 64 + (((kk * 4 + lg) ^ (r & 7)) << 3)];
    }
    #pragma unroll
    for (int kk = 0; kk < 2; kk++)
      #pragma unroll
      for (int i = 0; i < 2; i++)
        #pragma unroll
        for (int j = 0; j < 4; j++)
          acc[i][j] = MFMA16(af[i][kk], bfr[j][kk], acc[i][j]);
    __syncthreads();
  }

  #pragma unroll
  for (int i = 0; i < 2; i++)
    #pragma unroll
    for (int j = 0; j < 4; j++)
      #pragma unroll
      for (int r = 0; r < 4; r++) {
        int m = m0 + wm * 32 + i * 16 + lg * 4 + r;
        int n = n0 + wn * 64 + j * 16 + l15;
        float vv = acc[i][j][r] + bias[n];
        size_t idx = (size_t)m * N + n;
        float ov = vv + add[idx];
        if (EPI == 3) __builtin_nontemporal_store(ov, &((float*)outp)[idx]);
        else          ((float*)outp)[idx] = ov;
      }
}

// ---------- fused causal attention (R15-proven: f32 Pf staging) ----------
__global__ __launch_bounds__(256) void attn_fused(const short* __restrict__ qkv,
                                                  const short* __restrict__ vt,
                                                  float* __restrict__ attw,
                                                  short* __restrict__ ctx) {
  __shared__ short VtL[2][4096];
  __shared__ float Pf[4][16][68];
  int flat = blockIdx.y * 16 + blockIdx.x;
  int xcd = flat & 7, rr0 = flat >> 3;
  int bh   = xcd * 12 + (rr0 >> 4);
  int tile = 15 - (rr0 & 15);
  int q0 = tile * 64;
  int b = bh / Hh, h = bh % Hh;
  int tid = threadIdx.x, lane = tid & 63, wid = tid >> 6;
  int l15 = lane & 15, lg = lane >> 4;
  const short* base = qkv + (size_t)b * Tt * 2304;

  bf16x8 qa[2];
  {
    const short* qp = base + (size_t)(q0 + wid * 16 + l15) * 2304 + h * 64 + lg * 8;
    qa[0] = *(const bf16x8*)qp;
    qa[1] = *(const bf16x8*)(qp + 32);
  }

  float l[4] = {0.f, 0.f, 0.f, 0.f};
  for (int kt = 0; kt <= tile; ++kt) {
    f32x4 acc[4] = {};
    #pragma unroll
    for (int nf = 0; nf < 4; ++nf) {
      const short* kp = base + (size_t)(kt * 64 + nf * 16 + l15) * 2304 + 768 + h * 64 + lg * 8;
      bf16x8 k0 = *(const bf16x8*)kp;
      bf16x8 k1 = *(const bf16x8*)(kp + 32);
      acc[nf] = MFMA16(qa[0], k0, acc[nf]);
      acc[nf] = MFMA16(qa[1], k1, acc[nf]);
    }
    #pragma unroll
    for (int r = 0; r < 4; r++) {
      int qg = q0 + wid * 16 + lg * 4 + r;
      #pragma unroll
      for (int nf = 0; nf < 4; nf++) {
        int kg = kt * 64 + nf * 16 + l15;
        l[r] += (kg <= qg) ? __expf(acc[nf][r] * 0.125f) : 0.f;
      }
    }
  }
  float rl[4];
  #pragma unroll
  for (int r = 0; r < 4; r++) {
    float s = l[r];
    #pragma unroll
    for (int off = 1; off < 16; off <<= 1) s += __shfl_xor(s, off);
    rl[r] = 1.f / s;
  }

  const short* vtb = vt + (size_t)bh * 64 * Tt;
  int dS = wid * 16 + (lane >> 3);
  int cS = (lane & 7) ^ (lane >> 3);
  auto stageV = [&](int bi, int kt) {
    gl_lds16(&vtb[(size_t)dS * Tt + kt * 64 + cS * 8],       &VtL[bi][wid * 1024]);
    gl_lds16(&vtb[(size_t)(dS + 8) * Tt + kt * 64 + cS * 8], &VtL[bi][wid * 1024 + 512]);
  };

  f32x4 oacc[4] = {};
  stageV(0, 0);
  for (int kt = 0; kt <= tile; ++kt) {
    int cur = kt & 1;
    f32x4 acc[4] = {};
    #pragma unroll
    for (int nf = 0; nf < 4; nf++) {
      const short* kp = base + (size_t)(kt * 64 + nf * 16 + l15) * 2304 + 768 + h * 64 + lg * 8;
      bf16x8 k0 = *(const bf16x8*)kp;
      bf16x8 k1 = *(const bf16x8*)(kp + 32);
      acc[nf] = MFMA16(qa[0], k0, acc[nf]);
      acc[nf] = MFMA16(qa[1], k1, acc[nf]);
    }
    #pragma unroll
    for (int nf = 0; nf < 4; nf++) {
      #pragma unroll
      for (int r = 0; r < 4; r++) {
        int qg = q0 + wid * 16 + lg * 4 + r;
        int kg = kt * 64 + nf * 16 + l15;
        float p = (kg <= qg) ? __expf(acc[nf][r] * 0.125f) * rl[r] : 0.f;
        Pf[wid][lg * 4 + r][nf * 16 + l15] = p;
      }
    }
    asm volatile("s_waitcnt lgkmcnt(0)" ::: "memory");
    __builtin_amdgcn_sched_barrier(0);
    #pragma unroll
    for (int it = 0; it < 4; ++it) {
      int pr = it * 4 + lg;
      f32x4 pv = *(f32x4*)&Pf[wid][pr][l15 * 4];
      __builtin_nontemporal_store(
          pv, (f32x4*)&attw[((size_t)bh * Tt + q0 + wid * 16 + pr) * Tt + kt * 64 + l15 * 4]);
    }
    f32x4 pf0 = *(f32x4*)&Pf[wid][l15][lg * 8];
    f32x4 pf1 = *(f32x4*)&Pf[wid][l15][lg * 8 + 4];
    f32x4 pf2 = *(f32x4*)&Pf[wid][l15][lg * 8 + 32];
    f32x4 pf3 = *(f32x4*)&Pf[wid][l15][lg * 8 + 36];
    bf16x8 pa0, pa1;
    #pragma unroll
    for (int j = 0; j < 4; j++) {
      pa0[j] = f2bf(pf0[j]); pa0[4 + j] = f2bf(pf1[j]);
      pa1[j] = f2bf(pf2[j]); pa1[4 + j] = f2bf(pf3[j]);
    }
    asm volatile("s_waitcnt vmcnt(4)" ::: "memory");
    __builtin_amdgcn_s_barrier();
    __builtin_amdgcn_sched_barrier(0);
    if (kt < tile) stageV(cur ^ 1, kt + 1);
    #pragma unroll
    for (int nf = 0; nf < 4; nf++) {
      int dA = nf * 16 + l15;
      int sw = dA & 7;
      bf16x8 vb0 = *(bf16x8*)&VtL[cur][dA * 64 + ((lg ^ sw) << 3)];
      bf16x8 vb1 = *(bf16x8*)&VtL[cur][dA * 64 + (((4 + lg) ^ sw) << 3)];
      oacc[nf] = MFMA16(pa0, vb0, oacc[nf]);
      oacc[nf] = MFMA16(pa1, vb1, oacc[nf]);
    }
  }
  f32x4 z = {0.f, 0.f, 0.f, 0.f};
  for (int kt = tile + 1; kt < 16; ++kt) {
    #pragma unroll
    for (int it = 0; it < 4; ++it) {
      int pr = it * 4 + lg;
      __builtin_nontemporal_store(
          z, (f32x4*)&attw[((size_t)bh * Tt + q0 + wid * 16 + pr) * Tt + kt * 64 + l15 * 4]);
    }
  }
  #pragma unroll
  for (int nf = 0; nf < 4; nf++) {
    #pragma unroll
    for (int r = 0; r < 4; r++) {
      int t = q0 + wid * 16 + lg * 4 + r;
      ctx[((size_t)b * Tt + t) * Dd + h * 64 + nf * 16 + l15] = f2bf(oacc[nf][r]);
    }
  }
}

}  // namespace

extern "C" void kernel_launch(void* const* d_in, const int* in_sizes, int n_in,
                              void* d_out, int out_size, void* d_ws, size_t ws_size,
                              hipStream_t stream) {
  const float* x     = (const float*)d_in[0];
  const float* ln1g  = (const float*)d_in[1];
  const float* ln1b  = (const float*)d_in[2];
  const float* w_qkv = (const float*)d_in[3];
  const float* b_qkv = (const float*)d_in[4];
  const float* w_out = (const float*)d_in[5];
  const float* b_out = (const float*)d_in[6];
  const float* ln2g  = (const float*)d_in[7];
  const float* ln2b  = (const float*)d_in[8];
  const float* w_fc1 = (const float*)d_in[9];
  const float* b_fc1 = (const float*)d_in[10];
  const float* w_fc2 = (const float*)d_in[11];
  const float* b_fc2 = (const float*)d_in[12];

  char* ws = (char*)d_ws;
  size_t o = 0;
  short* wqkvT = (short*)(ws + o); o += (size_t)2304 * 768 * 2;
  short* woutT = (short*)(ws + o); o += (size_t)768 * 768 * 2;
  short* wfc1T = (short*)(ws + o); o += (size_t)3072 * 768 * 2;
  short* wfc2T = (short*)(ws + o); o += (size_t)768 * 3072 * 2;
  short* h     = (short*)(ws + o); o += (size_t)BT * Dd * 2;
  short* qkv   = (short*)(ws + o); o += (size_t)BT * 2304 * 2;
  float* y1    = (float*)(ws + o); o += (size_t)BT * Dd * 4;
  short* h2    = (short*)(ws + o); o += (size_t)BT * Dd * 2;
  short* vt    = (short*)(ws + o); o += (size_t)96 * 64 * Tt * 2;
  short* ctx  = h;     // reuse: h dead after QKV GEMM
  short* gbuf = h;     // reuse: h+qkv for GELU output (attw fully written before fc1)

  float* out_x = (float*)d_out;
  float* attw  = out_x + (size_t)BT * Dd;

  prep<<<8960, 256, 0, stream>>>(w_qkv, wqkvT, w_out, woutT, w_fc1, wfc1T,
                                 w_fc2, wfc2T, x, ln1g, ln1b, h);
  gemm_bt<0, 2304, true><<<dim3(BT / 128, 2304 / 128), 256, 0, stream>>>(
      h, wqkvT, b_qkv, nullptr, qkv, 768, vt);
  attn_fused<<<dim3(16, 96), 256, 0, stream>>>(qkv, vt, attw, ctx);
  gemm_n64k64<1, 768><<<dim3(BT / 64, 768 / 128), 256, 0, stream>>>(
      ctx, woutT, b_out, x, y1, 768);
  ln_rows<<<BT / 4, 256, 0, stream>>>(y1, ln2g, ln2b, h2);
  gemm_bt<2, 3072, false><<<dim3(BT / 128, 3072 / 128), 256, 0, stream>>>(
      h2, wfc1T, b_fc1, nullptr, gbuf, 768, nullptr);
  gemm_n64k64<3, 768><<<dim3(BT / 64, 768 / 128), 256, 0, stream>>>(
      gbuf, wfc2T, b_fc2, y1, out_x, 3072);
}

// Round 20
// 399.008 us; speedup vs baseline: 1.0358x; 1.0141x over previous
//
#include <hip/hip_runtime.h>
#include <cstdint>
#include <cstddef>

namespace {

constexpr int Bb  = 8;
constexpr int Tt  = 1024;
constexpr int Dd  = 768;
constexpr int Hh  = 12;
constexpr int DFF = 3072;
constexpr int BT  = Bb * Tt;

typedef __attribute__((ext_vector_type(8))) short bf16x8;
typedef __attribute__((ext_vector_type(4))) short bf16x4;
typedef __attribute__((ext_vector_type(4))) float f32x4;

__device__ __forceinline__ short f2bf(float f) {
  union { float f; unsigned u; } v; v.f = f;
  unsigned r = v.u + 0x7fffu + ((v.u >> 16) & 1u);   // RNE
  return (short)(r >> 16);
}
__device__ __forceinline__ float gelu_exact(float v) {
  return 0.5f * v * (1.0f + erff(v * 0.70710678118654752f));
}

#define MFMA16(a, b, c) __builtin_amdgcn_mfma_f32_16x16x32_bf16(a, b, c, 0, 0, 0)

__device__ __forceinline__ void gl_lds16(const short* g, short* l) {
  __builtin_amdgcn_global_load_lds(
      (const __attribute__((address_space(1))) unsigned int*)(g),
      (__attribute__((address_space(3))) unsigned int*)(l), 16, 0, 0);
}

// ---------- weight convert+transpose body ----------
__device__ __forceinline__ void cvt_body(float (*tile)[33],
                                         const float* __restrict__ in,
                                         short* __restrict__ out,
                                         int K, int N, int bx, int by) {
  int k0 = bx * 32, n0 = by * 32;
  int tx = threadIdx.x & 31, ty = threadIdx.x >> 5;
  #pragma unroll
  for (int r = ty; r < 32; r += 8)
    tile[r][tx] = in[(size_t)(k0 + r) * N + n0 + tx];
  __syncthreads();
  #pragma unroll
  for (int r = ty; r < 32; r += 8)
    out[(size_t)(n0 + r) * K + k0 + tx] = f2bf(tile[tx][r]);
}

// ---------- LayerNorm body ----------
__device__ __forceinline__ void ln_body(const float* __restrict__ x,
                                        const float* __restrict__ g,
                                        const float* __restrict__ b,
                                        short* __restrict__ out, int blkrow) {
  int lane = threadIdx.x & 63, wid = threadIdx.x >> 6;
  int row = blkrow * 4 + wid;
  const float* xr = x + (size_t)row * Dd;
  float v[12];
  float s = 0.f, ss = 0.f;
  #pragma unroll
  for (int c = 0; c < 3; c++) {
    float4 t = *(const float4*)&xr[c * 256 + lane * 4];
    v[c * 4 + 0] = t.x; v[c * 4 + 1] = t.y; v[c * 4 + 2] = t.z; v[c * 4 + 3] = t.w;
    s  += t.x + t.y + t.z + t.w;
    ss += t.x * t.x + t.y * t.y + t.z * t.z + t.w * t.w;
  }
  #pragma unroll
  for (int off = 1; off < 64; off <<= 1) {
    s += __shfl_xor(s, off); ss += __shfl_xor(ss, off);
  }
  float mu   = s * (1.f / Dd);
  float var  = ss * (1.f / Dd) - mu * mu;
  float rstd = rsqrtf(var + 1e-5f);
  #pragma unroll
  for (int c = 0; c < 3; c++) {
    bf16x4 o;
    #pragma unroll
    for (int j = 0; j < 4; j++) {
      int d = c * 256 + lane * 4 + j;
      o[j] = f2bf((v[c * 4 + j] - mu) * rstd * g[d] + b[d]);
    }
    *(bf16x4*)&out[(size_t)row * Dd + c * 256 + lane * 4] = o;
  }
}

// ---------- prep: 4 weight-converts + LN1 ----------
__global__ __launch_bounds__(256) void prep(const float* __restrict__ w_qkv, short* wqkvT,
                                            const float* __restrict__ w_out, short* woutT,
                                            const float* __restrict__ w_fc1, short* wfc1T,
                                            const float* __restrict__ w_fc2, short* wfc2T,
                                            const float* __restrict__ x,
                                            const float* __restrict__ g,
                                            const float* __restrict__ b,
                                            short* __restrict__ h) {
  __shared__ float tile[32][33];
  int j = blockIdx.x;
  if (j < 1728)      cvt_body(tile, w_qkv, wqkvT, 768, 2304, j % 24, j / 24);
  else if (j < 2304) { int t = j - 1728; cvt_body(tile, w_out, woutT, 768, 768, t % 24, t / 24); }
  else if (j < 4608) { int t = j - 2304; cvt_body(tile, w_fc1, wfc1T, 768, 3072, t % 24, t / 24); }
  else if (j < 6912) { int t = j - 4608; cvt_body(tile, w_fc2, wfc2T, 3072, 768, t % 96, t / 96); }
  else               ln_body(x, g, b, h, j - 6912);
}

// ---------- standalone LayerNorm (LN2) ----------
__global__ __launch_bounds__(256) void ln_rows(const float* __restrict__ x,
                                               const float* __restrict__ g,
                                               const float* __restrict__ b,
                                               short* __restrict__ out) {
  ln_body(x, g, b, out, blockIdx.x);
}

// ---------- 128x128 GEMM (QKV w/ VTR; fc1 EPI2) ----------
template <int EPI, int N, bool VTR>
__global__ __launch_bounds__(256) void gemm_bt(const short* __restrict__ A,
                                               const short* __restrict__ Bt,
                                               const float* __restrict__ bias,
                                               const float* __restrict__ add,
                                               void* __restrict__ outp,
                                               int K,
                                               short* __restrict__ vt) {
  __shared__ short S[17408];
  short* As0 = S;
  short* As1 = S + 4096;
  short* Bs0 = S + 8192;
  short* Bs1 = S + 12288;

  int nbx = gridDim.x;
  int flat = blockIdx.y * nbx + blockIdx.x;
  int cpx = (nbx * gridDim.y) >> 3;
  int swz = (flat & 7) * cpx + (flat >> 3);
  int m0 = (swz % nbx) * 128, n0 = (swz / nbx) * 128;

  int tid = threadIdx.x;
  int lane = tid & 63, wid = tid >> 6;
  int wm = wid >> 1, wn = wid & 1;
  int l15 = lane & 15, lg = lane >> 4;

  int jr = tid >> 2, jc = (tid & 3) << 3;
  int ldsb = wid << 9;

  auto stage = [&](short* Ad, short* Bd, int k0) {
    gl_lds16(&A[(size_t)(m0 + jr) * K + k0 + jc],       Ad + ldsb);
    gl_lds16(&A[(size_t)(m0 + 64 + jr) * K + k0 + jc],  Ad + 2048 + ldsb);
    gl_lds16(&Bt[(size_t)(n0 + jr) * K + k0 + jc],      Bd + ldsb);
    gl_lds16(&Bt[(size_t)(n0 + 64 + jr) * K + k0 + jc], Bd + 2048 + ldsb);
  };

  f32x4 acc[4][4] = {};
  stage(As0, Bs0, 0);
  int nk = K >> 5;
  for (int t = 0; t < nk; ++t) {
    short* Ab = (t & 1) ? As1 : As0;
    short* Bb = (t & 1) ? Bs1 : Bs0;
    if (t + 1 < nk) {
      stage((t & 1) ? As0 : As1, (t & 1) ? Bs0 : Bs1, (t + 1) << 5);
      asm volatile("s_waitcnt vmcnt(4)" ::: "memory");
    } else {
      asm volatile("s_waitcnt vmcnt(0)" ::: "memory");
    }
    __syncthreads();
    bf16x8 af[4], bfr[4];
    #pragma unroll
    for (int i = 0; i < 4; i++) af[i]  = *(bf16x8*)&Ab[(wm * 64 + i * 16 + l15) * 32 + lg * 8];
    #pragma unroll
    for (int j = 0; j < 4; j++) bfr[j] = *(bf16x8*)&Bb[(wn * 64 + j * 16 + l15) * 32 + lg * 8];
    #pragma unroll
    for (int i = 0; i < 4; i++)
      #pragma unroll
      for (int j = 0; j < 4; j++)
        acc[i][j] = MFMA16(af[i], bfr[j], acc[i][j]);
    __syncthreads();
  }

  if (EPI == 0 || EPI == 2) {
    short (*Cl)[136] = (short (*)[136])S;
    #pragma unroll
    for (int i = 0; i < 4; i++)
      #pragma unroll
      for (int j = 0; j < 4; j++)
        #pragma unroll
        for (int r = 0; r < 4; r++) {
          int row = wm * 64 + i * 16 + lg * 4 + r;
          int col = wn * 64 + j * 16 + l15;
          float vv = acc[i][j][r] + bias[n0 + col];
          if (EPI == 2) vv = gelu_exact(vv);
          int ch = col >> 3, co = col & 7;
          Cl[row][((ch ^ (row & 7)) << 3) | co] = f2bf(vv);
        }
    __syncthreads();
    if (VTR && n0 >= 1536) {
      int b = m0 >> 10, tbase = m0 & 1023;
      int h0 = (n0 - 1536) >> 6;
      #pragma unroll
      for (int half = 0; half < 2; ++half) {
        int c = (tid >> 2) + half * 64;
        int hh = c >> 6, d = c & 63;
        short* dst = vt + ((size_t)((b * Hh + h0 + hh) * 64 + d)) * Tt
                        + tbase + (tid & 3) * 32;
        #pragma unroll
        for (int j = 0; j < 4; ++j) {
          bf16x8 v8;
          #pragma unroll
          for (int k = 0; k < 8; ++k) {
            int t = (tid & 3) * 32 + j * 8 + k;
            v8[k] = Cl[t][(((c >> 3) ^ (t & 7)) << 3) | (c & 7)];
          }
          *(bf16x8*)(dst + j * 8) = v8;
        }
      }
    } else {
      int row = tid >> 1;
      int cb = (tid & 1) * 8;
      #pragma unroll
      for (int c = 0; c < 8; c++) {
        int ch = cb + c;
        bf16x8 v8 = *(bf16x8*)&Cl[row][(ch ^ (row & 7)) << 3];
        *(bf16x8*)&((short*)outp)[(size_t)(m0 + row) * N + n0 + (ch << 3)] = v8;
      }
    }
  } else {
    #pragma unroll
    for (int i = 0; i < 4; i++)
      #pragma unroll
      for (int j = 0; j < 4; j++)
        #pragma unroll
        for (int r = 0; r < 4; r++) {
          int m = m0 + wm * 64 + i * 16 + lg * 4 + r;
          int n = n0 + wn * 64 + j * 16 + l15;
          float vv = acc[i][j][r] + bias[n];
          size_t idx = (size_t)m * N + n;
          float ov = vv + add[idx];
          if (EPI == 3) __builtin_nontemporal_store(ov, &((float*)outp)[idx]);
          else          ((float*)outp)[idx] = ov;
        }
  }
}

// ---------- 64x128 GEMM, BK=64 + XOR-swizzled LDS (out-proj EPI1, fc2 EPI3) ----------
template <int EPI, int N>
__global__ __launch_bounds__(256) void gemm_n64k64(const short* __restrict__ A,
                                                   const short* __restrict__ Bt,
                                                   const float* __restrict__ bias,
                                                   const float* __restrict__ add,
                                                   void* __restrict__ outp,
                                                   int K) {
  __shared__ short S[24576];          // 49.2 KB
  short* As0 = S;
  short* As1 = S + 4096;
  short* Bs0 = S + 8192;
  short* Bs1 = S + 16384;

  int nbx = gridDim.x;
  int flat = blockIdx.y * nbx + blockIdx.x;
  int cpx = (nbx * gridDim.y) >> 3;
  int swz = (flat & 7) * cpx + (flat >> 3);
  int m0 = (swz % nbx) * 64, n0 = (swz / nbx) * 128;

  int tid = threadIdx.x;
  int lane = tid & 63, wid = tid >> 6;
  int wm = wid & 1, wn = wid >> 1;
  int l15 = lane & 15, lg = lane >> 4;

  int r8 = tid >> 3;
  int gsl = (tid & 7) ^ (r8 & 7);
  int wb = wid << 9;

  auto stage = [&](short* Ad, short* Bd, int k0) {
    #pragma unroll
    for (int c = 0; c < 2; ++c)
      gl_lds16(&A[(size_t)(m0 + c * 32 + r8) * K + k0 + gsl * 8], Ad + c * 2048 + wb);
    #pragma unroll
    for (int c = 0; c < 4; ++c)
      gl_lds16(&Bt[(size_t)(n0 + c * 32 + r8) * K + k0 + gsl * 8], Bd + c * 2048 + wb);
  };

  f32x4 acc[2][4] = {};
  stage(As0, Bs0, 0);
  int nk = K >> 6;
  for (int t = 0; t < nk; ++t) {
    short* Ab = (t & 1) ? As1 : As0;
    short* Bb = (t & 1) ? Bs1 : Bs0;
    if (t + 1 < nk) {
      stage((t & 1) ? As0 : As1, (t & 1) ? Bs0 : Bs1, (t + 1) << 6);
      asm volatile("s_waitcnt vmcnt(6)" ::: "memory");
    } else {
      asm volatile("s_waitcnt vmcnt(0)" ::: "memory");
    }
    __syncthreads();
    bf16x8 af[2][2], bfr[4][2];
    #pragma unroll
    for (int i = 0; i < 2; i++) {
      int r = wm * 32 + i * 16 + l15;
      #pragma unroll
      for (int kk = 0; kk < 2; kk++)
        af[i][kk] = *(bf16x8*)&Ab[r * 64 + (((kk * 4 + lg) ^ (r & 7)) << 3)];
    }
    #pragma unroll
    for (int j = 0; j < 4; j++) {
      int r = wn * 64 + j * 16 + l15;
      #pragma unroll
      for (int kk = 0; kk < 2; kk++)
        bfr[j][kk] = *(bf16x8*)&Bb[r * 64 + (((kk * 4 + lg) ^ (r & 7)) << 3)];
    }
    #pragma unroll
    for (int kk = 0; kk < 2; kk++)
      #pragma unroll
      for (int i = 0; i < 2; i++)
        #pragma unroll
        for (int j = 0; j < 4; j++)
          acc[i][j] = MFMA16(af[i][kk], bfr[j][kk], acc[i][j]);
    __syncthreads();
  }

  #pragma unroll
  for (int i = 0; i < 2; i++)
    #pragma unroll
    for (int j = 0; j < 4; j++)
      #pragma unroll
      for (int r = 0; r < 4; r++) {
        int m = m0 + wm * 32 + i * 16 + lg * 4 + r;
        int n = n0 + wn * 64 + j * 16 + l15;
        float vv = acc[i][j][r] + bias[n];
        size_t idx = (size_t)m * N + n;
        float ov = vv + add[idx];
        if (EPI == 3) __builtin_nontemporal_store(ov, &((float*)outp)[idx]);
        else          ((float*)outp)[idx] = ov;
      }
}

// ---------- fused causal attention (R18 + zero-tiles interleaved into pass 1) ----------
__global__ __launch_bounds__(256) void attn_fused(const short* __restrict__ qkv,
                                                  const short* __restrict__ vt,
                                                  float* __restrict__ attw,
                                                  short* __restrict__ ctx) {
  __shared__ short VtL[2][4096];
  __shared__ float Pf[4][16][68];
  int flat = blockIdx.y * 16 + blockIdx.x;
  int xcd = flat & 7, rr0 = flat >> 3;
  int bh   = xcd * 12 + (rr0 >> 4);
  int tile = 15 - (rr0 & 15);
  int q0 = tile * 64;
  int b = bh / Hh, h = bh % Hh;
  int tid = threadIdx.x, lane = tid & 63, wid = tid >> 6;
  int l15 = lane & 15, lg = lane >> 4;
  const short* base = qkv + (size_t)b * Tt * 2304;

  bf16x8 qa[2];
  {
    const short* qp = base + (size_t)(q0 + wid * 16 + l15) * 2304 + h * 64 + lg * 8;
    qa[0] = *(const bf16x8*)qp;
    qa[1] = *(const bf16x8*)(qp + 32);
  }

  // ---- pass 1: per-lane sumexp, with the strictly-upper ZERO-TILE stores
  // interleaved (store pipe is otherwise idle in this pass; nt stores have no
  // deps and drift freely — same values as the old tail loop).
  float l[4] = {0.f, 0.f, 0.f, 0.f};
  int nzero = 15 - tile;
  int nit = (tile + 1 > nzero) ? (tile + 1) : nzero;
  f32x4 z = {0.f, 0.f, 0.f, 0.f};
  for (int it = 0; it < nit; ++it) {
    if (it <= tile) {
      int kt = it;
      f32x4 acc[4] = {};
      #pragma unroll
      for (int nf = 0; nf < 4; ++nf) {
        const short* kp = base + (size_t)(kt * 64 + nf * 16 + l15) * 2304 + 768 + h * 64 + lg * 8;
        bf16x8 k0 = *(const bf16x8*)kp;
        bf16x8 k1 = *(const bf16x8*)(kp + 32);
        acc[nf] = MFMA16(qa[0], k0, acc[nf]);
        acc[nf] = MFMA16(qa[1], k1, acc[nf]);
      }
      #pragma unroll
      for (int r = 0; r < 4; r++) {
        int qg = q0 + wid * 16 + lg * 4 + r;
        #pragma unroll
        for (int nf = 0; nf < 4; nf++) {
          int kg = kt * 64 + nf * 16 + l15;
          l[r] += (kg <= qg) ? __expf(acc[nf][r] * 0.125f) : 0.f;
        }
      }
    }
    if (it < nzero) {
      int zt = tile + 1 + it;
      #pragma unroll
      for (int p = 0; p < 4; ++p) {
        int pr = p * 4 + lg;
        __builtin_nontemporal_store(
            z, (f32x4*)&attw[((size_t)bh * Tt + q0 + wid * 16 + pr) * Tt + zt * 64 + l15 * 4]);
      }
    }
  }
  float rl[4];
  #pragma unroll
  for (int r = 0; r < 4; r++) {
    float s = l[r];
    #pragma unroll
    for (int off = 1; off < 16; off <<= 1) s += __shfl_xor(s, off);
    rl[r] = 1.f / s;
  }

  // ---- pass 2 ----
  const short* vtb = vt + (size_t)bh * 64 * Tt;
  int dS = wid * 16 + (lane >> 3);
  int cS = (lane & 7) ^ (lane >> 3);
  auto stageV = [&](int bi, int kt) {
    gl_lds16(&vtb[(size_t)dS * Tt + kt * 64 + cS * 8],       &VtL[bi][wid * 1024]);
    gl_lds16(&vtb[(size_t)(dS + 8) * Tt + kt * 64 + cS * 8], &VtL[bi][wid * 1024 + 512]);
  };

  f32x4 oacc[4] = {};
  stageV(0, 0);
  for (int kt = 0; kt <= tile; ++kt) {
    int cur = kt & 1;
    f32x4 acc[4] = {};
    #pragma unroll
    for (int nf = 0; nf < 4; nf++) {
      const short* kp = base + (size_t)(kt * 64 + nf * 16 + l15) * 2304 + 768 + h * 64 + lg * 8;
      bf16x8 k0 = *(const bf16x8*)kp;
      bf16x8 k1 = *(const bf16x8*)(kp + 32);
      acc[nf] = MFMA16(qa[0], k0, acc[nf]);
      acc[nf] = MFMA16(qa[1], k1, acc[nf]);
    }
    #pragma unroll
    for (int nf = 0; nf < 4; nf++) {
      #pragma unroll
      for (int r = 0; r < 4; r++) {
        int qg = q0 + wid * 16 + lg * 4 + r;
        int kg = kt * 64 + nf * 16 + l15;
        float p = (kg <= qg) ? __expf(acc[nf][r] * 0.125f) * rl[r] : 0.f;
        Pf[wid][lg * 4 + r][nf * 16 + l15] = p;
      }
    }
    asm volatile("s_waitcnt lgkmcnt(0)" ::: "memory");
    __builtin_amdgcn_sched_barrier(0);
    #pragma unroll
    for (int it = 0; it < 4; ++it) {
      int pr = it * 4 + lg;
      f32x4 pv = *(f32x4*)&Pf[wid][pr][l15 * 4];
      __builtin_nontemporal_store(
          pv, (f32x4*)&attw[((size_t)bh * Tt + q0 + wid * 16 + pr) * Tt + kt * 64 + l15 * 4]);
    }
    f32x4 pf0 = *(f32x4*)&Pf[wid][l15][lg * 8];
    f32x4 pf1 = *(f32x4*)&Pf[wid][l15][lg * 8 + 4];
    f32x4 pf2 = *(f32x4*)&Pf[wid][l15][lg * 8 + 32];
    f32x4 pf3 = *(f32x4*)&Pf[wid][l15][lg * 8 + 36];
    bf16x8 pa0, pa1;
    #pragma unroll
    for (int j = 0; j < 4; j++) {
      pa0[j] = f2bf(pf0[j]); pa0[4 + j] = f2bf(pf1[j]);
      pa1[j] = f2bf(pf2[j]); pa1[4 + j] = f2bf(pf3[j]);
    }
    asm volatile("s_waitcnt vmcnt(4)" ::: "memory");
    __builtin_amdgcn_s_barrier();
    __builtin_amdgcn_sched_barrier(0);
    if (kt < tile) stageV(cur ^ 1, kt + 1);
    #pragma unroll
    for (int nf = 0; nf < 4; nf++) {
      int dA = nf * 16 + l15;
      int sw = dA & 7;
      bf16x8 vb0 = *(bf16x8*)&VtL[cur][dA * 64 + ((lg ^ sw) << 3)];
      bf16x8 vb1 = *(bf16x8*)&VtL[cur][dA * 64 + (((4 + lg) ^ sw) << 3)];
      oacc[nf] = MFMA16(pa0, vb0, oacc[nf]);
      oacc[nf] = MFMA16(pa1, vb1, oacc[nf]);
    }
  }
  #pragma unroll
  for (int nf = 0; nf < 4; nf++) {
    #pragma unroll
    for (int r = 0; r < 4; r++) {
      int t = q0 + wid * 16 + lg * 4 + r;
      ctx[((size_t)b * Tt + t) * Dd + h * 64 + nf * 16 + l15] = f2bf(oacc[nf][r]);
    }
  }
}

}  // namespace

extern "C" void kernel_launch(void* const* d_in, const int* in_sizes, int n_in,
                              void* d_out, int out_size, void* d_ws, size_t ws_size,
                              hipStream_t stream) {
  const float* x     = (const float*)d_in[0];
  const float* ln1g  = (const float*)d_in[1];
  const float* ln1b  = (const float*)d_in[2];
  const float* w_qkv = (const float*)d_in[3];
  const float* b_qkv = (const float*)d_in[4];
  const float* w_out = (const float*)d_in[5];
  const float* b_out = (const float*)d_in[6];
  const float* ln2g  = (const float*)d_in[7];
  const float* ln2b  = (const float*)d_in[8];
  const float* w_fc1 = (const float*)d_in[9];
  const float* b_fc1 = (const float*)d_in[10];
  const float* w_fc2 = (const float*)d_in[11];
  const float* b_fc2 = (const float*)d_in[12];

  char* ws = (char*)d_ws;
  size_t o = 0;
  short* wqkvT = (short*)(ws + o); o += (size_t)2304 * 768 * 2;
  short* woutT = (short*)(ws + o); o += (size_t)768 * 768 * 2;
  short* wfc1T = (short*)(ws + o); o += (size_t)3072 * 768 * 2;
  short* wfc2T = (short*)(ws + o); o += (size_t)768 * 3072 * 2;
  short* h     = (short*)(ws + o); o += (size_t)BT * Dd * 2;
  short* qkv   = (short*)(ws + o); o += (size_t)BT * 2304 * 2;
  float* y1    = (float*)(ws + o); o += (size_t)BT * Dd * 4;
  short* h2    = (short*)(ws + o); o += (size_t)BT * Dd * 2;
  short* vt    = (short*)(ws + o); o += (size_t)96 * 64 * Tt * 2;
  short* ctx  = h;     // reuse: h dead after QKV GEMM
  short* gbuf = h;     // reuse: h+qkv for GELU output (attw fully written before fc1)

  float* out_x = (float*)d_out;
  float* attw  = out_x + (size_t)BT * Dd;

  prep<<<8960, 256, 0, stream>>>(w_qkv, wqkvT, w_out, woutT, w_fc1, wfc1T,
                                 w_fc2, wfc2T, x, ln1g, ln1b, h);
  gemm_bt<0, 2304, true><<<dim3(BT / 128, 2304 / 128), 256, 0, stream>>>(
      h, wqkvT, b_qkv, nullptr, qkv, 768, vt);
  attn_fused<<<dim3(16, 96), 256, 0, stream>>>(qkv, vt, attw, ctx);
  gemm_n64k64<1, 768><<<dim3(BT / 64, 768 / 128), 256, 0, stream>>>(
      ctx, woutT, b_out, x, y1, 768);
  ln_rows<<<BT / 4, 256, 0, stream>>>(y1, ln2g, ln2b, h2);
  gemm_bt<2, 3072, false><<<dim3(BT / 128, 3072 / 128), 256, 0, stream>>>(
      h2, wfc1T, b_fc1, nullptr, gbuf, 768, nullptr);
  gemm_n64k64<3, 768><<<dim3(BT / 64, 768 / 128), 256, 0, stream>>>(
      gbuf, wfc2T, b_fc2, y1, out_x, 3072);
}

// Round 21
// 377.211 us; speedup vs baseline: 1.0957x; 1.0578x over previous
//
#include <hip/hip_runtime.h>
#include <cstdint>
#include <cstddef>

namespace {

constexpr int Bb  = 8;
constexpr int Tt  = 1024;
constexpr int Dd  = 768;
constexpr int Hh  = 12;
constexpr int DFF = 3072;
constexpr int BT  = Bb * Tt;

typedef __attribute__((ext_vector_type(8))) short bf16x8;
typedef __attribute__((ext_vector_type(4))) short bf16x4;
typedef __attribute__((ext_vector_type(4))) float f32x4;

__device__ __forceinline__ short f2bf(float f) {
  union { float f; unsigned u; } v; v.f = f;
  unsigned r = v.u + 0x7fffu + ((v.u >> 16) & 1u);   // RNE
  return (short)(r >> 16);
}
__device__ __forceinline__ float gelu_exact(float v) {
  return 0.5f * v * (1.0f + erff(v * 0.70710678118654752f));
}

#define MFMA16(a, b, c) __builtin_amdgcn_mfma_f32_16x16x32_bf16(a, b, c, 0, 0, 0)

__device__ __forceinline__ void gl_lds16(const short* g, short* l) {
  __builtin_amdgcn_global_load_lds(
      (const __attribute__((address_space(1))) unsigned int*)(g),
      (__attribute__((address_space(3))) unsigned int*)(l), 16, 0, 0);
}

// ---------- weight convert+transpose body ----------
__device__ __forceinline__ void cvt_body(float (*tile)[33],
                                         const float* __restrict__ in,
                                         short* __restrict__ out,
                                         int K, int N, int bx, int by) {
  int k0 = bx * 32, n0 = by * 32;
  int tx = threadIdx.x & 31, ty = threadIdx.x >> 5;
  #pragma unroll
  for (int r = ty; r < 32; r += 8)
    tile[r][tx] = in[(size_t)(k0 + r) * N + n0 + tx];
  __syncthreads();
  #pragma unroll
  for (int r = ty; r < 32; r += 8)
    out[(size_t)(n0 + r) * K + k0 + tx] = f2bf(tile[tx][r]);
}

// ---------- LayerNorm body ----------
__device__ __forceinline__ void ln_body(const float* __restrict__ x,
                                        const float* __restrict__ g,
                                        const float* __restrict__ b,
                                        short* __restrict__ out, int blkrow) {
  int lane = threadIdx.x & 63, wid = threadIdx.x >> 6;
  int row = blkrow * 4 + wid;
  const float* xr = x + (size_t)row * Dd;
  float v[12];
  float s = 0.f, ss = 0.f;
  #pragma unroll
  for (int c = 0; c < 3; c++) {
    float4 t = *(const float4*)&xr[c * 256 + lane * 4];
    v[c * 4 + 0] = t.x; v[c * 4 + 1] = t.y; v[c * 4 + 2] = t.z; v[c * 4 + 3] = t.w;
    s  += t.x + t.y + t.z + t.w;
    ss += t.x * t.x + t.y * t.y + t.z * t.z + t.w * t.w;
  }
  #pragma unroll
  for (int off = 1; off < 64; off <<= 1) {
    s += __shfl_xor(s, off); ss += __shfl_xor(ss, off);
  }
  float mu   = s * (1.f / Dd);
  float var  = ss * (1.f / Dd) - mu * mu;
  float rstd = rsqrtf(var + 1e-5f);
  #pragma unroll
  for (int c = 0; c < 3; c++) {
    bf16x4 o;
    #pragma unroll
    for (int j = 0; j < 4; j++) {
      int d = c * 256 + lane * 4 + j;
      o[j] = f2bf((v[c * 4 + j] - mu) * rstd * g[d] + b[d]);
    }
    *(bf16x4*)&out[(size_t)row * Dd + c * 256 + lane * 4] = o;
  }
}

// ---------- prep: 4 weight-converts + LN1 ----------
__global__ __launch_bounds__(256) void prep(const float* __restrict__ w_qkv, short* wqkvT,
                                            const float* __restrict__ w_out, short* woutT,
                                            const float* __restrict__ w_fc1, short* wfc1T,
                                            const float* __restrict__ w_fc2, short* wfc2T,
                                            const float* __restrict__ x,
                                            const float* __restrict__ g,
                                            const float* __restrict__ b,
                                            short* __restrict__ h) {
  __shared__ float tile[32][33];
  int j = blockIdx.x;
  if (j < 1728)      cvt_body(tile, w_qkv, wqkvT, 768, 2304, j % 24, j / 24);
  else if (j < 2304) { int t = j - 1728; cvt_body(tile, w_out, woutT, 768, 768, t % 24, t / 24); }
  else if (j < 4608) { int t = j - 2304; cvt_body(tile, w_fc1, wfc1T, 768, 3072, t % 24, t / 24); }
  else if (j < 6912) { int t = j - 4608; cvt_body(tile, w_fc2, wfc2T, 3072, 768, t % 96, t / 96); }
  else               ln_body(x, g, b, h, j - 6912);
}

// ---------- standalone LayerNorm (LN2) ----------
__global__ __launch_bounds__(256) void ln_rows(const float* __restrict__ x,
                                               const float* __restrict__ g,
                                               const float* __restrict__ b,
                                               short* __restrict__ out) {
  ln_body(x, g, b, out, blockIdx.x);
}

// ---------- 128x128 GEMM (QKV w/ VTR; fc1 EPI2) ----------
template <int EPI, int N, bool VTR>
__global__ __launch_bounds__(256) void gemm_bt(const short* __restrict__ A,
                                               const short* __restrict__ Bt,
                                               const float* __restrict__ bias,
                                               const float* __restrict__ add,
                                               void* __restrict__ outp,
                                               int K,
                                               short* __restrict__ vt) {
  __shared__ short S[17408];
  short* As0 = S;
  short* As1 = S + 4096;
  short* Bs0 = S + 8192;
  short* Bs1 = S + 12288;

  int nbx = gridDim.x;
  int flat = blockIdx.y * nbx + blockIdx.x;
  int cpx = (nbx * gridDim.y) >> 3;
  int swz = (flat & 7) * cpx + (flat >> 3);
  int m0 = (swz % nbx) * 128, n0 = (swz / nbx) * 128;

  int tid = threadIdx.x;
  int lane = tid & 63, wid = tid >> 6;
  int wm = wid >> 1, wn = wid & 1;
  int l15 = lane & 15, lg = lane >> 4;

  int jr = tid >> 2, jc = (tid & 3) << 3;
  int ldsb = wid << 9;

  auto stage = [&](short* Ad, short* Bd, int k0) {
    gl_lds16(&A[(size_t)(m0 + jr) * K + k0 + jc],       Ad + ldsb);
    gl_lds16(&A[(size_t)(m0 + 64 + jr) * K + k0 + jc],  Ad + 2048 + ldsb);
    gl_lds16(&Bt[(size_t)(n0 + jr) * K + k0 + jc],      Bd + ldsb);
    gl_lds16(&Bt[(size_t)(n0 + 64 + jr) * K + k0 + jc], Bd + 2048 + ldsb);
  };

  f32x4 acc[4][4] = {};
  stage(As0, Bs0, 0);
  int nk = K >> 5;
  for (int t = 0; t < nk; ++t) {
    short* Ab = (t & 1) ? As1 : As0;
    short* Bb = (t & 1) ? Bs1 : Bs0;
    if (t + 1 < nk) {
      stage((t & 1) ? As0 : As1, (t & 1) ? Bs0 : Bs1, (t + 1) << 5);
      asm volatile("s_waitcnt vmcnt(4)" ::: "memory");
    } else {
      asm volatile("s_waitcnt vmcnt(0)" ::: "memory");
    }
    __syncthreads();
    bf16x8 af[4], bfr[4];
    #pragma unroll
    for (int i = 0; i < 4; i++) af[i]  = *(bf16x8*)&Ab[(wm * 64 + i * 16 + l15) * 32 + lg * 8];
    #pragma unroll
    for (int j = 0; j < 4; j++) bfr[j] = *(bf16x8*)&Bb[(wn * 64 + j * 16 + l15) * 32 + lg * 8];
    #pragma unroll
    for (int i = 0; i < 4; i++)
      #pragma unroll
      for (int j = 0; j < 4; j++)
        acc[i][j] = MFMA16(af[i], bfr[j], acc[i][j]);
    __syncthreads();
  }

  if (EPI == 0 || EPI == 2) {
    short (*Cl)[136] = (short (*)[136])S;
    #pragma unroll
    for (int i = 0; i < 4; i++)
      #pragma unroll
      for (int j = 0; j < 4; j++)
        #pragma unroll
        for (int r = 0; r < 4; r++) {
          int row = wm * 64 + i * 16 + lg * 4 + r;
          int col = wn * 64 + j * 16 + l15;
          float vv = acc[i][j][r] + bias[n0 + col];
          if (EPI == 2) vv = gelu_exact(vv);
          int ch = col >> 3, co = col & 7;
          Cl[row][((ch ^ (row & 7)) << 3) | co] = f2bf(vv);
        }
    __syncthreads();
    if (VTR && n0 >= 1536) {
      int b = m0 >> 10, tbase = m0 & 1023;
      int h0 = (n0 - 1536) >> 6;
      #pragma unroll
      for (int half = 0; half < 2; ++half) {
        int c = (tid >> 2) + half * 64;
        int hh = c >> 6, d = c & 63;
        short* dst = vt + ((size_t)((b * Hh + h0 + hh) * 64 + d)) * Tt
                        + tbase + (tid & 3) * 32;
        #pragma unroll
        for (int j = 0; j < 4; ++j) {
          bf16x8 v8;
          #pragma unroll
          for (int k = 0; k < 8; ++k) {
            int t = (tid & 3) * 32 + j * 8 + k;
            v8[k] = Cl[t][(((c >> 3) ^ (t & 7)) << 3) | (c & 7)];
          }
          *(bf16x8*)(dst + j * 8) = v8;
        }
      }
    } else {
      int row = tid >> 1;
      int cb = (tid & 1) * 8;
      #pragma unroll
      for (int c = 0; c < 8; c++) {
        int ch = cb + c;
        bf16x8 v8 = *(bf16x8*)&Cl[row][(ch ^ (row & 7)) << 3];
        *(bf16x8*)&((short*)outp)[(size_t)(m0 + row) * N + n0 + (ch << 3)] = v8;
      }
    }
  } else {
    #pragma unroll
    for (int i = 0; i < 4; i++)
      #pragma unroll
      for (int j = 0; j < 4; j++)
        #pragma unroll
        for (int r = 0; r < 4; r++) {
          int m = m0 + wm * 64 + i * 16 + lg * 4 + r;
          int n = n0 + wn * 64 + j * 16 + l15;
          float vv = acc[i][j][r] + bias[n];
          size_t idx = (size_t)m * N + n;
          float ov = vv + add[idx];
          if (EPI == 3) __builtin_nontemporal_store(ov, &((float*)outp)[idx]);
          else          ((float*)outp)[idx] = ov;
        }
  }
}

// ---------- 64x128 GEMM, BK=64 + XOR-swizzled LDS (out-proj EPI1, fc2 EPI3) ----------
template <int EPI, int N>
__global__ __launch_bounds__(256) void gemm_n64k64(const short* __restrict__ A,
                                                   const short* __restrict__ Bt,
                                                   const float* __restrict__ bias,
                                                   const float* __restrict__ add,
                                                   void* __restrict__ outp,
                                                   int K) {
  __shared__ short S[24576];          // 49.2 KB
  short* As0 = S;
  short* As1 = S + 4096;
  short* Bs0 = S + 8192;
  short* Bs1 = S + 16384;

  int nbx = gridDim.x;
  int flat = blockIdx.y * nbx + blockIdx.x;
  int cpx = (nbx * gridDim.y) >> 3;
  int swz = (flat & 7) * cpx + (flat >> 3);
  int m0 = (swz % nbx) * 64, n0 = (swz / nbx) * 128;

  int tid = threadIdx.x;
  int lane = tid & 63, wid = tid >> 6;
  int wm = wid & 1, wn = wid >> 1;
  int l15 = lane & 15, lg = lane >> 4;

  int r8 = tid >> 3;
  int gsl = (tid & 7) ^ (r8 & 7);
  int wb = wid << 9;

  auto stage = [&](short* Ad, short* Bd, int k0) {
    #pragma unroll
    for (int c = 0; c < 2; ++c)
      gl_lds16(&A[(size_t)(m0 + c * 32 + r8) * K + k0 + gsl * 8], Ad + c * 2048 + wb);
    #pragma unroll
    for (int c = 0; c < 4; ++c)
      gl_lds16(&Bt[(size_t)(n0 + c * 32 + r8) * K + k0 + gsl * 8], Bd + c * 2048 + wb);
  };

  f32x4 acc[2][4] = {};
  stage(As0, Bs0, 0);
  int nk = K >> 6;
  for (int t = 0; t < nk; ++t) {
    short* Ab = (t & 1) ? As1 : As0;
    short* Bb = (t & 1) ? Bs1 : Bs0;
    if (t + 1 < nk) {
      stage((t & 1) ? As0 : As1, (t & 1) ? Bs0 : Bs1, (t + 1) << 6);
      asm volatile("s_waitcnt vmcnt(6)" ::: "memory");
    } else {
      asm volatile("s_waitcnt vmcnt(0)" ::: "memory");
    }
    __syncthreads();
    bf16x8 af[2][2], bfr[4][2];
    #pragma unroll
    for (int i = 0; i < 2; i++) {
      int r = wm * 32 + i * 16 + l15;
      #pragma unroll
      for (int kk = 0; kk < 2; kk++)
        af[i][kk] = *(bf16x8*)&Ab[r * 64 + (((kk * 4 + lg) ^ (r & 7)) << 3)];
    }
    #pragma unroll
    for (int j = 0; j < 4; j++) {
      int r = wn * 64 + j * 16 + l15;
      #pragma unroll
      for (int kk = 0; kk < 2; kk++)
        bfr[j][kk] = *(bf16x8*)&Bb[r * 64 + (((kk * 4 + lg) ^ (r & 7)) << 3)];
    }
    #pragma unroll
    for (int kk = 0; kk < 2; kk++)
      #pragma unroll
      for (int i = 0; i < 2; i++)
        #pragma unroll
        for (int j = 0; j < 4; j++)
          acc[i][j] = MFMA16(af[i][kk], bfr[j][kk], acc[i][j]);
    __syncthreads();
  }

  #pragma unroll
  for (int i = 0; i < 2; i++)
    #pragma unroll
    for (int j = 0; j < 4; j++)
      #pragma unroll
      for (int r = 0; r < 4; r++) {
        int m = m0 + wm * 32 + i * 16 + lg * 4 + r;
        int n = n0 + wn * 64 + j * 16 + l15;
        float vv = acc[i][j][r] + bias[n];
        size_t idx = (size_t)m * N + n;
        float ov = vv + add[idx];
        if (EPI == 3) __builtin_nontemporal_store(ov, &((float*)outp)[idx]);
        else          ((float*)outp)[idx] = ov;
      }
}

// ---------- fused causal attention (R19 + global-LPT dispatch order) ----------
// tile-rank is the OUTER dispatch dimension: all tile-15 blocks first, then
// tile-14, ... (descending LPT across the whole grid). XCD affinity kept: each
// XCD owns a fixed 12-bh set at every rank (K+vt ~3MB/XCD, L2-resident).
__global__ __launch_bounds__(256) void attn_fused(const short* __restrict__ qkv,
                                                  const short* __restrict__ vt,
                                                  float* __restrict__ attw,
                                                  short* __restrict__ ctx) {
  __shared__ short VtL[2][4096];
  __shared__ float Pf[4][16][68];
  int flat = blockIdx.y * 16 + blockIdx.x;
  int tr = flat / 96;                 // 0..15, dispatched ascending
  int rj = flat - tr * 96;            // 0..95
  int xcd = rj & 7;
  int bh  = xcd * 12 + (rj >> 3);
  int tile = 15 - tr;                 // heavy (15) first globally
  int q0 = tile * 64;
  int b = bh / Hh, h = bh % Hh;
  int tid = threadIdx.x, lane = tid & 63, wid = tid >> 6;
  int l15 = lane & 15, lg = lane >> 4;
  const short* base = qkv + (size_t)b * Tt * 2304;

  bf16x8 qa[2];
  {
    const short* qp = base + (size_t)(q0 + wid * 16 + l15) * 2304 + h * 64 + lg * 8;
    qa[0] = *(const bf16x8*)qp;
    qa[1] = *(const bf16x8*)(qp + 32);
  }

  // ---- pass 1: per-lane sumexp, zero-tile stores interleaved ----
  float l[4] = {0.f, 0.f, 0.f, 0.f};
  int nzero = 15 - tile;
  int nit = (tile + 1 > nzero) ? (tile + 1) : nzero;
  f32x4 z = {0.f, 0.f, 0.f, 0.f};
  for (int it = 0; it < nit; ++it) {
    if (it <= tile) {
      int kt = it;
      f32x4 acc[4] = {};
      #pragma unroll
      for (int nf = 0; nf < 4; ++nf) {
        const short* kp = base + (size_t)(kt * 64 + nf * 16 + l15) * 2304 + 768 + h * 64 + lg * 8;
        bf16x8 k0 = *(const bf16x8*)kp;
        bf16x8 k1 = *(const bf16x8*)(kp + 32);
        acc[nf] = MFMA16(qa[0], k0, acc[nf]);
        acc[nf] = MFMA16(qa[1], k1, acc[nf]);
      }
      #pragma unroll
      for (int r = 0; r < 4; r++) {
        int qg = q0 + wid * 16 + lg * 4 + r;
        #pragma unroll
        for (int nf = 0; nf < 4; nf++) {
          int kg = kt * 64 + nf * 16 + l15;
          l[r] += (kg <= qg) ? __expf(acc[nf][r] * 0.125f) : 0.f;
        }
      }
    }
    if (it < nzero) {
      int zt = tile + 1 + it;
      #pragma unroll
      for (int p = 0; p < 4; ++p) {
        int pr = p * 4 + lg;
        __builtin_nontemporal_store(
            z, (f32x4*)&attw[((size_t)bh * Tt + q0 + wid * 16 + pr) * Tt + zt * 64 + l15 * 4]);
      }
    }
  }
  float rl[4];
  #pragma unroll
  for (int r = 0; r < 4; r++) {
    float s = l[r];
    #pragma unroll
    for (int off = 1; off < 16; off <<= 1) s += __shfl_xor(s, off);
    rl[r] = 1.f / s;
  }

  // ---- pass 2 ----
  const short* vtb = vt + (size_t)bh * 64 * Tt;
  int dS = wid * 16 + (lane >> 3);
  int cS = (lane & 7) ^ (lane >> 3);
  auto stageV = [&](int bi, int kt) {
    gl_lds16(&vtb[(size_t)dS * Tt + kt * 64 + cS * 8],       &VtL[bi][wid * 1024]);
    gl_lds16(&vtb[(size_t)(dS + 8) * Tt + kt * 64 + cS * 8], &VtL[bi][wid * 1024 + 512]);
  };

  f32x4 oacc[4] = {};
  stageV(0, 0);
  for (int kt = 0; kt <= tile; ++kt) {
    int cur = kt & 1;
    f32x4 acc[4] = {};
    #pragma unroll
    for (int nf = 0; nf < 4; nf++) {
      const short* kp = base + (size_t)(kt * 64 + nf * 16 + l15) * 2304 + 768 + h * 64 + lg * 8;
      bf16x8 k0 = *(const bf16x8*)kp;
      bf16x8 k1 = *(const bf16x8*)(kp + 32);
      acc[nf] = MFMA16(qa[0], k0, acc[nf]);
      acc[nf] = MFMA16(qa[1], k1, acc[nf]);
    }
    #pragma unroll
    for (int nf = 0; nf < 4; nf++) {
      #pragma unroll
      for (int r = 0; r < 4; r++) {
        int qg = q0 + wid * 16 + lg * 4 + r;
        int kg = kt * 64 + nf * 16 + l15;
        float p = (kg <= qg) ? __expf(acc[nf][r] * 0.125f) * rl[r] : 0.f;
        Pf[wid][lg * 4 + r][nf * 16 + l15] = p;
      }
    }
    asm volatile("s_waitcnt lgkmcnt(0)" ::: "memory");
    __builtin_amdgcn_sched_barrier(0);
    #pragma unroll
    for (int it = 0; it < 4; ++it) {
      int pr = it * 4 + lg;
      f32x4 pv = *(f32x4*)&Pf[wid][pr][l15 * 4];
      __builtin_nontemporal_store(
          pv, (f32x4*)&attw[((size_t)bh * Tt + q0 + wid * 16 + pr) * Tt + kt * 64 + l15 * 4]);
    }
    f32x4 pf0 = *(f32x4*)&Pf[wid][l15][lg * 8];
    f32x4 pf1 = *(f32x4*)&Pf[wid][l15][lg * 8 + 4];
    f32x4 pf2 = *(f32x4*)&Pf[wid][l15][lg * 8 + 32];
    f32x4 pf3 = *(f32x4*)&Pf[wid][l15][lg * 8 + 36];
    bf16x8 pa0, pa1;
    #pragma unroll
    for (int j = 0; j < 4; j++) {
      pa0[j] = f2bf(pf0[j]); pa0[4 + j] = f2bf(pf1[j]);
      pa1[j] = f2bf(pf2[j]); pa1[4 + j] = f2bf(pf3[j]);
    }
    asm volatile("s_waitcnt vmcnt(4)" ::: "memory");
    __builtin_amdgcn_s_barrier();
    __builtin_amdgcn_sched_barrier(0);
    if (kt < tile) stageV(cur ^ 1, kt + 1);
    #pragma unroll
    for (int nf = 0; nf < 4; nf++) {
      int dA = nf * 16 + l15;
      int sw = dA & 7;
      bf16x8 vb0 = *(bf16x8*)&VtL[cur][dA * 64 + ((lg ^ sw) << 3)];
      bf16x8 vb1 = *(bf16x8*)&VtL[cur][dA * 64 + (((4 + lg) ^ sw) << 3)];
      oacc[nf] = MFMA16(pa0, vb0, oacc[nf]);
      oacc[nf] = MFMA16(pa1, vb1, oacc[nf]);
    }
  }
  #pragma unroll
  for (int nf = 0; nf < 4; nf++) {
    #pragma unroll
    for (int r = 0; r < 4; r++) {
      int t = q0 + wid * 16 + lg * 4 + r;
      ctx[((size_t)b * Tt + t) * Dd + h * 64 + nf * 16 + l15] = f2bf(oacc[nf][r]);
    }
  }
}

}  // namespace

extern "C" void kernel_launch(void* const* d_in, const int* in_sizes, int n_in,
                              void* d_out, int out_size, void* d_ws, size_t ws_size,
                              hipStream_t stream) {
  const float* x     = (const float*)d_in[0];
  const float* ln1g  = (const float*)d_in[1];
  const float* ln1b  = (const float*)d_in[2];
  const float* w_qkv = (const float*)d_in[3];
  const float* b_qkv = (const float*)d_in[4];
  const float* w_out = (const float*)d_in[5];
  const float* b_out = (const float*)d_in[6];
  const float* ln2g  = (const float*)d_in[7];
  const float* ln2b  = (const float*)d_in[8];
  const float* w_fc1 = (const float*)d_in[9];
  const float* b_fc1 = (const float*)d_in[10];
  const float* w_fc2 = (const float*)d_in[11];
  const float* b_fc2 = (const float*)d_in[12];

  char* ws = (char*)d_ws;
  size_t o = 0;
  short* wqkvT = (short*)(ws + o); o += (size_t)2304 * 768 * 2;
  short* woutT = (short*)(ws + o); o += (size_t)768 * 768 * 2;
  short* wfc1T = (short*)(ws + o); o += (size_t)3072 * 768 * 2;
  short* wfc2T = (short*)(ws + o); o += (size_t)768 * 3072 * 2;
  short* h     = (short*)(ws + o); o += (size_t)BT * Dd * 2;
  short* qkv   = (short*)(ws + o); o += (size_t)BT * 2304 * 2;
  float* y1    = (float*)(ws + o); o += (size_t)BT * Dd * 4;
  short* h2    = (short*)(ws + o); o += (size_t)BT * Dd * 2;
  short* vt    = (short*)(ws + o); o += (size_t)96 * 64 * Tt * 2;
  short* ctx  = h;     // reuse: h dead after QKV GEMM
  short* gbuf = h;     // reuse: h+qkv for GELU output (attw fully written before fc1)

  float* out_x = (float*)d_out;
  float* attw  = out_x + (size_t)BT * Dd;

  prep<<<8960, 256, 0, stream>>>(w_qkv, wqkvT, w_out, woutT, w_fc1, wfc1T,
                                 w_fc2, wfc2T, x, ln1g, ln1b, h);
  gemm_bt<0, 2304, true><<<dim3(BT / 128, 2304 / 128), 256, 0, stream>>>(
      h, wqkvT, b_qkv, nullptr, qkv, 768, vt);
  attn_fused<<<dim3(16, 96), 256, 0, stream>>>(qkv, vt, attw, ctx);
  gemm_n64k64<1, 768><<<dim3(BT / 64, 768 / 128), 256, 0, stream>>>(
      ctx, woutT, b_out, x, y1, 768);
  ln_rows<<<BT / 4, 256, 0, stream>>>(y1, ln2g, ln2b, h2);
  gemm_bt<2, 3072, false><<<dim3(BT / 128, 3072 / 128), 256, 0, stream>>>(
      h2, wfc1T, b_fc1, nullptr, gbuf, 768, nullptr);
  gemm_n64k64<3, 768><<<dim3(BT / 64, 768 / 128), 256, 0, stream>>>(
      gbuf, wfc2T, b_fc2, y1, out_x, 3072);
}

// Round 22
// 370.122 us; speedup vs baseline: 1.1167x; 1.0192x over previous
//
#include <hip/hip_runtime.h>
#include <cstdint>
#include <cstddef>

namespace {

constexpr int Bb  = 8;
constexpr int Tt  = 1024;
constexpr int Dd  = 768;
constexpr int Hh  = 12;
constexpr int DFF = 3072;
constexpr int BT  = Bb * Tt;

typedef __attribute__((ext_vector_type(8))) short bf16x8;
typedef __attribute__((ext_vector_type(4))) short bf16x4;
typedef __attribute__((ext_vector_type(4))) float f32x4;

__device__ __forceinline__ short f2bf(float f) {
  union { float f; unsigned u; } v; v.f = f;
  unsigned r = v.u + 0x7fffu + ((v.u >> 16) & 1u);   // RNE
  return (short)(r >> 16);
}
__device__ __forceinline__ float gelu_exact(float v) {
  return 0.5f * v * (1.0f + erff(v * 0.70710678118654752f));
}

#define MFMA16(a, b, c) __builtin_amdgcn_mfma_f32_16x16x32_bf16(a, b, c, 0, 0, 0)

__device__ __forceinline__ void gl_lds16(const short* g, short* l) {
  __builtin_amdgcn_global_load_lds(
      (const __attribute__((address_space(1))) unsigned int*)(g),
      (__attribute__((address_space(3))) unsigned int*)(l), 16, 0, 0);
}

// ---------- weight convert+transpose body ----------
__device__ __forceinline__ void cvt_body(float (*tile)[33],
                                         const float* __restrict__ in,
                                         short* __restrict__ out,
                                         int K, int N, int bx, int by) {
  int k0 = bx * 32, n0 = by * 32;
  int tx = threadIdx.x & 31, ty = threadIdx.x >> 5;
  #pragma unroll
  for (int r = ty; r < 32; r += 8)
    tile[r][tx] = in[(size_t)(k0 + r) * N + n0 + tx];
  __syncthreads();
  #pragma unroll
  for (int r = ty; r < 32; r += 8)
    out[(size_t)(n0 + r) * K + k0 + tx] = f2bf(tile[tx][r]);
}

// ---------- LayerNorm body ----------
__device__ __forceinline__ void ln_body(const float* __restrict__ x,
                                        const float* __restrict__ g,
                                        const float* __restrict__ b,
                                        short* __restrict__ out, int blkrow) {
  int lane = threadIdx.x & 63, wid = threadIdx.x >> 6;
  int row = blkrow * 4 + wid;
  const float* xr = x + (size_t)row * Dd;
  float v[12];
  float s = 0.f, ss = 0.f;
  #pragma unroll
  for (int c = 0; c < 3; c++) {
    float4 t = *(const float4*)&xr[c * 256 + lane * 4];
    v[c * 4 + 0] = t.x; v[c * 4 + 1] = t.y; v[c * 4 + 2] = t.z; v[c * 4 + 3] = t.w;
    s  += t.x + t.y + t.z + t.w;
    ss += t.x * t.x + t.y * t.y + t.z * t.z + t.w * t.w;
  }
  #pragma unroll
  for (int off = 1; off < 64; off <<= 1) {
    s += __shfl_xor(s, off); ss += __shfl_xor(ss, off);
  }
  float mu   = s * (1.f / Dd);
  float var  = ss * (1.f / Dd) - mu * mu;
  float rstd = rsqrtf(var + 1e-5f);
  #pragma unroll
  for (int c = 0; c < 3; c++) {
    bf16x4 o;
    #pragma unroll
    for (int j = 0; j < 4; j++) {
      int d = c * 256 + lane * 4 + j;
      o[j] = f2bf((v[c * 4 + j] - mu) * rstd * g[d] + b[d]);
    }
    *(bf16x4*)&out[(size_t)row * Dd + c * 256 + lane * 4] = o;
  }
}

// ---------- prep: 4 weight-converts + LN1 ----------
__global__ __launch_bounds__(256) void prep(const float* __restrict__ w_qkv, short* wqkvT,
                                            const float* __restrict__ w_out, short* woutT,
                                            const float* __restrict__ w_fc1, short* wfc1T,
                                            const float* __restrict__ w_fc2, short* wfc2T,
                                            const float* __restrict__ x,
                                            const float* __restrict__ g,
                                            const float* __restrict__ b,
                                            short* __restrict__ h) {
  __shared__ float tile[32][33];
  int j = blockIdx.x;
  if (j < 1728)      cvt_body(tile, w_qkv, wqkvT, 768, 2304, j % 24, j / 24);
  else if (j < 2304) { int t = j - 1728; cvt_body(tile, w_out, woutT, 768, 768, t % 24, t / 24); }
  else if (j < 4608) { int t = j - 2304; cvt_body(tile, w_fc1, wfc1T, 768, 3072, t % 24, t / 24); }
  else if (j < 6912) { int t = j - 4608; cvt_body(tile, w_fc2, wfc2T, 3072, 768, t % 96, t / 96); }
  else               ln_body(x, g, b, h, j - 6912);
}

// ---------- standalone LayerNorm (LN2) ----------
__global__ __launch_bounds__(256) void ln_rows(const float* __restrict__ x,
                                               const float* __restrict__ g,
                                               const float* __restrict__ b,
                                               short* __restrict__ out) {
  ln_body(x, g, b, out, blockIdx.x);
}

// ---------- 128x128 GEMM (QKV w/ VTR; fc1 EPI2) ----------
template <int EPI, int N, bool VTR>
__global__ __launch_bounds__(256) void gemm_bt(const short* __restrict__ A,
                                               const short* __restrict__ Bt,
                                               const float* __restrict__ bias,
                                               const float* __restrict__ add,
                                               void* __restrict__ outp,
                                               int K,
                                               short* __restrict__ vt) {
  __shared__ short S[17408];
  short* As0 = S;
  short* As1 = S + 4096;
  short* Bs0 = S + 8192;
  short* Bs1 = S + 12288;

  int nbx = gridDim.x;
  int flat = blockIdx.y * nbx + blockIdx.x;
  int cpx = (nbx * gridDim.y) >> 3;
  int swz = (flat & 7) * cpx + (flat >> 3);
  int m0 = (swz % nbx) * 128, n0 = (swz / nbx) * 128;

  int tid = threadIdx.x;
  int lane = tid & 63, wid = tid >> 6;
  int wm = wid >> 1, wn = wid & 1;
  int l15 = lane & 15, lg = lane >> 4;

  int jr = tid >> 2, jc = (tid & 3) << 3;
  int ldsb = wid << 9;

  auto stage = [&](short* Ad, short* Bd, int k0) {
    gl_lds16(&A[(size_t)(m0 + jr) * K + k0 + jc],       Ad + ldsb);
    gl_lds16(&A[(size_t)(m0 + 64 + jr) * K + k0 + jc],  Ad + 2048 + ldsb);
    gl_lds16(&Bt[(size_t)(n0 + jr) * K + k0 + jc],      Bd + ldsb);
    gl_lds16(&Bt[(size_t)(n0 + 64 + jr) * K + k0 + jc], Bd + 2048 + ldsb);
  };

  f32x4 acc[4][4] = {};
  stage(As0, Bs0, 0);
  int nk = K >> 5;
  for (int t = 0; t < nk; ++t) {
    short* Ab = (t & 1) ? As1 : As0;
    short* Bb = (t & 1) ? Bs1 : Bs0;
    if (t + 1 < nk) {
      stage((t & 1) ? As0 : As1, (t & 1) ? Bs0 : Bs1, (t + 1) << 5);
      asm volatile("s_waitcnt vmcnt(4)" ::: "memory");
    } else {
      asm volatile("s_waitcnt vmcnt(0)" ::: "memory");
    }
    __syncthreads();
    bf16x8 af[4], bfr[4];
    #pragma unroll
    for (int i = 0; i < 4; i++) af[i]  = *(bf16x8*)&Ab[(wm * 64 + i * 16 + l15) * 32 + lg * 8];
    #pragma unroll
    for (int j = 0; j < 4; j++) bfr[j] = *(bf16x8*)&Bb[(wn * 64 + j * 16 + l15) * 32 + lg * 8];
    #pragma unroll
    for (int i = 0; i < 4; i++)
      #pragma unroll
      for (int j = 0; j < 4; j++)
        acc[i][j] = MFMA16(af[i], bfr[j], acc[i][j]);
    __syncthreads();
  }

  if (EPI == 0 || EPI == 2) {
    short (*Cl)[136] = (short (*)[136])S;
    #pragma unroll
    for (int i = 0; i < 4; i++)
      #pragma unroll
      for (int j = 0; j < 4; j++)
        #pragma unroll
        for (int r = 0; r < 4; r++) {
          int row = wm * 64 + i * 16 + lg * 4 + r;
          int col = wn * 64 + j * 16 + l15;
          float vv = acc[i][j][r] + bias[n0 + col];
          if (EPI == 2) vv = gelu_exact(vv);
          int ch = col >> 3, co = col & 7;
          Cl[row][((ch ^ (row & 7)) << 3) | co] = f2bf(vv);
        }
    __syncthreads();
    if (VTR && n0 >= 1536) {
      int b = m0 >> 10, tbase = m0 & 1023;
      int h0 = (n0 - 1536) >> 6;
      #pragma unroll
      for (int half = 0; half < 2; ++half) {
        int c = (tid >> 2) + half * 64;
        int hh = c >> 6, d = c & 63;
        short* dst = vt + ((size_t)((b * Hh + h0 + hh) * 64 + d)) * Tt
                        + tbase + (tid & 3) * 32;
        #pragma unroll
        for (int j = 0; j < 4; ++j) {
          bf16x8 v8;
          #pragma unroll
          for (int k = 0; k < 8; ++k) {
            int t = (tid & 3) * 32 + j * 8 + k;
            v8[k] = Cl[t][(((c >> 3) ^ (t & 7)) << 3) | (c & 7)];
          }
          *(bf16x8*)(dst + j * 8) = v8;
        }
      }
    } else {
      int row = tid >> 1;
      int cb = (tid & 1) * 8;
      #pragma unroll
      for (int c = 0; c < 8; c++) {
        int ch = cb + c;
        bf16x8 v8 = *(bf16x8*)&Cl[row][(ch ^ (row & 7)) << 3];
        *(bf16x8*)&((short*)outp)[(size_t)(m0 + row) * N + n0 + (ch << 3)] = v8;
      }
    }
  } else {
    #pragma unroll
    for (int i = 0; i < 4; i++)
      #pragma unroll
      for (int j = 0; j < 4; j++)
        #pragma unroll
        for (int r = 0; r < 4; r++) {
          int m = m0 + wm * 64 + i * 16 + lg * 4 + r;
          int n = n0 + wn * 64 + j * 16 + l15;
          float vv = acc[i][j][r] + bias[n];
          size_t idx = (size_t)m * N + n;
          float ov = vv + add[idx];
          if (EPI == 3) __builtin_nontemporal_store(ov, &((float*)outp)[idx]);
          else          ((float*)outp)[idx] = ov;
        }
  }
}

// ---------- 64x128 GEMM, BK=64 + XOR-swizzled LDS (out-proj EPI1, fc2 EPI3) ----------
template <int EPI, int N>
__global__ __launch_bounds__(256) void gemm_n64k64(const short* __restrict__ A,
                                                   const short* __restrict__ Bt,
                                                   const float* __restrict__ bias,
                                                   const float* __restrict__ add,
                                                   void* __restrict__ outp,
                                                   int K) {
  __shared__ short S[24576];          // 49.2 KB
  short* As0 = S;
  short* As1 = S + 4096;
  short* Bs0 = S + 8192;
  short* Bs1 = S + 16384;

  int nbx = gridDim.x;
  int flat = blockIdx.y * nbx + blockIdx.x;
  int cpx = (nbx * gridDim.y) >> 3;
  int swz = (flat & 7) * cpx + (flat >> 3);
  int m0 = (swz % nbx) * 64, n0 = (swz / nbx) * 128;

  int tid = threadIdx.x;
  int lane = tid & 63, wid = tid >> 6;
  int wm = wid & 1, wn = wid >> 1;
  int l15 = lane & 15, lg = lane >> 4;

  int r8 = tid >> 3;
  int gsl = (tid & 7) ^ (r8 & 7);
  int wb = wid << 9;

  auto stage = [&](short* Ad, short* Bd, int k0) {
    #pragma unroll
    for (int c = 0; c < 2; ++c)
      gl_lds16(&A[(size_t)(m0 + c * 32 + r8) * K + k0 + gsl * 8], Ad + c * 2048 + wb);
    #pragma unroll
    for (int c = 0; c < 4; ++c)
      gl_lds16(&Bt[(size_t)(n0 + c * 32 + r8) * K + k0 + gsl * 8], Bd + c * 2048 + wb);
  };

  f32x4 acc[2][4] = {};
  stage(As0, Bs0, 0);
  int nk = K >> 6;
  for (int t = 0; t < nk; ++t) {
    short* Ab = (t & 1) ? As1 : As0;
    short* Bb = (t & 1) ? Bs1 : Bs0;
    if (t + 1 < nk) {
      stage((t & 1) ? As0 : As1, (t & 1) ? Bs0 : Bs1, (t + 1) << 6);
      asm volatile("s_waitcnt vmcnt(6)" ::: "memory");
    } else {
      asm volatile("s_waitcnt vmcnt(0)" ::: "memory");
    }
    __syncthreads();
    bf16x8 af[2][2], bfr[4][2];
    #pragma unroll
    for (int i = 0; i < 2; i++) {
      int r = wm * 32 + i * 16 + l15;
      #pragma unroll
      for (int kk = 0; kk < 2; kk++)
        af[i][kk] = *(bf16x8*)&Ab[r * 64 + (((kk * 4 + lg) ^ (r & 7)) << 3)];
    }
    #pragma unroll
    for (int j = 0; j < 4; j++) {
      int r = wn * 64 + j * 16 + l15;
      #pragma unroll
      for (int kk = 0; kk < 2; kk++)
        bfr[j][kk] = *(bf16x8*)&Bb[r * 64 + (((kk * 4 + lg) ^ (r & 7)) << 3)];
    }
    #pragma unroll
    for (int kk = 0; kk < 2; kk++)
      #pragma unroll
      for (int i = 0; i < 2; i++)
        #pragma unroll
        for (int j = 0; j < 4; j++)
          acc[i][j] = MFMA16(af[i][kk], bfr[j][kk], acc[i][j]);
    __syncthreads();
  }

  #pragma unroll
  for (int i = 0; i < 2; i++)
    #pragma unroll
    for (int j = 0; j < 4; j++)
      #pragma unroll
      for (int r = 0; r < 4; r++) {
        int m = m0 + wm * 32 + i * 16 + lg * 4 + r;
        int n = n0 + wn * 64 + j * 16 + l15;
        float vv = acc[i][j][r] + bias[n];
        size_t idx = (size_t)m * N + n;
        float ov = vv + add[idx];
        if (EPI == 3) __builtin_nontemporal_store(ov, &((float*)outp)[idx]);
        else          ((float*)outp)[idx] = ov;
      }
}

// ---------- fused causal attention (R20 + complementary tile-pairing) ----------
// 768 blocks; each processes q-tiles {15-pair, pair} serially -> every block
// has EXACTLY 17 compute iterations + 15 zero tiles (perfect balance), and the
// whole grid is co-resident at 4 blocks/CU. XCD affinity preserved.
__global__ __launch_bounds__(256) void attn_fused(const short* __restrict__ qkv,
                                                  const short* __restrict__ vt,
                                                  float* __restrict__ attw,
                                                  short* __restrict__ ctx) {
  __shared__ short VtL[2][4096];
  __shared__ float Pf[4][16][68];
  int flat = blockIdx.y * 8 + blockIdx.x;
  int xcd = flat & 7;
  int rr  = flat >> 3;                 // 0..95
  int bh  = xcd * 12 + (rr % 12);
  int pair = rr / 12;                  // 0..7
  int b = bh / Hh, h = bh % Hh;
  int tid = threadIdx.x, lane = tid & 63, wid = tid >> 6;
  int l15 = lane & 15, lg = lane >> 4;
  const short* base = qkv + (size_t)b * Tt * 2304;
  const short* vtb = vt + (size_t)bh * 64 * Tt;
  int dS = wid * 16 + (lane >> 3);
  int cS = (lane & 7) ^ (lane >> 3);

  #pragma unroll 1
  for (int sub = 0; sub < 2; ++sub) {
    int tile = sub == 0 ? 15 - pair : pair;
    int q0 = tile * 64;

    bf16x8 qa[2];
    {
      const short* qp = base + (size_t)(q0 + wid * 16 + l15) * 2304 + h * 64 + lg * 8;
      qa[0] = *(const bf16x8*)qp;
      qa[1] = *(const bf16x8*)(qp + 32);
    }

    // ---- pass 1: per-lane sumexp, zero-tile stores interleaved ----
    float l[4] = {0.f, 0.f, 0.f, 0.f};
    int nzero = 15 - tile;
    int nit = (tile + 1 > nzero) ? (tile + 1) : nzero;
    f32x4 z = {0.f, 0.f, 0.f, 0.f};
    for (int it = 0; it < nit; ++it) {
      if (it <= tile) {
        int kt = it;
        f32x4 acc[4] = {};
        #pragma unroll
        for (int nf = 0; nf < 4; ++nf) {
          const short* kp = base + (size_t)(kt * 64 + nf * 16 + l15) * 2304 + 768 + h * 64 + lg * 8;
          bf16x8 k0 = *(const bf16x8*)kp;
          bf16x8 k1 = *(const bf16x8*)(kp + 32);
          acc[nf] = MFMA16(qa[0], k0, acc[nf]);
          acc[nf] = MFMA16(qa[1], k1, acc[nf]);
        }
        #pragma unroll
        for (int r = 0; r < 4; r++) {
          int qg = q0 + wid * 16 + lg * 4 + r;
          #pragma unroll
          for (int nf = 0; nf < 4; nf++) {
            int kg = kt * 64 + nf * 16 + l15;
            l[r] += (kg <= qg) ? __expf(acc[nf][r] * 0.125f) : 0.f;
          }
        }
      }
      if (it < nzero) {
        int zt = tile + 1 + it;
        #pragma unroll
        for (int p = 0; p < 4; ++p) {
          int pr = p * 4 + lg;
          __builtin_nontemporal_store(
              z, (f32x4*)&attw[((size_t)bh * Tt + q0 + wid * 16 + pr) * Tt + zt * 64 + l15 * 4]);
        }
      }
    }
    float rl[4];
    #pragma unroll
    for (int r = 0; r < 4; r++) {
      float s = l[r];
      #pragma unroll
      for (int off = 1; off < 16; off <<= 1) s += __shfl_xor(s, off);
      rl[r] = 1.f / s;
    }

    // ---- pass 2 ----
    f32x4 oacc[4] = {};
    stageV: ;
    {
      // protect VtL reuse across sub-jobs (all waves done reading prior VtL)
      __syncthreads();
      gl_lds16(&vtb[(size_t)dS * Tt + 0 + cS * 8],            &VtL[0][wid * 1024]);
      gl_lds16(&vtb[(size_t)(dS + 8) * Tt + 0 + cS * 8],      &VtL[0][wid * 1024 + 512]);
    }
    for (int kt = 0; kt <= tile; ++kt) {
      int cur = kt & 1;
      f32x4 acc[4] = {};
      #pragma unroll
      for (int nf = 0; nf < 4; nf++) {
        const short* kp = base + (size_t)(kt * 64 + nf * 16 + l15) * 2304 + 768 + h * 64 + lg * 8;
        bf16x8 k0 = *(const bf16x8*)kp;
        bf16x8 k1 = *(const bf16x8*)(kp + 32);
        acc[nf] = MFMA16(qa[0], k0, acc[nf]);
        acc[nf] = MFMA16(qa[1], k1, acc[nf]);
      }
      #pragma unroll
      for (int nf = 0; nf < 4; nf++) {
        #pragma unroll
        for (int r = 0; r < 4; r++) {
          int qg = q0 + wid * 16 + lg * 4 + r;
          int kg = kt * 64 + nf * 16 + l15;
          float p = (kg <= qg) ? __expf(acc[nf][r] * 0.125f) * rl[r] : 0.f;
          Pf[wid][lg * 4 + r][nf * 16 + l15] = p;
        }
      }
      asm volatile("s_waitcnt lgkmcnt(0)" ::: "memory");
      __builtin_amdgcn_sched_barrier(0);
      #pragma unroll
      for (int it = 0; it < 4; ++it) {
        int pr = it * 4 + lg;
        f32x4 pv = *(f32x4*)&Pf[wid][pr][l15 * 4];
        __builtin_nontemporal_store(
            pv, (f32x4*)&attw[((size_t)bh * Tt + q0 + wid * 16 + pr) * Tt + kt * 64 + l15 * 4]);
      }
      f32x4 pf0 = *(f32x4*)&Pf[wid][l15][lg * 8];
      f32x4 pf1 = *(f32x4*)&Pf[wid][l15][lg * 8 + 4];
      f32x4 pf2 = *(f32x4*)&Pf[wid][l15][lg * 8 + 32];
      f32x4 pf3 = *(f32x4*)&Pf[wid][l15][lg * 8 + 36];
      bf16x8 pa0, pa1;
      #pragma unroll
      for (int j = 0; j < 4; j++) {
        pa0[j] = f2bf(pf0[j]); pa0[4 + j] = f2bf(pf1[j]);
        pa1[j] = f2bf(pf2[j]); pa1[4 + j] = f2bf(pf3[j]);
      }
      asm volatile("s_waitcnt vmcnt(4)" ::: "memory");
      __builtin_amdgcn_s_barrier();
      __builtin_amdgcn_sched_barrier(0);
      if (kt < tile) {
        int nx = cur ^ 1, nkt = kt + 1;
        gl_lds16(&vtb[(size_t)dS * Tt + nkt * 64 + cS * 8],       &VtL[nx][wid * 1024]);
        gl_lds16(&vtb[(size_t)(dS + 8) * Tt + nkt * 64 + cS * 8], &VtL[nx][wid * 1024 + 512]);
      }
      #pragma unroll
      for (int nf = 0; nf < 4; nf++) {
        int dA = nf * 16 + l15;
        int sw = dA & 7;
        bf16x8 vb0 = *(bf16x8*)&VtL[cur][dA * 64 + ((lg ^ sw) << 3)];
        bf16x8 vb1 = *(bf16x8*)&VtL[cur][dA * 64 + (((4 + lg) ^ sw) << 3)];
        oacc[nf] = MFMA16(pa0, vb0, oacc[nf]);
        oacc[nf] = MFMA16(pa1, vb1, oacc[nf]);
      }
    }
    #pragma unroll
    for (int nf = 0; nf < 4; nf++) {
      #pragma unroll
      for (int r = 0; r < 4; r++) {
        int t = q0 + wid * 16 + lg * 4 + r;
        ctx[((size_t)b * Tt + t) * Dd + h * 64 + nf * 16 + l15] = f2bf(oacc[nf][r]);
      }
    }
  }
}

}  // namespace

extern "C" void kernel_launch(void* const* d_in, const int* in_sizes, int n_in,
                              void* d_out, int out_size, void* d_ws, size_t ws_size,
                              hipStream_t stream) {
  const float* x     = (const float*)d_in[0];
  const float* ln1g  = (const float*)d_in[1];
  const float* ln1b  = (const float*)d_in[2];
  const float* w_qkv = (const float*)d_in[3];
  const float* b_qkv = (const float*)d_in[4];
  const float* w_out = (const float*)d_in[5];
  const float* b_out = (const float*)d_in[6];
  const float* ln2g  = (const float*)d_in[7];
  const float* ln2b  = (const float*)d_in[8];
  const float* w_fc1 = (const float*)d_in[9];
  const float* b_fc1 = (const float*)d_in[10];
  const float* w_fc2 = (const float*)d_in[11];
  const float* b_fc2 = (const float*)d_in[12];

  char* ws = (char*)d_ws;
  size_t o = 0;
  short* wqkvT = (short*)(ws + o); o += (size_t)2304 * 768 * 2;
  short* woutT = (short*)(ws + o); o += (size_t)768 * 768 * 2;
  short* wfc1T = (short*)(ws + o); o += (size_t)3072 * 768 * 2;
  short* wfc2T = (short*)(ws + o); o += (size_t)768 * 3072 * 2;
  short* h     = (short*)(ws + o); o += (size_t)BT * Dd * 2;
  short* qkv   = (short*)(ws + o); o += (size_t)BT * 2304 * 2;
  float* y1    = (float*)(ws + o); o += (size_t)BT * Dd * 4;
  short* h2    = (short*)(ws + o); o += (size_t)BT * Dd * 2;
  short* vt    = (short*)(ws + o); o += (size_t)96 * 64 * Tt * 2;
  short* ctx  = h;     // reuse: h dead after QKV GEMM
  short* gbuf = h;     // reuse: h+qkv for GELU output (attw fully written before fc1)

  float* out_x = (float*)d_out;
  float* attw  = out_x + (size_t)BT * Dd;

  prep<<<8960, 256, 0, stream>>>(w_qkv, wqkvT, w_out, woutT, w_fc1, wfc1T,
                                 w_fc2, wfc2T, x, ln1g, ln1b, h);
  gemm_bt<0, 2304, true><<<dim3(BT / 128, 2304 / 128), 256, 0, stream>>>(
      h, wqkvT, b_qkv, nullptr, qkv, 768, vt);
  attn_fused<<<dim3(8, 96), 256, 0, stream>>>(qkv, vt, attw, ctx);
  gemm_n64k64<1, 768><<<dim3(BT / 64, 768 / 128), 256, 0, stream>>>(
      ctx, woutT, b_out, x, y1, 768);
  ln_rows<<<BT / 4, 256, 0, stream>>>(y1, ln2g, ln2b, h2);
  gemm_bt<2, 3072, false><<<dim3(BT / 128, 3072 / 128), 256, 0, stream>>>(
      h2, wfc1T, b_fc1, nullptr, gbuf, 768, nullptr);
  gemm_n64k64<3, 768><<<dim3(BT / 64, 768 / 128), 256, 0, stream>>>(
      gbuf, wfc2T, b_fc2, y1, out_x, 3072);
}

// Round 23
// 369.796 us; speedup vs baseline: 1.1176x; 1.0009x over previous
//
#include <hip/hip_runtime.h>
#include <cstdint>
#include <cstddef>

namespace {

constexpr int Bb  = 8;
constexpr int Tt  = 1024;
constexpr int Dd  = 768;
constexpr int Hh  = 12;
constexpr int DFF = 3072;
constexpr int BT  = Bb * Tt;

typedef __attribute__((ext_vector_type(8))) short bf16x8;
typedef __attribute__((ext_vector_type(4))) short bf16x4;
typedef __attribute__((ext_vector_type(4))) float f32x4;

__device__ __forceinline__ short f2bf(float f) {
  union { float f; unsigned u; } v; v.f = f;
  unsigned r = v.u + 0x7fffu + ((v.u >> 16) & 1u);   // RNE
  return (short)(r >> 16);
}
__device__ __forceinline__ float gelu_exact(float v) {
  return 0.5f * v * (1.0f + erff(v * 0.70710678118654752f));
}

#define MFMA16(a, b, c) __builtin_amdgcn_mfma_f32_16x16x32_bf16(a, b, c, 0, 0, 0)

__device__ __forceinline__ void gl_lds16(const short* g, short* l) {
  __builtin_amdgcn_global_load_lds(
      (const __attribute__((address_space(1))) unsigned int*)(g),
      (__attribute__((address_space(3))) unsigned int*)(l), 16, 0, 0);
}

// ---------- weight convert+transpose body ----------
__device__ __forceinline__ void cvt_body(float (*tile)[33],
                                         const float* __restrict__ in,
                                         short* __restrict__ out,
                                         int K, int N, int bx, int by) {
  int k0 = bx * 32, n0 = by * 32;
  int tx = threadIdx.x & 31, ty = threadIdx.x >> 5;
  #pragma unroll
  for (int r = ty; r < 32; r += 8)
    tile[r][tx] = in[(size_t)(k0 + r) * N + n0 + tx];
  __syncthreads();
  #pragma unroll
  for (int r = ty; r < 32; r += 8)
    out[(size_t)(n0 + r) * K + k0 + tx] = f2bf(tile[tx][r]);
}

// ---------- LayerNorm body ----------
__device__ __forceinline__ void ln_body(const float* __restrict__ x,
                                        const float* __restrict__ g,
                                        const float* __restrict__ b,
                                        short* __restrict__ out, int blkrow) {
  int lane = threadIdx.x & 63, wid = threadIdx.x >> 6;
  int row = blkrow * 4 + wid;
  const float* xr = x + (size_t)row * Dd;
  float v[12];
  float s = 0.f, ss = 0.f;
  #pragma unroll
  for (int c = 0; c < 3; c++) {
    float4 t = *(const float4*)&xr[c * 256 + lane * 4];
    v[c * 4 + 0] = t.x; v[c * 4 + 1] = t.y; v[c * 4 + 2] = t.z; v[c * 4 + 3] = t.w;
    s  += t.x + t.y + t.z + t.w;
    ss += t.x * t.x + t.y * t.y + t.z * t.z + t.w * t.w;
  }
  #pragma unroll
  for (int off = 1; off < 64; off <<= 1) {
    s += __shfl_xor(s, off); ss += __shfl_xor(ss, off);
  }
  float mu   = s * (1.f / Dd);
  float var  = ss * (1.f / Dd) - mu * mu;
  float rstd = rsqrtf(var + 1e-5f);
  #pragma unroll
  for (int c = 0; c < 3; c++) {
    bf16x4 o;
    #pragma unroll
    for (int j = 0; j < 4; j++) {
      int d = c * 256 + lane * 4 + j;
      o[j] = f2bf((v[c * 4 + j] - mu) * rstd * g[d] + b[d]);
    }
    *(bf16x4*)&out[(size_t)row * Dd + c * 256 + lane * 4] = o;
  }
}

// ---------- prep: 4 weight-converts + LN1 ----------
__global__ __launch_bounds__(256) void prep(const float* __restrict__ w_qkv, short* wqkvT,
                                            const float* __restrict__ w_out, short* woutT,
                                            const float* __restrict__ w_fc1, short* wfc1T,
                                            const float* __restrict__ w_fc2, short* wfc2T,
                                            const float* __restrict__ x,
                                            const float* __restrict__ g,
                                            const float* __restrict__ b,
                                            short* __restrict__ h) {
  __shared__ float tile[32][33];
  int j = blockIdx.x;
  if (j < 1728)      cvt_body(tile, w_qkv, wqkvT, 768, 2304, j % 24, j / 24);
  else if (j < 2304) { int t = j - 1728; cvt_body(tile, w_out, woutT, 768, 768, t % 24, t / 24); }
  else if (j < 4608) { int t = j - 2304; cvt_body(tile, w_fc1, wfc1T, 768, 3072, t % 24, t / 24); }
  else if (j < 6912) { int t = j - 4608; cvt_body(tile, w_fc2, wfc2T, 3072, 768, t % 96, t / 96); }
  else               ln_body(x, g, b, h, j - 6912);
}

// ---------- standalone LayerNorm (LN2) ----------
__global__ __launch_bounds__(256) void ln_rows(const float* __restrict__ x,
                                               const float* __restrict__ g,
                                               const float* __restrict__ b,
                                               short* __restrict__ out) {
  ln_body(x, g, b, out, blockIdx.x);
}

// ---------- 128x128 GEMM (QKV w/ VTR+KPK; fc1 EPI2) ----------
// VTR: V tiles (n0>=1536) -> vt transposed; K tiles (768<=n0<1536) -> kp
// packed [bh][t][64] (contiguous 128B/token-head); Q tiles -> qkv.
template <int EPI, int N, bool VTR>
__global__ __launch_bounds__(256) void gemm_bt(const short* __restrict__ A,
                                               const short* __restrict__ Bt,
                                               const float* __restrict__ bias,
                                               const float* __restrict__ add,
                                               void* __restrict__ outp,
                                               int K,
                                               short* __restrict__ vt,
                                               short* __restrict__ kp) {
  __shared__ short S[17408];
  short* As0 = S;
  short* As1 = S + 4096;
  short* Bs0 = S + 8192;
  short* Bs1 = S + 12288;

  int nbx = gridDim.x;
  int flat = blockIdx.y * nbx + blockIdx.x;
  int cpx = (nbx * gridDim.y) >> 3;
  int swz = (flat & 7) * cpx + (flat >> 3);
  int m0 = (swz % nbx) * 128, n0 = (swz / nbx) * 128;

  int tid = threadIdx.x;
  int lane = tid & 63, wid = tid >> 6;
  int wm = wid >> 1, wn = wid & 1;
  int l15 = lane & 15, lg = lane >> 4;

  int jr = tid >> 2, jc = (tid & 3) << 3;
  int ldsb = wid << 9;

  auto stage = [&](short* Ad, short* Bd, int k0) {
    gl_lds16(&A[(size_t)(m0 + jr) * K + k0 + jc],       Ad + ldsb);
    gl_lds16(&A[(size_t)(m0 + 64 + jr) * K + k0 + jc],  Ad + 2048 + ldsb);
    gl_lds16(&Bt[(size_t)(n0 + jr) * K + k0 + jc],      Bd + ldsb);
    gl_lds16(&Bt[(size_t)(n0 + 64 + jr) * K + k0 + jc], Bd + 2048 + ldsb);
  };

  f32x4 acc[4][4] = {};
  stage(As0, Bs0, 0);
  int nk = K >> 5;
  for (int t = 0; t < nk; ++t) {
    short* Ab = (t & 1) ? As1 : As0;
    short* Bb = (t & 1) ? Bs1 : Bs0;
    if (t + 1 < nk) {
      stage((t & 1) ? As0 : As1, (t & 1) ? Bs0 : Bs1, (t + 1) << 5);
      asm volatile("s_waitcnt vmcnt(4)" ::: "memory");
    } else {
      asm volatile("s_waitcnt vmcnt(0)" ::: "memory");
    }
    __syncthreads();
    bf16x8 af[4], bfr[4];
    #pragma unroll
    for (int i = 0; i < 4; i++) af[i]  = *(bf16x8*)&Ab[(wm * 64 + i * 16 + l15) * 32 + lg * 8];
    #pragma unroll
    for (int j = 0; j < 4; j++) bfr[j] = *(bf16x8*)&Bb[(wn * 64 + j * 16 + l15) * 32 + lg * 8];
    #pragma unroll
    for (int i = 0; i < 4; i++)
      #pragma unroll
      for (int j = 0; j < 4; j++)
        acc[i][j] = MFMA16(af[i], bfr[j], acc[i][j]);
    __syncthreads();
  }

  if (EPI == 0 || EPI == 2) {
    short (*Cl)[136] = (short (*)[136])S;
    #pragma unroll
    for (int i = 0; i < 4; i++)
      #pragma unroll
      for (int j = 0; j < 4; j++)
        #pragma unroll
        for (int r = 0; r < 4; r++) {
          int row = wm * 64 + i * 16 + lg * 4 + r;
          int col = wn * 64 + j * 16 + l15;
          float vv = acc[i][j][r] + bias[n0 + col];
          if (EPI == 2) vv = gelu_exact(vv);
          int ch = col >> 3, co = col & 7;
          Cl[row][((ch ^ (row & 7)) << 3) | co] = f2bf(vv);
        }
    __syncthreads();
    if (VTR && n0 >= 1536) {
      // V: transposed store vt[(b*12+h)*64 + d][tbase + t]
      int b = m0 >> 10, tbase = m0 & 1023;
      int h0 = (n0 - 1536) >> 6;
      #pragma unroll
      for (int half = 0; half < 2; ++half) {
        int c = (tid >> 2) + half * 64;
        int hh = c >> 6, d = c & 63;
        short* dst = vt + ((size_t)((b * Hh + h0 + hh) * 64 + d)) * Tt
                        + tbase + (tid & 3) * 32;
        #pragma unroll
        for (int j = 0; j < 4; ++j) {
          bf16x8 v8;
          #pragma unroll
          for (int k = 0; k < 8; ++k) {
            int t = (tid & 3) * 32 + j * 8 + k;
            v8[k] = Cl[t][(((c >> 3) ^ (t & 7)) << 3) | (c & 7)];
          }
          *(bf16x8*)(dst + j * 8) = v8;
        }
      }
    } else if (VTR && n0 >= 768) {
      // K: packed store kp[(b*12+h)*1024 + t][64] (128B contiguous per thread)
      int b = m0 >> 10, tbase = m0 & 1023;
      int h0 = (n0 - 768) >> 6;
      int row = tid >> 1;            // token row 0..127
      int hh = tid & 1;              // head within tile
      short* dst = kp + ((size_t)((b * Hh + h0 + hh) * Tt) + tbase + row) * 64;
      #pragma unroll
      for (int c = 0; c < 8; c++) {
        int ch = hh * 8 + c;
        bf16x8 v8 = *(bf16x8*)&Cl[row][(ch ^ (row & 7)) << 3];
        *(bf16x8*)(dst + c * 8) = v8;
      }
    } else {
      int row = tid >> 1;
      int cb = (tid & 1) * 8;
      #pragma unroll
      for (int c = 0; c < 8; c++) {
        int ch = cb + c;
        bf16x8 v8 = *(bf16x8*)&Cl[row][(ch ^ (row & 7)) << 3];
        *(bf16x8*)&((short*)outp)[(size_t)(m0 + row) * N + n0 + (ch << 3)] = v8;
      }
    }
  } else {
    #pragma unroll
    for (int i = 0; i < 4; i++)
      #pragma unroll
      for (int j = 0; j < 4; j++)
        #pragma unroll
        for (int r = 0; r < 4; r++) {
          int m = m0 + wm * 64 + i * 16 + lg * 4 + r;
          int n = n0 + wn * 64 + j * 16 + l15;
          float vv = acc[i][j][r] + bias[n];
          size_t idx = (size_t)m * N + n;
          float ov = vv + add[idx];
          if (EPI == 3) __builtin_nontemporal_store(ov, &((float*)outp)[idx]);
          else          ((float*)outp)[idx] = ov;
        }
  }
}

// ---------- 64x128 GEMM, BK=64 + XOR-swizzled LDS (out-proj EPI1, fc2 EPI3) ----------
template <int EPI, int N>
__global__ __launch_bounds__(256) void gemm_n64k64(const short* __restrict__ A,
                                                   const short* __restrict__ Bt,
                                                   const float* __restrict__ bias,
                                                   const float* __restrict__ add,
                                                   void* __restrict__ outp,
                                                   int K) {
  __shared__ short S[24576];          // 49.2 KB
  short* As0 = S;
  short* As1 = S + 4096;
  short* Bs0 = S + 8192;
  short* Bs1 = S + 16384;

  int nbx = gridDim.x;
  int flat = blockIdx.y * nbx + blockIdx.x;
  int cpx = (nbx * gridDim.y) >> 3;
  int swz = (flat & 7) * cpx + (flat >> 3);
  int m0 = (swz % nbx) * 64, n0 = (swz / nbx) * 128;

  int tid = threadIdx.x;
  int lane = tid & 63, wid = tid >> 6;
  int wm = wid & 1, wn = wid >> 1;
  int l15 = lane & 15, lg = lane >> 4;

  int r8 = tid >> 3;
  int gsl = (tid & 7) ^ (r8 & 7);
  int wb = wid << 9;

  auto stage = [&](short* Ad, short* Bd, int k0) {
    #pragma unroll
    for (int c = 0; c < 2; ++c)
      gl_lds16(&A[(size_t)(m0 + c * 32 + r8) * K + k0 + gsl * 8], Ad + c * 2048 + wb);
    #pragma unroll
    for (int c = 0; c < 4; ++c)
      gl_lds16(&Bt[(size_t)(n0 + c * 32 + r8) * K + k0 + gsl * 8], Bd + c * 2048 + wb);
  };

  f32x4 acc[2][4] = {};
  stage(As0, Bs0, 0);
  int nk = K >> 6;
  for (int t = 0; t < nk; ++t) {
    short* Ab = (t & 1) ? As1 : As0;
    short* Bb = (t & 1) ? Bs1 : Bs0;
    if (t + 1 < nk) {
      stage((t & 1) ? As0 : As1, (t & 1) ? Bs0 : Bs1, (t + 1) << 6);
      asm volatile("s_waitcnt vmcnt(6)" ::: "memory");
    } else {
      asm volatile("s_waitcnt vmcnt(0)" ::: "memory");
    }
    __syncthreads();
    bf16x8 af[2][2], bfr[4][2];
    #pragma unroll
    for (int i = 0; i < 2; i++) {
      int r = wm * 32 + i * 16 + l15;
      #pragma unroll
      for (int kk = 0; kk < 2; kk++)
        af[i][kk] = *(bf16x8*)&Ab[r * 64 + (((kk * 4 + lg) ^ (r & 7)) << 3)];
    }
    #pragma unroll
    for (int j = 0; j < 4; j++) {
      int r = wn * 64 + j * 16 + l15;
      #pragma unroll
      for (int kk = 0; kk < 2; kk++)
        bfr[j][kk] = *(bf16x8*)&Bb[r * 64 + (((kk * 4 + lg) ^ (r & 7)) << 3)];
    }
    #pragma unroll
    for (int kk = 0; kk < 2; kk++)
      #pragma unroll
      for (int i = 0; i < 2; i++)
        #pragma unroll
        for (int j = 0; j < 4; j++)
          acc[i][j] = MFMA16(af[i][kk], bfr[j][kk], acc[i][j]);
    __syncthreads();
  }

  #pragma unroll
  for (int i = 0; i < 2; i++)
    #pragma unroll
    for (int j = 0; j < 4; j++)
      #pragma unroll
      for (int r = 0; r < 4; r++) {
        int m = m0 + wm * 32 + i * 16 + lg * 4 + r;
        int n = n0 + wn * 64 + j * 16 + l15;
        float vv = acc[i][j][r] + bias[n];
        size_t idx = (size_t)m * N + n;
        float ov = vv + add[idx];
        if (EPI == 3) __builtin_nontemporal_store(ov, &((float*)outp)[idx]);
        else          ((float*)outp)[idx] = ov;
      }
}

// ---------- fused causal attention (R21 + packed-K reads) ----------
__global__ __launch_bounds__(256) void attn_fused(const short* __restrict__ qkv,
                                                  const short* __restrict__ kp,
                                                  const short* __restrict__ vt,
                                                  float* __restrict__ attw,
                                                  short* __restrict__ ctx) {
  __shared__ short VtL[2][4096];
  __shared__ float Pf[4][16][68];
  int flat = blockIdx.y * 8 + blockIdx.x;
  int xcd = flat & 7;
  int rr  = flat >> 3;                 // 0..95
  int bh  = xcd * 12 + (rr % 12);
  int pair = rr / 12;                  // 0..7
  int b = bh / Hh, h = bh % Hh;
  int tid = threadIdx.x, lane = tid & 63, wid = tid >> 6;
  int l15 = lane & 15, lg = lane >> 4;
  const short* base = qkv + (size_t)b * Tt * 2304;
  const short* kpb = kp + (size_t)bh * Tt * 64;   // packed K [t][64]
  const short* vtb = vt + (size_t)bh * 64 * Tt;
  int dS = wid * 16 + (lane >> 3);
  int cS = (lane & 7) ^ (lane >> 3);

  #pragma unroll 1
  for (int sub = 0; sub < 2; ++sub) {
    int tile = sub == 0 ? 15 - pair : pair;
    int q0 = tile * 64;

    bf16x8 qa[2];
    {
      const short* qp = base + (size_t)(q0 + wid * 16 + l15) * 2304 + h * 64 + lg * 8;
      qa[0] = *(const bf16x8*)qp;
      qa[1] = *(const bf16x8*)(qp + 32);
    }

    // ---- pass 1: per-lane sumexp, zero-tile stores interleaved ----
    float l[4] = {0.f, 0.f, 0.f, 0.f};
    int nzero = 15 - tile;
    int nit = (tile + 1 > nzero) ? (tile + 1) : nzero;
    f32x4 z = {0.f, 0.f, 0.f, 0.f};
    for (int it = 0; it < nit; ++it) {
      if (it <= tile) {
        int kt = it;
        f32x4 acc[4] = {};
        #pragma unroll
        for (int nf = 0; nf < 4; ++nf) {
          const short* kptr = kpb + (size_t)(kt * 64 + nf * 16 + l15) * 64 + lg * 8;
          bf16x8 k0 = *(const bf16x8*)kptr;
          bf16x8 k1 = *(const bf16x8*)(kptr + 32);
          acc[nf] = MFMA16(qa[0], k0, acc[nf]);
          acc[nf] = MFMA16(qa[1], k1, acc[nf]);
        }
        #pragma unroll
        for (int r = 0; r < 4; r++) {
          int qg = q0 + wid * 16 + lg * 4 + r;
          #pragma unroll
          for (int nf = 0; nf < 4; nf++) {
            int kg = kt * 64 + nf * 16 + l15;
            l[r] += (kg <= qg) ? __expf(acc[nf][r] * 0.125f) : 0.f;
          }
        }
      }
      if (it < nzero) {
        int zt = tile + 1 + it;
        #pragma unroll
        for (int p = 0; p < 4; ++p) {
          int pr = p * 4 + lg;
          __builtin_nontemporal_store(
              z, (f32x4*)&attw[((size_t)bh * Tt + q0 + wid * 16 + pr) * Tt + zt * 64 + l15 * 4]);
        }
      }
    }
    float rl[4];
    #pragma unroll
    for (int r = 0; r < 4; r++) {
      float s = l[r];
      #pragma unroll
      for (int off = 1; off < 16; off <<= 1) s += __shfl_xor(s, off);
      rl[r] = 1.f / s;
    }

    // ---- pass 2 ----
    f32x4 oacc[4] = {};
    {
      // protect VtL reuse across sub-jobs (all waves done reading prior VtL)
      __syncthreads();
      gl_lds16(&vtb[(size_t)dS * Tt + 0 + cS * 8],            &VtL[0][wid * 1024]);
      gl_lds16(&vtb[(size_t)(dS + 8) * Tt + 0 + cS * 8],      &VtL[0][wid * 1024 + 512]);
    }
    for (int kt = 0; kt <= tile; ++kt) {
      int cur = kt & 1;
      f32x4 acc[4] = {};
      #pragma unroll
      for (int nf = 0; nf < 4; nf++) {
        const short* kptr = kpb + (size_t)(kt * 64 + nf * 16 + l15) * 64 + lg * 8;
        bf16x8 k0 = *(const bf16x8*)kptr;
        bf16x8 k1 = *(const bf16x8*)(kptr + 32);
        acc[nf] = MFMA16(qa[0], k0, acc[nf]);
        acc[nf] = MFMA16(qa[1], k1, acc[nf]);
      }
      #pragma unroll
      for (int nf = 0; nf < 4; nf++) {
        #pragma unroll
        for (int r = 0; r < 4; r++) {
          int qg = q0 + wid * 16 + lg * 4 + r;
          int kg = kt * 64 + nf * 16 + l15;
          float p = (kg <= qg) ? __expf(acc[nf][r] * 0.125f) * rl[r] : 0.f;
          Pf[wid][lg * 4 + r][nf * 16 + l15] = p;
        }
      }
      asm volatile("s_waitcnt lgkmcnt(0)" ::: "memory");
      __builtin_amdgcn_sched_barrier(0);
      #pragma unroll
      for (int it = 0; it < 4; ++it) {
        int pr = it * 4 + lg;
        f32x4 pv = *(f32x4*)&Pf[wid][pr][l15 * 4];
        __builtin_nontemporal_store(
            pv, (f32x4*)&attw[((size_t)bh * Tt + q0 + wid * 16 + pr) * Tt + kt * 64 + l15 * 4]);
      }
      f32x4 pf0 = *(f32x4*)&Pf[wid][l15][lg * 8];
      f32x4 pf1 = *(f32x4*)&Pf[wid][l15][lg * 8 + 4];
      f32x4 pf2 = *(f32x4*)&Pf[wid][l15][lg * 8 + 32];
      f32x4 pf3 = *(f32x4*)&Pf[wid][l15][lg * 8 + 36];
      bf16x8 pa0, pa1;
      #pragma unroll
      for (int j = 0; j < 4; j++) {
        pa0[j] = f2bf(pf0[j]); pa0[4 + j] = f2bf(pf1[j]);
        pa1[j] = f2bf(pf2[j]); pa1[4 + j] = f2bf(pf3[j]);
      }
      asm volatile("s_waitcnt vmcnt(4)" ::: "memory");
      __builtin_amdgcn_s_barrier();
      __builtin_amdgcn_sched_barrier(0);
      if (kt < tile) {
        int nx = cur ^ 1, nkt = kt + 1;
        gl_lds16(&vtb[(size_t)dS * Tt + nkt * 64 + cS * 8],       &VtL[nx][wid * 1024]);
        gl_lds16(&vtb[(size_t)(dS + 8) * Tt + nkt * 64 + cS * 8], &VtL[nx][wid * 1024 + 512]);
      }
      #pragma unroll
      for (int nf = 0; nf < 4; nf++) {
        int dA = nf * 16 + l15;
        int sw = dA & 7;
        bf16x8 vb0 = *(bf16x8*)&VtL[cur][dA * 64 + ((lg ^ sw) << 3)];
        bf16x8 vb1 = *(bf16x8*)&VtL[cur][dA * 64 + (((4 + lg) ^ sw) << 3)];
        oacc[nf] = MFMA16(pa0, vb0, oacc[nf]);
        oacc[nf] = MFMA16(pa1, vb1, oacc[nf]);
      }
    }
    #pragma unroll
    for (int nf = 0; nf < 4; nf++) {
      #pragma unroll
      for (int r = 0; r < 4; r++) {
        int t = q0 + wid * 16 + lg * 4 + r;
        ctx[((size_t)b * Tt + t) * Dd + h * 64 + nf * 16 + l15] = f2bf(oacc[nf][r]);
      }
    }
  }
}

}  // namespace

extern "C" void kernel_launch(void* const* d_in, const int* in_sizes, int n_in,
                              void* d_out, int out_size, void* d_ws, size_t ws_size,
                              hipStream_t stream) {
  const float* x     = (const float*)d_in[0];
  const float* ln1g  = (const float*)d_in[1];
  const float* ln1b  = (const float*)d_in[2];
  const float* w_qkv = (const float*)d_in[3];
  const float* b_qkv = (const float*)d_in[4];
  const float* w_out = (const float*)d_in[5];
  const float* b_out = (const float*)d_in[6];
  const float* ln2g  = (const float*)d_in[7];
  const float* ln2b  = (const float*)d_in[8];
  const float* w_fc1 = (const float*)d_in[9];
  const float* b_fc1 = (const float*)d_in[10];
  const float* w_fc2 = (const float*)d_in[11];
  const float* b_fc2 = (const float*)d_in[12];

  char* ws = (char*)d_ws;
  size_t o = 0;
  short* wqkvT = (short*)(ws + o); o += (size_t)2304 * 768 * 2;
  short* woutT = (short*)(ws + o); o += (size_t)768 * 768 * 2;
  short* wfc1T = (short*)(ws + o); o += (size_t)3072 * 768 * 2;
  short* wfc2T = (short*)(ws + o); o += (size_t)768 * 3072 * 2;
  short* h     = (short*)(ws + o); o += (size_t)BT * Dd * 2;
  short* qkv   = (short*)(ws + o); o += (size_t)BT * 2304 * 2;
  float* y1    = (float*)(ws + o); o += (size_t)BT * Dd * 4;
  short* h2    = (short*)(ws + o); o += (size_t)BT * Dd * 2;
  short* vt    = (short*)(ws + o); o += (size_t)96 * 64 * Tt * 2;
  short* ctx  = h;     // reuse: h dead after QKV GEMM
  short* gbuf = h;     // reuse: h+qkv for GELU output (attw fully written before fc1)
  short* kpak = (short*)y1;  // packed K [bh][t][64], 12.6MB — y1 written only
                             // by out-proj AFTER attention completes (serial stream)

  float* out_x = (float*)d_out;
  float* attw  = out_x + (size_t)BT * Dd;

  prep<<<8960, 256, 0, stream>>>(w_qkv, wqkvT, w_out, woutT, w_fc1, wfc1T,
                                 w_fc2, wfc2T, x, ln1g, ln1b, h);
  gemm_bt<0, 2304, true><<<dim3(BT / 128, 2304 / 128), 256, 0, stream>>>(
      h, wqkvT, b_qkv, nullptr, qkv, 768, vt, kpak);
  attn_fused<<<dim3(8, 96), 256, 0, stream>>>(qkv, kpak, vt, attw, ctx);
  gemm_n64k64<1, 768><<<dim3(BT / 64, 768 / 128), 256, 0, stream>>>(
      ctx, woutT, b_out, x, y1, 768);
  ln_rows<<<BT / 4, 256, 0, stream>>>(y1, ln2g, ln2b, h2);
  gemm_bt<2, 3072, false><<<dim3(BT / 128, 3072 / 128), 256, 0, stream>>>(
      h2, wfc1T, b_fc1, nullptr, gbuf, 768, nullptr, nullptr);
  gemm_n64k64<3, 768><<<dim3(BT / 64, 768 / 128), 256, 0, stream>>>(
      gbuf, wfc2T, b_fc2, y1, out_x, 3072);
}

// Round 24
// 364.819 us; speedup vs baseline: 1.1329x; 1.0136x over previous
//
#include <hip/hip_runtime.h>
#include <cstdint>
#include <cstddef>

namespace {

constexpr int Bb  = 8;
constexpr int Tt  = 1024;
constexpr int Dd  = 768;
constexpr int Hh  = 12;
constexpr int DFF = 3072;
constexpr int BT  = Bb * Tt;

typedef __attribute__((ext_vector_type(8))) short bf16x8;
typedef __attribute__((ext_vector_type(4))) short bf16x4;
typedef __attribute__((ext_vector_type(4))) float f32x4;

__device__ __forceinline__ short f2bf(float f) {
  union { float f; unsigned u; } v; v.f = f;
  unsigned r = v.u + 0x7fffu + ((v.u >> 16) & 1u);   // RNE
  return (short)(r >> 16);
}
__device__ __forceinline__ float gelu_exact(float v) {
  return 0.5f * v * (1.0f + erff(v * 0.70710678118654752f));
}

#define MFMA16(a, b, c) __builtin_amdgcn_mfma_f32_16x16x32_bf16(a, b, c, 0, 0, 0)

__device__ __forceinline__ void gl_lds16(const short* g, short* l) {
  __builtin_amdgcn_global_load_lds(
      (const __attribute__((address_space(1))) unsigned int*)(g),
      (__attribute__((address_space(3))) unsigned int*)(l), 16, 0, 0);
}

// ---------- weight convert+transpose body ----------
__device__ __forceinline__ void cvt_body(float (*tile)[33],
                                         const float* __restrict__ in,
                                         short* __restrict__ out,
                                         int K, int N, int bx, int by) {
  int k0 = bx * 32, n0 = by * 32;
  int tx = threadIdx.x & 31, ty = threadIdx.x >> 5;
  #pragma unroll
  for (int r = ty; r < 32; r += 8)
    tile[r][tx] = in[(size_t)(k0 + r) * N + n0 + tx];
  __syncthreads();
  #pragma unroll
  for (int r = ty; r < 32; r += 8)
    out[(size_t)(n0 + r) * K + k0 + tx] = f2bf(tile[tx][r]);
}

// ---------- LayerNorm body ----------
__device__ __forceinline__ void ln_body(const float* __restrict__ x,
                                        const float* __restrict__ g,
                                        const float* __restrict__ b,
                                        short* __restrict__ out, int blkrow) {
  int lane = threadIdx.x & 63, wid = threadIdx.x >> 6;
  int row = blkrow * 4 + wid;
  const float* xr = x + (size_t)row * Dd;
  float v[12];
  float s = 0.f, ss = 0.f;
  #pragma unroll
  for (int c = 0; c < 3; c++) {
    float4 t = *(const float4*)&xr[c * 256 + lane * 4];
    v[c * 4 + 0] = t.x; v[c * 4 + 1] = t.y; v[c * 4 + 2] = t.z; v[c * 4 + 3] = t.w;
    s  += t.x + t.y + t.z + t.w;
    ss += t.x * t.x + t.y * t.y + t.z * t.z + t.w * t.w;
  }
  #pragma unroll
  for (int off = 1; off < 64; off <<= 1) {
    s += __shfl_xor(s, off); ss += __shfl_xor(ss, off);
  }
  float mu   = s * (1.f / Dd);
  float var  = ss * (1.f / Dd) - mu * mu;
  float rstd = rsqrtf(var + 1e-5f);
  #pragma unroll
  for (int c = 0; c < 3; c++) {
    bf16x4 o;
    #pragma unroll
    for (int j = 0; j < 4; j++) {
      int d = c * 256 + lane * 4 + j;
      o[j] = f2bf((v[c * 4 + j] - mu) * rstd * g[d] + b[d]);
    }
    *(bf16x4*)&out[(size_t)row * Dd + c * 256 + lane * 4] = o;
  }
}

// ---------- prep: 4 weight-converts + LN1 ----------
__global__ __launch_bounds__(256) void prep(const float* __restrict__ w_qkv, short* wqkvT,
                                            const float* __restrict__ w_out, short* woutT,
                                            const float* __restrict__ w_fc1, short* wfc1T,
                                            const float* __restrict__ w_fc2, short* wfc2T,
                                            const float* __restrict__ x,
                                            const float* __restrict__ g,
                                            const float* __restrict__ b,
                                            short* __restrict__ h) {
  __shared__ float tile[32][33];
  int j = blockIdx.x;
  if (j < 1728)      cvt_body(tile, w_qkv, wqkvT, 768, 2304, j % 24, j / 24);
  else if (j < 2304) { int t = j - 1728; cvt_body(tile, w_out, woutT, 768, 768, t % 24, t / 24); }
  else if (j < 4608) { int t = j - 2304; cvt_body(tile, w_fc1, wfc1T, 768, 3072, t % 24, t / 24); }
  else if (j < 6912) { int t = j - 4608; cvt_body(tile, w_fc2, wfc2T, 3072, 768, t % 96, t / 96); }
  else               ln_body(x, g, b, h, j - 6912);
}

// ---------- standalone LayerNorm (LN2) ----------
__global__ __launch_bounds__(256) void ln_rows(const float* __restrict__ x,
                                               const float* __restrict__ g,
                                               const float* __restrict__ b,
                                               short* __restrict__ out) {
  ln_body(x, g, b, out, blockIdx.x);
}

// ---------- 128x128 GEMM (QKV w/ VTR+KPK; fc1 EPI2). LDS exactly 32KB -> 5 blocks/CU ----------
template <int EPI, int N, bool VTR>
__global__ __launch_bounds__(256) void gemm_bt(const short* __restrict__ A,
                                               const short* __restrict__ Bt,
                                               const float* __restrict__ bias,
                                               const float* __restrict__ add,
                                               void* __restrict__ outp,
                                               int K,
                                               short* __restrict__ vt,
                                               short* __restrict__ kp) {
  __shared__ short S[16384];          // 32 KB exactly (staging 4x8KB; epilogue Cl[128][128])
  short* As0 = S;
  short* As1 = S + 4096;
  short* Bs0 = S + 8192;
  short* Bs1 = S + 12288;

  int nbx = gridDim.x;
  int flat = blockIdx.y * nbx + blockIdx.x;
  int cpx = (nbx * gridDim.y) >> 3;
  int swz = (flat & 7) * cpx + (flat >> 3);
  int m0 = (swz % nbx) * 128, n0 = (swz / nbx) * 128;

  int tid = threadIdx.x;
  int lane = tid & 63, wid = tid >> 6;
  int wm = wid >> 1, wn = wid & 1;
  int l15 = lane & 15, lg = lane >> 4;

  int jr = tid >> 2, jc = (tid & 3) << 3;
  int ldsb = wid << 9;

  auto stage = [&](short* Ad, short* Bd, int k0) {
    gl_lds16(&A[(size_t)(m0 + jr) * K + k0 + jc],       Ad + ldsb);
    gl_lds16(&A[(size_t)(m0 + 64 + jr) * K + k0 + jc],  Ad + 2048 + ldsb);
    gl_lds16(&Bt[(size_t)(n0 + jr) * K + k0 + jc],      Bd + ldsb);
    gl_lds16(&Bt[(size_t)(n0 + 64 + jr) * K + k0 + jc], Bd + 2048 + ldsb);
  };

  f32x4 acc[4][4] = {};
  stage(As0, Bs0, 0);
  int nk = K >> 5;
  for (int t = 0; t < nk; ++t) {
    short* Ab = (t & 1) ? As1 : As0;
    short* Bb = (t & 1) ? Bs1 : Bs0;
    if (t + 1 < nk) {
      stage((t & 1) ? As0 : As1, (t & 1) ? Bs0 : Bs1, (t + 1) << 5);
      asm volatile("s_waitcnt vmcnt(4)" ::: "memory");
    } else {
      asm volatile("s_waitcnt vmcnt(0)" ::: "memory");
    }
    __syncthreads();
    bf16x8 af[4], bfr[4];
    #pragma unroll
    for (int i = 0; i < 4; i++) af[i]  = *(bf16x8*)&Ab[(wm * 64 + i * 16 + l15) * 32 + lg * 8];
    #pragma unroll
    for (int j = 0; j < 4; j++) bfr[j] = *(bf16x8*)&Bb[(wn * 64 + j * 16 + l15) * 32 + lg * 8];
    #pragma unroll
    for (int i = 0; i < 4; i++)
      #pragma unroll
      for (int j = 0; j < 4; j++)
        acc[i][j] = MFMA16(af[i], bfr[j], acc[i][j]);
    __syncthreads();
  }

  if (EPI == 0 || EPI == 2) {
    short (*Cl)[128] = (short (*)[128])S;
    #pragma unroll
    for (int i = 0; i < 4; i++)
      #pragma unroll
      for (int j = 0; j < 4; j++)
        #pragma unroll
        for (int r = 0; r < 4; r++) {
          int row = wm * 64 + i * 16 + lg * 4 + r;
          int col = wn * 64 + j * 16 + l15;
          float vv = acc[i][j][r] + bias[n0 + col];
          if (EPI == 2) vv = gelu_exact(vv);
          int ch = col >> 3, co = col & 7;
          Cl[row][((ch ^ (row & 7)) << 3) | co] = f2bf(vv);
        }
    __syncthreads();
    if (VTR && n0 >= 1536) {
      // V: transposed store vt[(b*12+h)*64 + d][tbase + t]
      int b = m0 >> 10, tbase = m0 & 1023;
      int h0 = (n0 - 1536) >> 6;
      #pragma unroll
      for (int half = 0; half < 2; ++half) {
        int c = (tid >> 2) + half * 64;
        int hh = c >> 6, d = c & 63;
        short* dst = vt + ((size_t)((b * Hh + h0 + hh) * 64 + d)) * Tt
                        + tbase + (tid & 3) * 32;
        #pragma unroll
        for (int j = 0; j < 4; ++j) {
          bf16x8 v8;
          #pragma unroll
          for (int k = 0; k < 8; ++k) {
            int t = (tid & 3) * 32 + j * 8 + k;
            v8[k] = Cl[t][(((c >> 3) ^ (t & 7)) << 3) | (c & 7)];
          }
          *(bf16x8*)(dst + j * 8) = v8;
        }
      }
    } else if (VTR && n0 >= 768) {
      // K: packed store kp[(b*12+h)*1024 + t][64]
      int b = m0 >> 10, tbase = m0 & 1023;
      int h0 = (n0 - 768) >> 6;
      int row = tid >> 1;
      int hh = tid & 1;
      short* dst = kp + ((size_t)((b * Hh + h0 + hh) * Tt) + tbase + row) * 64;
      #pragma unroll
      for (int c = 0; c < 8; c++) {
        int ch = hh * 8 + c;
        bf16x8 v8 = *(bf16x8*)&Cl[row][(ch ^ (row & 7)) << 3];
        *(bf16x8*)(dst + c * 8) = v8;
      }
    } else {
      int row = tid >> 1;
      int cb = (tid & 1) * 8;
      #pragma unroll
      for (int c = 0; c < 8; c++) {
        int ch = cb + c;
        bf16x8 v8 = *(bf16x8*)&Cl[row][(ch ^ (row & 7)) << 3];
        *(bf16x8*)&((short*)outp)[(size_t)(m0 + row) * N + n0 + (ch << 3)] = v8;
      }
    }
  } else {
    #pragma unroll
    for (int i = 0; i < 4; i++)
      #pragma unroll
      for (int j = 0; j < 4; j++)
        #pragma unroll
        for (int r = 0; r < 4; r++) {
          int m = m0 + wm * 64 + i * 16 + lg * 4 + r;
          int n = n0 + wn * 64 + j * 16 + l15;
          float vv = acc[i][j][r] + bias[n];
          size_t idx = (size_t)m * N + n;
          float ov = vv + add[idx];
          if (EPI == 3) __builtin_nontemporal_store(ov, &((float*)outp)[idx]);
          else          ((float*)outp)[idx] = ov;
        }
  }
}

// ---------- 64x128 GEMM, BK=64 + XOR-swizzled LDS (out-proj EPI1, fc2 EPI3) ----------
template <int EPI, int N>
__global__ __launch_bounds__(256) void gemm_n64k64(const short* __restrict__ A,
                                                   const short* __restrict__ Bt,
                                                   const float* __restrict__ bias,
                                                   const float* __restrict__ add,
                                                   void* __restrict__ outp,
                                                   int K) {
  __shared__ short S[24576];          // 49.2 KB
  short* As0 = S;
  short* As1 = S + 4096;
  short* Bs0 = S + 8192;
  short* Bs1 = S + 16384;

  int nbx = gridDim.x;
  int flat = blockIdx.y * nbx + blockIdx.x;
  int cpx = (nbx * gridDim.y) >> 3;
  int swz = (flat & 7) * cpx + (flat >> 3);
  int m0 = (swz % nbx) * 64, n0 = (swz / nbx) * 128;

  int tid = threadIdx.x;
  int lane = tid & 63, wid = tid >> 6;
  int wm = wid & 1, wn = wid >> 1;
  int l15 = lane & 15, lg = lane >> 4;

  int r8 = tid >> 3;
  int gsl = (tid & 7) ^ (r8 & 7);
  int wb = wid << 9;

  auto stage = [&](short* Ad, short* Bd, int k0) {
    #pragma unroll
    for (int c = 0; c < 2; ++c)
      gl_lds16(&A[(size_t)(m0 + c * 32 + r8) * K + k0 + gsl * 8], Ad + c * 2048 + wb);
    #pragma unroll
    for (int c = 0; c < 4; ++c)
      gl_lds16(&Bt[(size_t)(n0 + c * 32 + r8) * K + k0 + gsl * 8], Bd + c * 2048 + wb);
  };

  f32x4 acc[2][4] = {};
  stage(As0, Bs0, 0);
  int nk = K >> 6;
  for (int t = 0; t < nk; ++t) {
    short* Ab = (t & 1) ? As1 : As0;
    short* Bb = (t & 1) ? Bs1 : Bs0;
    if (t + 1 < nk) {
      stage((t & 1) ? As0 : As1, (t & 1) ? Bs0 : Bs1, (t + 1) << 6);
      asm volatile("s_waitcnt vmcnt(6)" ::: "memory");
    } else {
      asm volatile("s_waitcnt vmcnt(0)" ::: "memory");
    }
    __syncthreads();
    bf16x8 af[2][2], bfr[4][2];
    #pragma unroll
    for (int i = 0; i < 2; i++) {
      int r = wm * 32 + i * 16 + l15;
      #pragma unroll
      for (int kk = 0; kk < 2; kk++)
        af[i][kk] = *(bf16x8*)&Ab[r * 64 + (((kk * 4 + lg) ^ (r & 7)) << 3)];
    }
    #pragma unroll
    for (int j = 0; j < 4; j++) {
      int r = wn * 64 + j * 16 + l15;
      #pragma unroll
      for (int kk = 0; kk < 2; kk++)
        bfr[j][kk] = *(bf16x8*)&Bb[r * 64 + (((kk * 4 + lg) ^ (r & 7)) << 3)];
    }
    #pragma unroll
    for (int kk = 0; kk < 2; kk++)
      #pragma unroll
      for (int i = 0; i < 2; i++)
        #pragma unroll
        for (int j = 0; j < 4; j++)
          acc[i][j] = MFMA16(af[i][kk], bfr[j][kk], acc[i][j]);
    __syncthreads();
  }

  #pragma unroll
  for (int i = 0; i < 2; i++)
    #pragma unroll
    for (int j = 0; j < 4; j++)
      #pragma unroll
      for (int r = 0; r < 4; r++) {
        int m = m0 + wm * 32 + i * 16 + lg * 4 + r;
        int n = n0 + wn * 64 + j * 16 + l15;
        float vv = acc[i][j][r] + bias[n];
        size_t idx = (size_t)m * N + n;
        float ov = vv + add[idx];
        if (EPI == 3) __builtin_nontemporal_store(ov, &((float*)outp)[idx]);
        else          ((float*)outp)[idx] = ov;
      }
}

// ---------- fused causal attention (R22: pairing + packed K) ----------
__global__ __launch_bounds__(256) void attn_fused(const short* __restrict__ qkv,
                                                  const short* __restrict__ kp,
                                                  const short* __restrict__ vt,
                                                  float* __restrict__ attw,
                                                  short* __restrict__ ctx) {
  __shared__ short VtL[2][4096];
  __shared__ float Pf[4][16][68];
  int flat = blockIdx.y * 8 + blockIdx.x;
  int xcd = flat & 7;
  int rr  = flat >> 3;                 // 0..95
  int bh  = xcd * 12 + (rr % 12);
  int pair = rr / 12;                  // 0..7
  int b = bh / Hh, h = bh % Hh;
  int tid = threadIdx.x, lane = tid & 63, wid = tid >> 6;
  int l15 = lane & 15, lg = lane >> 4;
  const short* base = qkv + (size_t)b * Tt * 2304;
  const short* kpb = kp + (size_t)bh * Tt * 64;
  const short* vtb = vt + (size_t)bh * 64 * Tt;
  int dS = wid * 16 + (lane >> 3);
  int cS = (lane & 7) ^ (lane >> 3);

  #pragma unroll 1
  for (int sub = 0; sub < 2; ++sub) {
    int tile = sub == 0 ? 15 - pair : pair;
    int q0 = tile * 64;

    bf16x8 qa[2];
    {
      const short* qp = base + (size_t)(q0 + wid * 16 + l15) * 2304 + h * 64 + lg * 8;
      qa[0] = *(const bf16x8*)qp;
      qa[1] = *(const bf16x8*)(qp + 32);
    }

    // ---- pass 1: per-lane sumexp, zero-tile stores interleaved ----
    float l[4] = {0.f, 0.f, 0.f, 0.f};
    int nzero = 15 - tile;
    int nit = (tile + 1 > nzero) ? (tile + 1) : nzero;
    f32x4 z = {0.f, 0.f, 0.f, 0.f};
    for (int it = 0; it < nit; ++it) {
      if (it <= tile) {
        int kt = it;
        f32x4 acc[4] = {};
        #pragma unroll
        for (int nf = 0; nf < 4; ++nf) {
          const short* kptr = kpb + (size_t)(kt * 64 + nf * 16 + l15) * 64 + lg * 8;
          bf16x8 k0 = *(const bf16x8*)kptr;
          bf16x8 k1 = *(const bf16x8*)(kptr + 32);
          acc[nf] = MFMA16(qa[0], k0, acc[nf]);
          acc[nf] = MFMA16(qa[1], k1, acc[nf]);
        }
        #pragma unroll
        for (int r = 0; r < 4; r++) {
          int qg = q0 + wid * 16 + lg * 4 + r;
          #pragma unroll
          for (int nf = 0; nf < 4; nf++) {
            int kg = kt * 64 + nf * 16 + l15;
            l[r] += (kg <= qg) ? __expf(acc[nf][r] * 0.125f) : 0.f;
          }
        }
      }
      if (it < nzero) {
        int zt = tile + 1 + it;
        #pragma unroll
        for (int p = 0; p < 4; ++p) {
          int pr = p * 4 + lg;
          __builtin_nontemporal_store(
              z, (f32x4*)&attw[((size_t)bh * Tt + q0 + wid * 16 + pr) * Tt + zt * 64 + l15 * 4]);
        }
      }
    }
    float rl[4];
    #pragma unroll
    for (int r = 0; r < 4; r++) {
      float s = l[r];
      #pragma unroll
      for (int off = 1; off < 16; off <<= 1) s += __shfl_xor(s, off);
      rl[r] = 1.f / s;
    }

    // ---- pass 2 ----
    f32x4 oacc[4] = {};
    {
      __syncthreads();
      gl_lds16(&vtb[(size_t)dS * Tt + 0 + cS * 8],            &VtL[0][wid * 1024]);
      gl_lds16(&vtb[(size_t)(dS + 8) * Tt + 0 + cS * 8],      &VtL[0][wid * 1024 + 512]);
    }
    for (int kt = 0; kt <= tile; ++kt) {
      int cur = kt & 1;
      f32x4 acc[4] = {};
      #pragma unroll
      for (int nf = 0; nf < 4; nf++) {
        const short* kptr = kpb + (size_t)(kt * 64 + nf * 16 + l15) * 64 + lg * 8;
        bf16x8 k0 = *(const bf16x8*)kptr;
        bf16x8 k1 = *(const bf16x8*)(kptr + 32);
        acc[nf] = MFMA16(qa[0], k0, acc[nf]);
        acc[nf] = MFMA16(qa[1], k1, acc[nf]);
      }
      #pragma unroll
      for (int nf = 0; nf < 4; nf++) {
        #pragma unroll
        for (int r = 0; r < 4; r++) {
          int qg = q0 + wid * 16 + lg * 4 + r;
          int kg = kt * 64 + nf * 16 + l15;
          float p = (kg <= qg) ? __expf(acc[nf][r] * 0.125f) * rl[r] : 0.f;
          Pf[wid][lg * 4 + r][nf * 16 + l15] = p;
        }
      }
      asm volatile("s_waitcnt lgkmcnt(0)" ::: "memory");
      __builtin_amdgcn_sched_barrier(0);
      #pragma unroll
      for (int it = 0; it < 4; ++it) {
        int pr = it * 4 + lg;
        f32x4 pv = *(f32x4*)&Pf[wid][pr][l15 * 4];
        __builtin_nontemporal_store(
            pv, (f32x4*)&attw[((size_t)bh * Tt + q0 + wid * 16 + pr) * Tt + kt * 64 + l15 * 4]);
      }
      f32x4 pf0 = *(f32x4*)&Pf[wid][l15][lg * 8];
      f32x4 pf1 = *(f32x4*)&Pf[wid][l15][lg * 8 + 4];
      f32x4 pf2 = *(f32x4*)&Pf[wid][l15][lg * 8 + 32];
      f32x4 pf3 = *(f32x4*)&Pf[wid][l15][lg * 8 + 36];
      bf16x8 pa0, pa1;
      #pragma unroll
      for (int j = 0; j < 4; j++) {
        pa0[j] = f2bf(pf0[j]); pa0[4 + j] = f2bf(pf1[j]);
        pa1[j] = f2bf(pf2[j]); pa1[4 + j] = f2bf(pf3[j]);
      }
      asm volatile("s_waitcnt vmcnt(4)" ::: "memory");
      __builtin_amdgcn_s_barrier();
      __builtin_amdgcn_sched_barrier(0);
      if (kt < tile) {
        int nx = cur ^ 1, nkt = kt + 1;
        gl_lds16(&vtb[(size_t)dS * Tt + nkt * 64 + cS * 8],       &VtL[nx][wid * 1024]);
        gl_lds16(&vtb[(size_t)(dS + 8) * Tt + nkt * 64 + cS * 8], &VtL[nx][wid * 1024 + 512]);
      }
      #pragma unroll
      for (int nf = 0; nf < 4; nf++) {
        int dA = nf * 16 + l15;
        int sw = dA & 7;
        bf16x8 vb0 = *(bf16x8*)&VtL[cur][dA * 64 + ((lg ^ sw) << 3)];
        bf16x8 vb1 = *(bf16x8*)&VtL[cur][dA * 64 + (((4 + lg) ^ sw) << 3)];
        oacc[nf] = MFMA16(pa0, vb0, oacc[nf]);
        oacc[nf] = MFMA16(pa1, vb1, oacc[nf]);
      }
    }
    #pragma unroll
    for (int nf = 0; nf < 4; nf++) {
      #pragma unroll
      for (int r = 0; r < 4; r++) {
        int t = q0 + wid * 16 + lg * 4 + r;
        ctx[((size_t)b * Tt + t) * Dd + h * 64 + nf * 16 + l15] = f2bf(oacc[nf][r]);
      }
    }
  }
}

}  // namespace

extern "C" void kernel_launch(void* const* d_in, const int* in_sizes, int n_in,
                              void* d_out, int out_size, void* d_ws, size_t ws_size,
                              hipStream_t stream) {
  const float* x     = (const float*)d_in[0];
  const float* ln1g  = (const float*)d_in[1];
  const float* ln1b  = (const float*)d_in[2];
  const float* w_qkv = (const float*)d_in[3];
  const float* b_qkv = (const float*)d_in[4];
  const float* w_out = (const float*)d_in[5];
  const float* b_out = (const float*)d_in[6];
  const float* ln2g  = (const float*)d_in[7];
  const float* ln2b  = (const float*)d_in[8];
  const float* w_fc1 = (const float*)d_in[9];
  const float* b_fc1 = (const float*)d_in[10];
  const float* w_fc2 = (const float*)d_in[11];
  const float* b_fc2 = (const float*)d_in[12];

  char* ws = (char*)d_ws;
  size_t o = 0;
  short* wqkvT = (short*)(ws + o); o += (size_t)2304 * 768 * 2;
  short* woutT = (short*)(ws + o); o += (size_t)768 * 768 * 2;
  short* wfc1T = (short*)(ws + o); o += (size_t)3072 * 768 * 2;
  short* wfc2T = (short*)(ws + o); o += (size_t)768 * 3072 * 2;
  short* h     = (short*)(ws + o); o += (size_t)BT * Dd * 2;
  short* qkv   = (short*)(ws + o); o += (size_t)BT * 2304 * 2;
  float* y1    = (float*)(ws + o); o += (size_t)BT * Dd * 4;
  short* h2    = (short*)(ws + o); o += (size_t)BT * Dd * 2;
  short* vt    = (short*)(ws + o); o += (size_t)96 * 64 * Tt * 2;
  short* ctx  = h;     // reuse: h dead after QKV GEMM
  short* gbuf = h;     // reuse: h+qkv for GELU output (attw fully written before fc1)
  short* kpak = (short*)y1;  // packed K [bh][t][64]; y1 written only after attn

  float* out_x = (float*)d_out;
  float* attw  = out_x + (size_t)BT * Dd;

  prep<<<8960, 256, 0, stream>>>(w_qkv, wqkvT, w_out, woutT, w_fc1, wfc1T,
                                 w_fc2, wfc2T, x, ln1g, ln1b, h);
  gemm_bt<0, 2304, true><<<dim3(BT / 128, 2304 / 128), 256, 0, stream>>>(
      h, wqkvT, b_qkv, nullptr, qkv, 768, vt, kpak);
  attn_fused<<<dim3(8, 96), 256, 0, stream>>>(qkv, kpak, vt, attw, ctx);
  gemm_n64k64<1, 768><<<dim3(BT / 64, 768 / 128), 256, 0, stream>>>(
      ctx, woutT, b_out, x, y1, 768);
  ln_rows<<<BT / 4, 256, 0, stream>>>(y1, ln2g, ln2b, h2);
  gemm_bt<2, 3072, false><<<dim3(BT / 128, 3072 / 128), 256, 0, stream>>>(
      h2, wfc1T, b_fc1, nullptr, gbuf, 768, nullptr, nullptr);
  gemm_n64k64<3, 768><<<dim3(BT / 64, 768 / 128), 256, 0, stream>>>(
      gbuf, wfc2T, b_fc2, y1, out_x, 3072);
}

// Round 25
// 359.048 us; speedup vs baseline: 1.1511x; 1.0161x over previous
//
#include <hip/hip_runtime.h>
#include <cstdint>
#include <cstddef>

namespace {

constexpr int Bb  = 8;
constexpr int Tt  = 1024;
constexpr int Dd  = 768;
constexpr int Hh  = 12;
constexpr int DFF = 3072;
constexpr int BT  = Bb * Tt;

typedef __attribute__((ext_vector_type(8))) short bf16x8;
typedef __attribute__((ext_vector_type(4))) short bf16x4;
typedef __attribute__((ext_vector_type(4))) float f32x4;

__device__ __forceinline__ short f2bf(float f) {
  union { float f; unsigned u; } v; v.f = f;
  unsigned r = v.u + 0x7fffu + ((v.u >> 16) & 1u);   // RNE
  return (short)(r >> 16);
}
__device__ __forceinline__ float gelu_exact(float v) {
  return 0.5f * v * (1.0f + erff(v * 0.70710678118654752f));
}

#define MFMA16(a, b, c) __builtin_amdgcn_mfma_f32_16x16x32_bf16(a, b, c, 0, 0, 0)

__device__ __forceinline__ void gl_lds16(const short* g, short* l) {
  __builtin_amdgcn_global_load_lds(
      (const __attribute__((address_space(1))) unsigned int*)(g),
      (__attribute__((address_space(3))) unsigned int*)(l), 16, 0, 0);
}

// ---------- weight convert+transpose body ----------
__device__ __forceinline__ void cvt_body(float (*tile)[33],
                                         const float* __restrict__ in,
                                         short* __restrict__ out,
                                         int K, int N, int bx, int by) {
  int k0 = bx * 32, n0 = by * 32;
  int tx = threadIdx.x & 31, ty = threadIdx.x >> 5;
  #pragma unroll
  for (int r = ty; r < 32; r += 8)
    tile[r][tx] = in[(size_t)(k0 + r) * N + n0 + tx];
  __syncthreads();
  #pragma unroll
  for (int r = ty; r < 32; r += 8)
    out[(size_t)(n0 + r) * K + k0 + tx] = f2bf(tile[tx][r]);
}

// ---------- LayerNorm body ----------
__device__ __forceinline__ void ln_body(const float* __restrict__ x,
                                        const float* __restrict__ g,
                                        const float* __restrict__ b,
                                        short* __restrict__ out, int blkrow) {
  int lane = threadIdx.x & 63, wid = threadIdx.x >> 6;
  int row = blkrow * 4 + wid;
  const float* xr = x + (size_t)row * Dd;
  float v[12];
  float s = 0.f, ss = 0.f;
  #pragma unroll
  for (int c = 0; c < 3; c++) {
    float4 t = *(const float4*)&xr[c * 256 + lane * 4];
    v[c * 4 + 0] = t.x; v[c * 4 + 1] = t.y; v[c * 4 + 2] = t.z; v[c * 4 + 3] = t.w;
    s  += t.x + t.y + t.z + t.w;
    ss += t.x * t.x + t.y * t.y + t.z * t.z + t.w * t.w;
  }
  #pragma unroll
  for (int off = 1; off < 64; off <<= 1) {
    s += __shfl_xor(s, off); ss += __shfl_xor(ss, off);
  }
  float mu   = s * (1.f / Dd);
  float var  = ss * (1.f / Dd) - mu * mu;
  float rstd = rsqrtf(var + 1e-5f);
  #pragma unroll
  for (int c = 0; c < 3; c++) {
    bf16x4 o;
    #pragma unroll
    for (int j = 0; j < 4; j++) {
      int d = c * 256 + lane * 4 + j;
      o[j] = f2bf((v[c * 4 + j] - mu) * rstd * g[d] + b[d]);
    }
    *(bf16x4*)&out[(size_t)row * Dd + c * 256 + lane * 4] = o;
  }
}

// ---------- prep: 4 weight-converts + LN1 ----------
__global__ __launch_bounds__(256) void prep(const float* __restrict__ w_qkv, short* wqkvT,
                                            const float* __restrict__ w_out, short* woutT,
                                            const float* __restrict__ w_fc1, short* wfc1T,
                                            const float* __restrict__ w_fc2, short* wfc2T,
                                            const float* __restrict__ x,
                                            const float* __restrict__ g,
                                            const float* __restrict__ b,
                                            short* __restrict__ h) {
  __shared__ float tile[32][33];
  int j = blockIdx.x;
  if (j < 1728)      cvt_body(tile, w_qkv, wqkvT, 768, 2304, j % 24, j / 24);
  else if (j < 2304) { int t = j - 1728; cvt_body(tile, w_out, woutT, 768, 768, t % 24, t / 24); }
  else if (j < 4608) { int t = j - 2304; cvt_body(tile, w_fc1, wfc1T, 768, 3072, t % 24, t / 24); }
  else if (j < 6912) { int t = j - 4608; cvt_body(tile, w_fc2, wfc2T, 3072, 768, t % 96, t / 96); }
  else               ln_body(x, g, b, h, j - 6912);
}

// ---------- standalone LayerNorm (LN2) ----------
__global__ __launch_bounds__(256) void ln_rows(const float* __restrict__ x,
                                               const float* __restrict__ g,
                                               const float* __restrict__ b,
                                               short* __restrict__ out) {
  ln_body(x, g, b, out, blockIdx.x);
}

// ---------- 128x128 GEMM (QKV w/ VTR+KPK; fc1 EPI2). LDS exactly 32KB -> 5 blocks/CU ----------
template <int EPI, int N, bool VTR>
__global__ __launch_bounds__(256) void gemm_bt(const short* __restrict__ A,
                                               const short* __restrict__ Bt,
                                               const float* __restrict__ bias,
                                               const float* __restrict__ add,
                                               void* __restrict__ outp,
                                               int K,
                                               short* __restrict__ vt,
                                               short* __restrict__ kp) {
  __shared__ short S[16384];          // 32 KB exactly
  short* As0 = S;
  short* As1 = S + 4096;
  short* Bs0 = S + 8192;
  short* Bs1 = S + 12288;

  int nbx = gridDim.x;
  int flat = blockIdx.y * nbx + blockIdx.x;
  int cpx = (nbx * gridDim.y) >> 3;
  int swz = (flat & 7) * cpx + (flat >> 3);
  int m0 = (swz % nbx) * 128, n0 = (swz / nbx) * 128;

  int tid = threadIdx.x;
  int lane = tid & 63, wid = tid >> 6;
  int wm = wid >> 1, wn = wid & 1;
  int l15 = lane & 15, lg = lane >> 4;

  int jr = tid >> 2, jc = (tid & 3) << 3;
  int ldsb = wid << 9;

  auto stage = [&](short* Ad, short* Bd, int k0) {
    gl_lds16(&A[(size_t)(m0 + jr) * K + k0 + jc],       Ad + ldsb);
    gl_lds16(&A[(size_t)(m0 + 64 + jr) * K + k0 + jc],  Ad + 2048 + ldsb);
    gl_lds16(&Bt[(size_t)(n0 + jr) * K + k0 + jc],      Bd + ldsb);
    gl_lds16(&Bt[(size_t)(n0 + 64 + jr) * K + k0 + jc], Bd + 2048 + ldsb);
  };

  f32x4 acc[4][4] = {};
  stage(As0, Bs0, 0);
  int nk = K >> 5;
  for (int t = 0; t < nk; ++t) {
    short* Ab = (t & 1) ? As1 : As0;
    short* Bb = (t & 1) ? Bs1 : Bs0;
    if (t + 1 < nk) {
      stage((t & 1) ? As0 : As1, (t & 1) ? Bs0 : Bs1, (t + 1) << 5);
      asm volatile("s_waitcnt vmcnt(4)" ::: "memory");
    } else {
      asm volatile("s_waitcnt vmcnt(0)" ::: "memory");
    }
    __syncthreads();
    bf16x8 af[4], bfr[4];
    #pragma unroll
    for (int i = 0; i < 4; i++) af[i]  = *(bf16x8*)&Ab[(wm * 64 + i * 16 + l15) * 32 + lg * 8];
    #pragma unroll
    for (int j = 0; j < 4; j++) bfr[j] = *(bf16x8*)&Bb[(wn * 64 + j * 16 + l15) * 32 + lg * 8];
    #pragma unroll
    for (int i = 0; i < 4; i++)
      #pragma unroll
      for (int j = 0; j < 4; j++)
        acc[i][j] = MFMA16(af[i], bfr[j], acc[i][j]);
    __syncthreads();
  }

  if (EPI == 0 || EPI == 2) {
    short (*Cl)[128] = (short (*)[128])S;
    #pragma unroll
    for (int i = 0; i < 4; i++)
      #pragma unroll
      for (int j = 0; j < 4; j++)
        #pragma unroll
        for (int r = 0; r < 4; r++) {
          int row = wm * 64 + i * 16 + lg * 4 + r;
          int col = wn * 64 + j * 16 + l15;
          float vv = acc[i][j][r] + bias[n0 + col];
          if (EPI == 2) vv = gelu_exact(vv);
          int ch = col >> 3, co = col & 7;
          Cl[row][((ch ^ (row & 7)) << 3) | co] = f2bf(vv);
        }
    __syncthreads();
    if (VTR && n0 >= 1536) {
      int b = m0 >> 10, tbase = m0 & 1023;
      int h0 = (n0 - 1536) >> 6;
      #pragma unroll
      for (int half = 0; half < 2; ++half) {
        int c = (tid >> 2) + half * 64;
        int hh = c >> 6, d = c & 63;
        short* dst = vt + ((size_t)((b * Hh + h0 + hh) * 64 + d)) * Tt
                        + tbase + (tid & 3) * 32;
        #pragma unroll
        for (int j = 0; j < 4; ++j) {
          bf16x8 v8;
          #pragma unroll
          for (int k = 0; k < 8; ++k) {
            int t = (tid & 3) * 32 + j * 8 + k;
            v8[k] = Cl[t][(((c >> 3) ^ (t & 7)) << 3) | (c & 7)];
          }
          *(bf16x8*)(dst + j * 8) = v8;
        }
      }
    } else if (VTR && n0 >= 768) {
      int b = m0 >> 10, tbase = m0 & 1023;
      int h0 = (n0 - 768) >> 6;
      int row = tid >> 1;
      int hh = tid & 1;
      short* dst = kp + ((size_t)((b * Hh + h0 + hh) * Tt) + tbase + row) * 64;
      #pragma unroll
      for (int c = 0; c < 8; c++) {
        int ch = hh * 8 + c;
        bf16x8 v8 = *(bf16x8*)&Cl[row][(ch ^ (row & 7)) << 3];
        *(bf16x8*)(dst + c * 8) = v8;
      }
    } else {
      int row = tid >> 1;
      int cb = (tid & 1) * 8;
      #pragma unroll
      for (int c = 0; c < 8; c++) {
        int ch = cb + c;
        bf16x8 v8 = *(bf16x8*)&Cl[row][(ch ^ (row & 7)) << 3];
        *(bf16x8*)&((short*)outp)[(size_t)(m0 + row) * N + n0 + (ch << 3)] = v8;
      }
    }
  } else {
    #pragma unroll
    for (int i = 0; i < 4; i++)
      #pragma unroll
      for (int j = 0; j < 4; j++)
        #pragma unroll
        for (int r = 0; r < 4; r++) {
          int m = m0 + wm * 64 + i * 16 + lg * 4 + r;
          int n = n0 + wn * 64 + j * 16 + l15;
          float vv = acc[i][j][r] + bias[n];
          size_t idx = (size_t)m * N + n;
          float ov = vv + add[idx];
          if (EPI == 3) __builtin_nontemporal_store(ov, &((float*)outp)[idx]);
          else          ((float*)outp)[idx] = ov;
        }
  }
}

// ---------- 64x128 GEMM, BK=64 + XOR-swizzled LDS (out-proj EPI1, fc2 EPI3) ----------
template <int EPI, int N>
__global__ __launch_bounds__(256) void gemm_n64k64(const short* __restrict__ A,
                                                   const short* __restrict__ Bt,
                                                   const float* __restrict__ bias,
                                                   const float* __restrict__ add,
                                                   void* __restrict__ outp,
                                                   int K) {
  __shared__ short S[24576];          // 49.2 KB
  short* As0 = S;
  short* As1 = S + 4096;
  short* Bs0 = S + 8192;
  short* Bs1 = S + 16384;

  int nbx = gridDim.x;
  int flat = blockIdx.y * nbx + blockIdx.x;
  int cpx = (nbx * gridDim.y) >> 3;
  int swz = (flat & 7) * cpx + (flat >> 3);
  int m0 = (swz % nbx) * 64, n0 = (swz / nbx) * 128;

  int tid = threadIdx.x;
  int lane = tid & 63, wid = tid >> 6;
  int wm = wid & 1, wn = wid >> 1;
  int l15 = lane & 15, lg = lane >> 4;

  int r8 = tid >> 3;
  int gsl = (tid & 7) ^ (r8 & 7);
  int wb = wid << 9;

  auto stage = [&](short* Ad, short* Bd, int k0) {
    #pragma unroll
    for (int c = 0; c < 2; ++c)
      gl_lds16(&A[(size_t)(m0 + c * 32 + r8) * K + k0 + gsl * 8], Ad + c * 2048 + wb);
    #pragma unroll
    for (int c = 0; c < 4; ++c)
      gl_lds16(&Bt[(size_t)(n0 + c * 32 + r8) * K + k0 + gsl * 8], Bd + c * 2048 + wb);
  };

  f32x4 acc[2][4] = {};
  stage(As0, Bs0, 0);
  int nk = K >> 6;
  for (int t = 0; t < nk; ++t) {
    short* Ab = (t & 1) ? As1 : As0;
    short* Bb = (t & 1) ? Bs1 : Bs0;
    if (t + 1 < nk) {
      stage((t & 1) ? As0 : As1, (t & 1) ? Bs0 : Bs1, (t + 1) << 6);
      asm volatile("s_waitcnt vmcnt(6)" ::: "memory");
    } else {
      asm volatile("s_waitcnt vmcnt(0)" ::: "memory");
    }
    __syncthreads();
    bf16x8 af[2][2], bfr[4][2];
    #pragma unroll
    for (int i = 0; i < 2; i++) {
      int r = wm * 32 + i * 16 + l15;
      #pragma unroll
      for (int kk = 0; kk < 2; kk++)
        af[i][kk] = *(bf16x8*)&Ab[r * 64 + (((kk * 4 + lg) ^ (r & 7)) << 3)];
    }
    #pragma unroll
    for (int j = 0; j < 4; j++) {
      int r = wn * 64 + j * 16 + l15;
      #pragma unroll
      for (int kk = 0; kk < 2; kk++)
        bfr[j][kk] = *(bf16x8*)&Bb[r * 64 + (((kk * 4 + lg) ^ (r & 7)) << 3)];
    }
    #pragma unroll
    for (int kk = 0; kk < 2; kk++)
      #pragma unroll
      for (int i = 0; i < 2; i++)
        #pragma unroll
        for (int j = 0; j < 4; j++)
          acc[i][j] = MFMA16(af[i][kk], bfr[j][kk], acc[i][j]);
    __syncthreads();
  }

  #pragma unroll
  for (int i = 0; i < 2; i++)
    #pragma unroll
    for (int j = 0; j < 4; j++)
      #pragma unroll
      for (int r = 0; r < 4; r++) {
        int m = m0 + wm * 32 + i * 16 + lg * 4 + r;
        int n = n0 + wn * 64 + j * 16 + l15;
        float vv = acc[i][j][r] + bias[n];
        size_t idx = (size_t)m * N + n;
        float ov = vv + add[idx];
        if (EPI == 3) __builtin_nontemporal_store(ov, &((float*)outp)[idx]);
        else          ((float*)outp)[idx] = ov;
      }
}

// ---------- fused causal attention (R23 + parity-staggered sub-job order) ----------
// Half the blocks process (heavy,light), half (light,heavy): at any instant the
// grid mixes compute-heavy and store-heavy phases instead of global lockstep.
__global__ __launch_bounds__(256) void attn_fused(const short* __restrict__ qkv,
                                                  const short* __restrict__ kp,
                                                  const short* __restrict__ vt,
                                                  float* __restrict__ attw,
                                                  short* __restrict__ ctx) {
  __shared__ short VtL[2][4096];
  __shared__ float Pf[4][16][68];
  int flat = blockIdx.y * 8 + blockIdx.x;
  int xcd = flat & 7;
  int rr  = flat >> 3;                 // 0..95
  int bh  = xcd * 12 + (rr % 12);
  int pair = rr / 12;                  // 0..7
  int stag = rr & 1;                   // stagger sub-job order by parity
  int b = bh / Hh, h = bh % Hh;
  int tid = threadIdx.x, lane = tid & 63, wid = tid >> 6;
  int l15 = lane & 15, lg = lane >> 4;
  const short* base = qkv + (size_t)b * Tt * 2304;
  const short* kpb = kp + (size_t)bh * Tt * 64;
  const short* vtb = vt + (size_t)bh * 64 * Tt;
  int dS = wid * 16 + (lane >> 3);
  int cS = (lane & 7) ^ (lane >> 3);

  #pragma unroll 1
  for (int sub = 0; sub < 2; ++sub) {
    int tile = (sub ^ stag) == 0 ? 15 - pair : pair;
    int q0 = tile * 64;

    bf16x8 qa[2];
    {
      const short* qp = base + (size_t)(q0 + wid * 16 + l15) * 2304 + h * 64 + lg * 8;
      qa[0] = *(const bf16x8*)qp;
      qa[1] = *(const bf16x8*)(qp + 32);
    }

    // ---- pass 1: per-lane sumexp, zero-tile stores interleaved ----
    float l[4] = {0.f, 0.f, 0.f, 0.f};
    int nzero = 15 - tile;
    int nit = (tile + 1 > nzero) ? (tile + 1) : nzero;
    f32x4 z = {0.f, 0.f, 0.f, 0.f};
    for (int it = 0; it < nit; ++it) {
      if (it <= tile) {
        int kt = it;
        f32x4 acc[4] = {};
        #pragma unroll
        for (int nf = 0; nf < 4; ++nf) {
          const short* kptr = kpb + (size_t)(kt * 64 + nf * 16 + l15) * 64 + lg * 8;
          bf16x8 k0 = *(const bf16x8*)kptr;
          bf16x8 k1 = *(const bf16x8*)(kptr + 32);
          acc[nf] = MFMA16(qa[0], k0, acc[nf]);
          acc[nf] = MFMA16(qa[1], k1, acc[nf]);
        }
        #pragma unroll
        for (int r = 0; r < 4; r++) {
          int qg = q0 + wid * 16 + lg * 4 + r;
          #pragma unroll
          for (int nf = 0; nf < 4; nf++) {
            int kg = kt * 64 + nf * 16 + l15;
            l[r] += (kg <= qg) ? __expf(acc[nf][r] * 0.125f) : 0.f;
          }
        }
      }
      if (it < nzero) {
        int zt = tile + 1 + it;
        #pragma unroll
        for (int p = 0; p < 4; ++p) {
          int pr = p * 4 + lg;
          __builtin_nontemporal_store(
              z, (f32x4*)&attw[((size_t)bh * Tt + q0 + wid * 16 + pr) * Tt + zt * 64 + l15 * 4]);
        }
      }
    }
    float rl[4];
    #pragma unroll
    for (int r = 0; r < 4; r++) {
      float s = l[r];
      #pragma unroll
      for (int off = 1; off < 16; off <<= 1) s += __shfl_xor(s, off);
      rl[r] = 1.f / s;
    }

    // ---- pass 2 ----
    f32x4 oacc[4] = {};
    {
      __syncthreads();
      gl_lds16(&vtb[(size_t)dS * Tt + 0 + cS * 8],            &VtL[0][wid * 1024]);
      gl_lds16(&vtb[(size_t)(dS + 8) * Tt + 0 + cS * 8],      &VtL[0][wid * 1024 + 512]);
    }
    for (int kt = 0; kt <= tile; ++kt) {
      int cur = kt & 1;
      f32x4 acc[4] = {};
      #pragma unroll
      for (int nf = 0; nf < 4; nf++) {
        const short* kptr = kpb + (size_t)(kt * 64 + nf * 16 + l15) * 64 + lg * 8;
        bf16x8 k0 = *(const bf16x8*)kptr;
        bf16x8 k1 = *(const bf16x8*)(kptr + 32);
        acc[nf] = MFMA16(qa[0], k0, acc[nf]);
        acc[nf] = MFMA16(qa[1], k1, acc[nf]);
      }
      #pragma unroll
      for (int nf = 0; nf < 4; nf++) {
        #pragma unroll
        for (int r = 0; r < 4; r++) {
          int qg = q0 + wid * 16 + lg * 4 + r;
          int kg = kt * 64 + nf * 16 + l15;
          float p = (kg <= qg) ? __expf(acc[nf][r] * 0.125f) * rl[r] : 0.f;
          Pf[wid][lg * 4 + r][nf * 16 + l15] = p;
        }
      }
      asm volatile("s_waitcnt lgkmcnt(0)" ::: "memory");
      __builtin_amdgcn_sched_barrier(0);
      #pragma unroll
      for (int it = 0; it < 4; ++it) {
        int pr = it * 4 + lg;
        f32x4 pv = *(f32x4*)&Pf[wid][pr][l15 * 4];
        __builtin_nontemporal_store(
            pv, (f32x4*)&attw[((size_t)bh * Tt + q0 + wid * 16 + pr) * Tt + kt * 64 + l15 * 4]);
      }
      f32x4 pf0 = *(f32x4*)&Pf[wid][l15][lg * 8];
      f32x4 pf1 = *(f32x4*)&Pf[wid][l15][lg * 8 + 4];
      f32x4 pf2 = *(f32x4*)&Pf[wid][l15][lg * 8 + 32];
      f32x4 pf3 = *(f32x4*)&Pf[wid][l15][lg * 8 + 36];
      bf16x8 pa0, pa1;
      #pragma unroll
      for (int j = 0; j < 4; j++) {
        pa0[j] = f2bf(pf0[j]); pa0[4 + j] = f2bf(pf1[j]);
        pa1[j] = f2bf(pf2[j]); pa1[4 + j] = f2bf(pf3[j]);
      }
      asm volatile("s_waitcnt vmcnt(4)" ::: "memory");
      __builtin_amdgcn_s_barrier();
      __builtin_amdgcn_sched_barrier(0);
      if (kt < tile) {
        int nx = cur ^ 1, nkt = kt + 1;
        gl_lds16(&vtb[(size_t)dS * Tt + nkt * 64 + cS * 8],       &VtL[nx][wid * 1024]);
        gl_lds16(&vtb[(size_t)(dS + 8) * Tt + nkt * 64 + cS * 8], &VtL[nx][wid * 1024 + 512]);
      }
      #pragma unroll
      for (int nf = 0; nf < 4; nf++) {
        int dA = nf * 16 + l15;
        int sw = dA & 7;
        bf16x8 vb0 = *(bf16x8*)&VtL[cur][dA * 64 + ((lg ^ sw) << 3)];
        bf16x8 vb1 = *(bf16x8*)&VtL[cur][dA * 64 + (((4 + lg) ^ sw) << 3)];
        oacc[nf] = MFMA16(pa0, vb0, oacc[nf]);
        oacc[nf] = MFMA16(pa1, vb1, oacc[nf]);
      }
    }
    #pragma unroll
    for (int nf = 0; nf < 4; nf++) {
      #pragma unroll
      for (int r = 0; r < 4; r++) {
        int t = q0 + wid * 16 + lg * 4 + r;
        ctx[((size_t)b * Tt + t) * Dd + h * 64 + nf * 16 + l15] = f2bf(oacc[nf][r]);
      }
    }
  }
}

}  // namespace

extern "C" void kernel_launch(void* const* d_in, const int* in_sizes, int n_in,
                              void* d_out, int out_size, void* d_ws, size_t ws_size,
                              hipStream_t stream) {
  const float* x     = (const float*)d_in[0];
  const float* ln1g  = (const float*)d_in[1];
  const float* ln1b  = (const float*)d_in[2];
  const float* w_qkv = (const float*)d_in[3];
  const float* b_qkv = (const float*)d_in[4];
  const float* w_out = (const float*)d_in[5];
  const float* b_out = (const float*)d_in[6];
  const float* ln2g  = (const float*)d_in[7];
  const float* ln2b  = (const float*)d_in[8];
  const float* w_fc1 = (const float*)d_in[9];
  const float* b_fc1 = (const float*)d_in[10];
  const float* w_fc2 = (const float*)d_in[11];
  const float* b_fc2 = (const float*)d_in[12];

  char* ws = (char*)d_ws;
  size_t o = 0;
  short* wqkvT = (short*)(ws + o); o += (size_t)2304 * 768 * 2;
  short* woutT = (short*)(ws + o); o += (size_t)768 * 768 * 2;
  short* wfc1T = (short*)(ws + o); o += (size_t)3072 * 768 * 2;
  short* wfc2T = (short*)(ws + o); o += (size_t)768 * 3072 * 2;
  short* h     = (short*)(ws + o); o += (size_t)BT * Dd * 2;
  short* qkv   = (short*)(ws + o); o += (size_t)BT * 2304 * 2;
  float* y1    = (float*)(ws + o); o += (size_t)BT * Dd * 4;
  short* h2    = (short*)(ws + o); o += (size_t)BT * Dd * 2;
  short* vt    = (short*)(ws + o); o += (size_t)96 * 64 * Tt * 2;
  short* ctx  = h;     // reuse: h dead after QKV GEMM
  short* gbuf = h;     // reuse: h+qkv for GELU output (attw fully written before fc1)
  short* kpak = (short*)y1;  // packed K [bh][t][64]; y1 written only after attn

  float* out_x = (float*)d_out;
  float* attw  = out_x + (size_t)BT * Dd;

  prep<<<8960, 256, 0, stream>>>(w_qkv, wqkvT, w_out, woutT, w_fc1, wfc1T,
                                 w_fc2, wfc2T, x, ln1g, ln1b, h);
  gemm_bt<0, 2304, true><<<dim3(BT / 128, 2304 / 128), 256, 0, stream>>>(
      h, wqkvT, b_qkv, nullptr, qkv, 768, vt, kpak);
  attn_fused<<<dim3(8, 96), 256, 0, stream>>>(qkv, kpak, vt, attw, ctx);
  gemm_n64k64<1, 768><<<dim3(BT / 64, 768 / 128), 256, 0, stream>>>(
      ctx, woutT, b_out, x, y1, 768);
  ln_rows<<<BT / 4, 256, 0, stream>>>(y1, ln2g, ln2b, h2);
  gemm_bt<2, 3072, false><<<dim3(BT / 128, 3072 / 128), 256, 0, stream>>>(
      h2, wfc1T, b_fc1, nullptr, gbuf, 768, nullptr, nullptr);
  gemm_n64k64<3, 768><<<dim3(BT / 64, 768 / 128), 256, 0, stream>>>(
      gbuf, wfc2T, b_fc2, y1, out_x, 3072);
}